// Round 11
// baseline (987.050 us; speedup 1.0000x reference)
//
#include <hip/hip_runtime.h>
#include <hip/hip_bf16.h>

#define BATCH 2048
#define FEAT  768
#define NIND  1024
#define NCLS  16

typedef unsigned short u16;
typedef __attribute__((ext_vector_type(8))) __bf16 bf16x8;
typedef __attribute__((ext_vector_type(4))) float f32x4;

static __device__ __forceinline__ unsigned f2bf(float f) {
  unsigned u = __float_as_uint(f);
  unsigned r = ((u >> 16) & 1u) + 0x7FFFu;
  return (u + r) >> 16;                       // RNE bf16 in low 16 bits
}
static __device__ __forceinline__ float bflo(unsigned x) {
  return __uint_as_float((x & 0xFFFFu) << 16);
}
static __device__ __forceinline__ float bfhi(unsigned x) {
  return __uint_as_float(x & 0xFFFF0000u);
}

// async 16B global->LDS (LDS dest = wave-uniform base + lane*16)
static __device__ __forceinline__ void gload16(const u16* g, u16* l) {
  __builtin_amdgcn_global_load_lds(
      (const __attribute__((address_space(1))) void*)g,
      (__attribute__((address_space(3))) void*)l, 16, 0, 0);
}

// pack 8 bf16 (as uint4) scaled by wv[0..7] back to 8 bf16 (uint4)
static __device__ __forceinline__ uint4 scale8(uint4 v, const float* wv) {
  unsigned out[4];
  const unsigned* in = (const unsigned*)&v;
  #pragma unroll
  for (int i = 0; i < 4; ++i) {
    float lo = bflo(in[i]) * wv[2*i];
    float hi = bfhi(in[i]) * wv[2*i+1];
    __hip_bfloat162 pk = __float22bfloat162_rn(float2{lo, hi});
    out[i] = *(unsigned*)&pk;
  }
  return uint4{out[0], out[1], out[2], out[3]};
}

// K1: phi = sqrt(2/N)*cos(2*(x@W+b)); writes phi [B][N] f32, phiB [B][N] bf16, phiTB [N][B] bf16
__global__ __launch_bounds__(256) void phi_kernel(
    const float* __restrict__ x, const float* __restrict__ rw,
    const float* __restrict__ rb, float* __restrict__ phi,
    u16* __restrict__ phiB, u16* __restrict__ phiTB)
{
  __shared__ float xs[64][17];
  __shared__ float wsh[16][68];
  __shared__ float ts[64][65];
  const int b0 = blockIdx.x * 64, i0 = blockIdx.y * 64;
  const int tid = threadIdx.x;
  const int tr = tid >> 4, tc = tid & 15;
  float acc[4][4] = {};
  for (int k0 = 0; k0 < FEAT; k0 += 16) {
    {
      int bb = tid >> 2, kk = (tid & 3) << 2;
      float4 v = *(const float4*)(x + (size_t)(b0 + bb) * FEAT + k0 + kk);
      xs[bb][kk] = v.x; xs[bb][kk+1] = v.y; xs[bb][kk+2] = v.z; xs[bb][kk+3] = v.w;
      int k2 = tid >> 4, ii = (tid & 15) << 2;
      *(float4*)(&wsh[k2][ii]) = *(const float4*)(rw + (size_t)(k0 + k2) * NIND + i0 + ii);
    }
    __syncthreads();
    #pragma unroll
    for (int q = 0; q < 16; ++q) {
      float a[4];
      #pragma unroll
      for (int r = 0; r < 4; ++r) a[r] = xs[tr*4+r][q];
      float4 b4 = *(const float4*)(&wsh[q][tc*4]);
      float bv[4] = {b4.x, b4.y, b4.z, b4.w};
      #pragma unroll
      for (int r = 0; r < 4; ++r)
        #pragma unroll
        for (int c = 0; c < 4; ++c) acc[r][c] += a[r] * bv[c];
    }
    __syncthreads();
  }
  const float SC = 0.04419417382415922f;   // sqrt(2/1024)
  float4 rb4 = *(const float4*)(rb + i0 + tc*4);
  float rbl[4] = {rb4.x, rb4.y, rb4.z, rb4.w};
  #pragma unroll
  for (int r = 0; r < 4; ++r) {
    float vals[4];
    #pragma unroll
    for (int c = 0; c < 4; ++c) {
      float pr = 2.0f * (acc[r][c] + rbl[c]);
      vals[c] = SC * cosf(pr);
      ts[tr*4+r][tc*4+c] = vals[c];
    }
    float4 o = make_float4(vals[0], vals[1], vals[2], vals[3]);
    *(float4*)(phi + (size_t)(b0 + tr*4 + r) * NIND + i0 + tc*4) = o;
    uint2 ob;
    ob.x = (f2bf(o.x) & 0xFFFFu) | (f2bf(o.y) << 16);
    ob.y = (f2bf(o.z) & 0xFFFFu) | (f2bf(o.w) << 16);
    *(uint2*)(phiB + (size_t)(b0 + tr*4 + r) * NIND + i0 + tc*4) = ob;
  }
  __syncthreads();
  #pragma unroll
  for (int rep = 0; rep < 4; ++rep) {
    int ii = tr*4 + rep;
    int bb2 = tc*4;
    float4 o = make_float4(ts[bb2][ii], ts[bb2+1][ii], ts[bb2+2][ii], ts[bb2+3][ii]);
    uint2 ob;
    ob.x = (f2bf(o.x) & 0xFFFFu) | (f2bf(o.y) << 16);
    ob.y = (f2bf(o.z) & 0xFFFFu) | (f2bf(o.w) << 16);
    *(uint2*)(phiTB + (size_t)(i0 + ii) * BATCH + b0 + bb2) = ob;
  }
}

// K2: tiled logits GEMM + in-block softmax -> wmat[k][b] = p(1-p)
__global__ __launch_bounds__(256) void logits_kernel(
    const float* __restrict__ phi, const float* __restrict__ bw,
    const float* __restrict__ bbias, float* __restrict__ out,
    float* __restrict__ wmat)
{
  __shared__ float ph[64][132];
  __shared__ float bwl[16][132];
  __shared__ float lg[64][17];
  const int b0 = blockIdx.x * 64;
  const int tid = threadIdx.x;
  const int bl = tid & 63, kq = tid >> 6;
  float acc[4] = {};
  for (int kb = 0; kb < NIND; kb += 128) {
    #pragma unroll
    for (int i = 0; i < 8; ++i) {
      int f = i * 256 + tid;
      int row = f >> 5, c4 = (f & 31) << 2;
      *(float4*)(&ph[row][c4]) = *(const float4*)(phi + (size_t)(b0 + row) * NIND + kb + c4);
    }
    #pragma unroll
    for (int i = 0; i < 2; ++i) {
      int f = i * 256 + tid;
      int row = f >> 5, c4 = (f & 31) << 2;
      *(float4*)(&bwl[row][c4]) = *(const float4*)(bw + (size_t)row * NIND + kb + c4);
    }
    __syncthreads();
    #pragma unroll 8
    for (int q = 0; q < 128; q += 4) {
      float4 a = *(const float4*)(&ph[bl][q]);
      #pragma unroll
      for (int j = 0; j < 4; ++j) {
        float4 b4 = *(const float4*)(&bwl[kq*4+j][q]);
        acc[j] += a.x*b4.x + a.y*b4.y + a.z*b4.z + a.w*b4.w;
      }
    }
    __syncthreads();
  }
  #pragma unroll
  for (int j = 0; j < 4; ++j) {
    float v = acc[j] + bbias[kq*4+j];
    lg[bl][kq*4+j] = v;
    out[(size_t)(b0 + bl) * NCLS + kq*4 + j] = v;
  }
  __syncthreads();
  if (tid < 64) {
    float mx = -1e30f;
    #pragma unroll
    for (int k = 0; k < 16; ++k) mx = fmaxf(mx, lg[tid][k]);
    float s = 0.f, ex[16];
    #pragma unroll
    for (int k = 0; k < 16; ++k) { ex[k] = expf(lg[tid][k] - mx); s += ex[k]; }
    float inv = 1.0f / s;
    #pragma unroll
    for (int k = 0; k < 16; ++k) {
      float p = ex[k] * inv;
      wmat[(size_t)k * BATCH + b0 + tid] = p * (1.0f - p);
    }
  }
}

// K3: MFMA bf16 gram -> Pb bf16. A = (w*phi) via reg-staging; B = raw phi via gload_lds.
__global__ __launch_bounds__(256) void gram_kernel(
    const u16* __restrict__ phiTB, const float* __restrict__ wmat,
    const float* __restrict__ prec, u16* __restrict__ Pb)
{
  __shared__ u16 Als[128 * 64];
  __shared__ u16 Bls[128 * 64];
  int p = blockIdx.x;
  int ti = 0;
  while ((ti + 1) * (ti + 2) / 2 <= p) ++ti;
  int tj = p - ti * (ti + 1) / 2;
  const int k = blockIdx.y;
  const int i0 = ti * 128, j0 = tj * 128;
  const bool diag = (ti == tj);
  const int tid = threadIdx.x;
  const int wid = tid >> 6, lane = tid & 63;
  const int wr = wid >> 1, wc = wid & 1;
  const u16* Ag = phiTB + (size_t)i0 * BATCH;
  const u16* Bg = phiTB + (size_t)j0 * BATCH;
  const float* sw = wmat + (size_t)k * BATCH;
  f32x4 acc[4][4];
  #pragma unroll
  for (int m = 0; m < 4; ++m)
    #pragma unroll
    for (int n = 0; n < 4; ++n) acc[m][n] = (f32x4){0.f, 0.f, 0.f, 0.f};
  const int kc8 = tid & 7;
  for (int b0 = 0; b0 < BATCH; b0 += 64) {
    #pragma unroll
    for (int c = 0; c < 4; ++c) {
      int f = c * 256 + tid;
      int row = f >> 3, s = f & 7;
      int sc = (s ^ (row & 7)) << 3;
      gload16(Bg + (size_t)row * BATCH + b0 + sc, Bls + ((c * 256 + wid * 64) << 3));
    }
    const int bcol = b0 + kc8 * 8;
    float4 w0 = *(const float4*)(sw + bcol);
    float4 w1 = *(const float4*)(sw + bcol + 4);
    float wv[8] = {w0.x, w0.y, w0.z, w0.w, w1.x, w1.y, w1.z, w1.w};
    #pragma unroll
    for (int c = 0; c < 4; ++c) {
      int row = c * 32 + (tid >> 3);
      int idx = (row * 64 + kc8 * 8) ^ ((row & 7) << 3);
      uint4 va = *(const uint4*)(Ag + (size_t)row * BATCH + bcol);
      *(uint4*)(&Als[idx]) = scale8(va, wv);
    }
    __syncthreads();
    #pragma unroll
    for (int ks = 0; ks < 2; ++ks) {
      bf16x8 af[4], bfr[4];
      #pragma unroll
      for (int m = 0; m < 4; ++m) {
        int row = wr * 64 + m * 16 + (lane & 15);
        int kb = ks * 32 + (lane >> 4) * 8;
        int idx = (row * 64 + kb) ^ ((row & 7) << 3);
        af[m] = *(const bf16x8*)(&Als[idx]);
      }
      #pragma unroll
      for (int n = 0; n < 4; ++n) {
        int row = wc * 64 + n * 16 + (lane & 15);
        int kb = ks * 32 + (lane >> 4) * 8;
        int idx = (row * 64 + kb) ^ ((row & 7) << 3);
        bfr[n] = *(const bf16x8*)(&Bls[idx]);
      }
      #pragma unroll
      for (int m = 0; m < 4; ++m)
        #pragma unroll
        for (int n = 0; n < 4; ++n)
          acc[m][n] = __builtin_amdgcn_mfma_f32_16x16x32_bf16(af[m], bfr[n], acc[m][n], 0, 0, 0);
    }
    __syncthreads();
  }
  const size_t kb2 = (size_t)k * NIND * NIND;
  #pragma unroll
  for (int m = 0; m < 4; ++m) {
    #pragma unroll
    for (int n = 0; n < 4; ++n) {
      #pragma unroll
      for (int r = 0; r < 4; ++r) {
        int gi = i0 + wr * 64 + m * 16 + (lane >> 4) * 4 + r;
        int gj = j0 + wc * 64 + n * 16 + (lane & 15);
        size_t idx = kb2 + (size_t)gi * NIND + gj;
        float v = acc[m][n][r] + prec[idx];
        u16 bv = (u16)f2bf(v);
        Pb[idx] = bv;
        if (!diag) Pb[kb2 + (size_t)gj * NIND + gi] = bv;
      }
    }
  }
}

// K4: Gershgorin bound per class: gmax[k] = max_i sum_j |P_ij| (certified >= lambda_max)
__global__ __launch_bounds__(256) void gersh_kernel(
    const u16* __restrict__ Pb, unsigned* __restrict__ gmax)
{
  __shared__ float psum[64][17];
  const int k = blockIdx.y, rbk = blockIdx.x;
  const int tid = threadIdx.x;
  const size_t mb = (size_t)k * NIND * NIND;
  #pragma unroll
  for (int p = 0; p < 4; ++p) {
    int rl = p * 16 + (tid >> 4);
    int row = rbk * 64 + rl;
    int ch = tid & 15;
    float s = 0.f;
    const u16* base = Pb + mb + (size_t)row * NIND + ch * 64;
    #pragma unroll
    for (int c8 = 0; c8 < 8; ++c8) {
      uint4 u = *(const uint4*)(base + c8 * 8);
      const unsigned* uu = (const unsigned*)&u;
      #pragma unroll
      for (int q = 0; q < 4; ++q)
        s += fabsf(bflo(uu[q])) + fabsf(bfhi(uu[q]));
    }
    psum[rl][ch] = s;
  }
  __syncthreads();
  if (tid < 64) {
    float s = 0.f;
    #pragma unroll
    for (int j = 0; j < 16; ++j) s += psum[tid][j];
    psum[tid][16] = s;
  }
  __syncthreads();
  if (tid == 0) {
    float mx = 0.f;
    for (int t = 0; t < 64; ++t) mx = fmaxf(mx, psum[t][16]);
    atomicMax(gmax + k, __float_as_uint(mx));
  }
}

// K5: X1 = 2a*I - a^2 * Pb with a = 2/(1+G)
__global__ __launch_bounds__(256) void xinit_kernel(
    const u16* __restrict__ Pb, const unsigned* __restrict__ gmax, u16* __restrict__ X)
{
  const int k = blockIdx.y;
  float lb = __uint_as_float(gmax[k]) * 1.001f + 0.01f;
  if (lb < 1.05f) lb = 1.05f;
  float al = 2.0f / (1.0f + lb);
  float a2 = al * al, two_a = 2.0f * al;
  size_t flat = ((size_t)blockIdx.x * 256 + threadIdx.x) * 8;
  int i = (int)(flat >> 10), j0 = (int)(flat & 1023);
  const size_t mb = (size_t)k * NIND * NIND;
  uint4 u = *(const uint4*)(Pb + mb + flat);
  const unsigned* uu = (const unsigned*)&u;
  unsigned ow[4];
  #pragma unroll
  for (int q = 0; q < 4; ++q) {
    float lo = -a2 * bflo(uu[q]);
    float hi = -a2 * bfhi(uu[q]);
    int cj = j0 + 2 * q;
    if (i == cj) lo += two_a;
    if (i == cj + 1) hi += two_a;
    ow[q] = (f2bf(lo) & 0xFFFFu) | (f2bf(hi) << 16);
  }
  *(uint4*)(X + mb + flat) = uint4{ow[0], ow[1], ow[2], ow[3]};
}

// K6: symmetric-output Newton GEMM. All of X, P, XP, X' are symmetric (X is a
// polynomial in P), so compute only the 36 lower tile-pairs and mirror.
// mode 0: C = A (*) B^T ; mode 1: C = 2*Xadd - A (*) B^T.
__global__ __launch_bounds__(256) void ntgemm_kernel(
    const u16* __restrict__ A, const u16* __restrict__ B,
    const u16* __restrict__ Xadd, u16* __restrict__ C, int mode)
{
  __shared__ u16 Als[128 * 64];
  __shared__ u16 Bls[128 * 64];
  const int k = blockIdx.y;
  int p = blockIdx.x;
  int ti = 0;
  while ((ti + 1) * (ti + 2) / 2 <= p) ++ti;
  int tj = p - ti * (ti + 1) / 2;
  const bool diag = (ti == tj);
  const int i0 = ti * 128, j0 = tj * 128;
  const int tid = threadIdx.x;
  const int wid = tid >> 6, lane = tid & 63;
  const int wr = wid >> 1, wc = wid & 1;
  const size_t mb = (size_t)k * NIND * NIND;
  const u16* Ag = A + mb + (size_t)i0 * NIND;
  const u16* Bg = B + mb + (size_t)j0 * NIND;
  f32x4 acc[4][4];
  #pragma unroll
  for (int m = 0; m < 4; ++m)
    #pragma unroll
    for (int n = 0; n < 4; ++n) acc[m][n] = (f32x4){0.f, 0.f, 0.f, 0.f};
  for (int kb = 0; kb < NIND; kb += 64) {
    #pragma unroll
    for (int c = 0; c < 4; ++c) {
      int f = c * 256 + tid;
      int row = f >> 3, s = f & 7;
      int sc = (s ^ (row & 7)) << 3;
      gload16(Ag + (size_t)row * NIND + kb + sc, Als + ((c * 256 + wid * 64) << 3));
      gload16(Bg + (size_t)row * NIND + kb + sc, Bls + ((c * 256 + wid * 64) << 3));
    }
    __syncthreads();
    #pragma unroll
    for (int ks = 0; ks < 2; ++ks) {
      bf16x8 af[4], bfr[4];
      #pragma unroll
      for (int m = 0; m < 4; ++m) {
        int row = wr * 64 + m * 16 + (lane & 15);
        int kq = ks * 32 + (lane >> 4) * 8;
        int idx = (row * 64 + kq) ^ ((row & 7) << 3);
        af[m] = *(const bf16x8*)(&Als[idx]);
      }
      #pragma unroll
      for (int n = 0; n < 4; ++n) {
        int row = wc * 64 + n * 16 + (lane & 15);
        int kq = ks * 32 + (lane >> 4) * 8;
        int idx = (row * 64 + kq) ^ ((row & 7) << 3);
        bfr[n] = *(const bf16x8*)(&Bls[idx]);
      }
      #pragma unroll
      for (int m = 0; m < 4; ++m)
        #pragma unroll
        for (int n = 0; n < 4; ++n)
          acc[m][n] = __builtin_amdgcn_mfma_f32_16x16x32_bf16(af[m], bfr[n], acc[m][n], 0, 0, 0);
    }
    __syncthreads();
  }
  #pragma unroll
  for (int m = 0; m < 4; ++m) {
    #pragma unroll
    for (int n = 0; n < 4; ++n) {
      #pragma unroll
      for (int r = 0; r < 4; ++r) {
        int gi = i0 + wr * 64 + m * 16 + (lane >> 4) * 4 + r;
        int gj = j0 + wc * 64 + n * 16 + (lane & 15);
        size_t idx = mb + (size_t)gi * NIND + gj;
        float v = acc[m][n][r];
        if (mode) v = 2.0f * bflo((unsigned)Xadd[idx]) - v;
        u16 bv = (u16)f2bf(v);
        C[idx] = bv;
        if (!diag) C[mb + (size_t)gj * NIND + gi] = bv;
      }
    }
  }
}

// K7: variance GEMM: C = phi (*) M^T; epilogue * phi[b][i], row-reduce -> partial
__global__ __launch_bounds__(256) void vgemm_kernel(
    const u16* __restrict__ phiB, const u16* __restrict__ M,
    float* __restrict__ partial)
{
  __shared__ u16 Als[128 * 64];
  __shared__ u16 Bls[128 * 64];
  __shared__ float red[128][33];
  const int btile = blockIdx.x >> 3, It = blockIdx.x & 7;
  const int k = blockIdx.y;
  const int b0 = btile * 128, i0 = It * 128;
  const int tid = threadIdx.x;
  const int wid = tid >> 6, lane = tid & 63;
  const int wr = wid >> 1, wc = wid & 1;
  const int q = lane >> 4, l15 = lane & 15;
  const u16* Ag = phiB + (size_t)b0 * NIND;
  const u16* Bg = M + (size_t)k * NIND * NIND + (size_t)i0 * NIND;
  f32x4 acc[4][4];
  #pragma unroll
  for (int m = 0; m < 4; ++m)
    #pragma unroll
    for (int n = 0; n < 4; ++n) acc[m][n] = (f32x4){0.f, 0.f, 0.f, 0.f};
  for (int kb = 0; kb < NIND; kb += 64) {
    #pragma unroll
    for (int c = 0; c < 4; ++c) {
      int f = c * 256 + tid;
      int row = f >> 3, s = f & 7;
      int sc = (s ^ (row & 7)) << 3;
      gload16(Ag + (size_t)row * NIND + kb + sc, Als + ((c * 256 + wid * 64) << 3));
      gload16(Bg + (size_t)row * NIND + kb + sc, Bls + ((c * 256 + wid * 64) << 3));
    }
    __syncthreads();
    #pragma unroll
    for (int ks = 0; ks < 2; ++ks) {
      bf16x8 af[4], bfr[4];
      #pragma unroll
      for (int m = 0; m < 4; ++m) {
        int row = wr * 64 + m * 16 + l15;
        int kq = ks * 32 + q * 8;
        int idx = (row * 64 + kq) ^ ((row & 7) << 3);
        af[m] = *(const bf16x8*)(&Als[idx]);
      }
      #pragma unroll
      for (int n = 0; n < 4; ++n) {
        int row = wc * 64 + n * 16 + l15;
        int kq = ks * 32 + q * 8;
        int idx = (row * 64 + kq) ^ ((row & 7) << 3);
        bfr[n] = *(const bf16x8*)(&Bls[idx]);
      }
      #pragma unroll
      for (int m = 0; m < 4; ++m)
        #pragma unroll
        for (int n = 0; n < 4; ++n)
          acc[m][n] = __builtin_amdgcn_mfma_f32_16x16x32_bf16(af[m], bfr[n], acc[m][n], 0, 0, 0);
    }
    __syncthreads();
  }
  float vs[4][4] = {};
  #pragma unroll
  for (int m = 0; m < 4; ++m) {
    #pragma unroll
    for (int r = 0; r < 4; ++r) {
      int gb = b0 + wr * 64 + m * 16 + q * 4 + r;
      #pragma unroll
      for (int n = 0; n < 4; ++n) {
        int gi = i0 + wc * 64 + n * 16 + l15;
        float pv = bflo((unsigned)phiB[(size_t)gb * NIND + gi]);
        vs[m][r] += acc[m][n][r] * pv;
      }
    }
  }
  #pragma unroll
  for (int m = 0; m < 4; ++m)
    #pragma unroll
    for (int r = 0; r < 4; ++r)
      red[wr * 64 + m * 16 + q * 4 + r][wc * 16 + l15] = vs[m][r];
  __syncthreads();
  if (tid < 128) {
    float s = 0.f;
    #pragma unroll
    for (int t = 0; t < 32; ++t) s += red[tid][t];
    partial[((size_t)It * NCLS + k) * BATCH + b0 + tid] = s;
  }
}

// K8: out variances[b][k] = sum_It partial[It][k][b]
__global__ __launch_bounds__(256) void reduce_kernel(
    const float* __restrict__ partial, float* __restrict__ out)
{
  int t = blockIdx.x * 256 + threadIdx.x;
  int k = t >> 11, b = t & 2047;
  float s = 0.f;
  #pragma unroll
  for (int It = 0; It < 8; ++It)
    s += partial[((size_t)It * NCLS + k) * BATCH + b];
  out[(size_t)BATCH * NCLS + (size_t)b * NCLS + k] = s;
}

extern "C" void kernel_launch(void* const* d_in, const int* in_sizes, int n_in,
                              void* d_out, int out_size, void* d_ws, size_t ws_size,
                              hipStream_t stream)
{
  (void)in_sizes; (void)n_in; (void)ws_size;
  const float* x   = (const float*)d_in[0];
  const float* rw  = (const float*)d_in[1];
  const float* rb  = (const float*)d_in[2];
  const float* bw  = (const float*)d_in[3];
  const float* bb  = (const float*)d_in[4];
  const float* prc = (const float*)d_in[5];
  float* out = (float*)d_out;
  char* ws = (char*)d_ws;
  size_t off = 0;
  auto alloc = [&](size_t bytes) -> void* {
    void* p = ws + off;
    off = (off + bytes + 255) & ~(size_t)255;
    return p;
  };
  const size_t MSZ = (size_t)NCLS * NIND * NIND * 2;   // 32MB bf16 matrix
  float* phi    = (float*)alloc((size_t)BATCH * NIND * 4);
  u16*   phiB   = (u16*)  alloc((size_t)BATCH * NIND * 2);
  u16*   phiTB  = (u16*)  alloc((size_t)NIND * BATCH * 2);
  float* wmat   = (float*)alloc((size_t)NCLS * BATCH * 4);
  u16*   Pb     = (u16*)  alloc(MSZ);
  unsigned* gbound = (unsigned*)alloc((size_t)NCLS * 4);
  float* partial = (float*)alloc((size_t)8 * NCLS * BATCH * 4);
  u16*   Xa     = (u16*)alloc(MSZ);
  u16*   B2     = (u16*)alloc(MSZ);
  u16*   BY     = (u16*)alloc(MSZ);

  hipMemsetAsync(d_out, 0, (size_t)out_size * sizeof(float), stream);
  hipMemsetAsync(gbound, 0, (size_t)NCLS * 4, stream);
  phi_kernel<<<dim3(BATCH/64, NIND/64), 256, 0, stream>>>(x, rw, rb, phi, phiB, phiTB);
  logits_kernel<<<dim3(BATCH/64), 256, 0, stream>>>(phi, bw, bb, out, wmat);
  gram_kernel<<<dim3(36, NCLS), 256, 0, stream>>>(phiTB, wmat, prc, Pb);
  gersh_kernel<<<dim3(16, NCLS), 256, 0, stream>>>(Pb, gbound);
  xinit_kernel<<<dim3(512, NCLS), 256, 0, stream>>>(Pb, gbound, Xa);
  const dim3 gg(36, NCLS);
  // 4 Newton iterations, all outputs symmetric (X polynomial in P):
  // BY = X*P ; X' = 2X - X*BY^T  — 36 lower tile-pairs each, mirrored.
  ntgemm_kernel<<<gg, 256, 0, stream>>>(Xa, Pb, (u16*)nullptr, BY, 0);
  ntgemm_kernel<<<gg, 256, 0, stream>>>(Xa, BY, Xa, B2, 1);
  ntgemm_kernel<<<gg, 256, 0, stream>>>(B2, Pb, (u16*)nullptr, BY, 0);
  ntgemm_kernel<<<gg, 256, 0, stream>>>(B2, BY, B2, Xa, 1);
  ntgemm_kernel<<<gg, 256, 0, stream>>>(Xa, Pb, (u16*)nullptr, BY, 0);
  ntgemm_kernel<<<gg, 256, 0, stream>>>(Xa, BY, Xa, B2, 1);
  ntgemm_kernel<<<gg, 256, 0, stream>>>(B2, Pb, (u16*)nullptr, BY, 0);
  ntgemm_kernel<<<gg, 256, 0, stream>>>(B2, BY, B2, Xa, 1);
  // variances: var_b = phi^T M phi, M = Xa
  vgemm_kernel<<<dim3(128, NCLS), 256, 0, stream>>>(phiB, Xa, partial);
  reduce_kernel<<<dim3(128), 256, 0, stream>>>(partial, out);
}

// Round 12
// 846.573 us; speedup vs baseline: 1.1659x; 1.1659x over previous
//
#include <hip/hip_runtime.h>
#include <hip/hip_bf16.h>

#define BATCH 2048
#define FEAT  768
#define NIND  1024
#define NCLS  16

typedef unsigned short u16;
typedef __attribute__((ext_vector_type(8))) __bf16 bf16x8;
typedef __attribute__((ext_vector_type(4))) float f32x4;

static __device__ __forceinline__ unsigned f2bf(float f) {
  unsigned u = __float_as_uint(f);
  unsigned r = ((u >> 16) & 1u) + 0x7FFFu;
  return (u + r) >> 16;                       // RNE bf16 in low 16 bits
}
static __device__ __forceinline__ float bflo(unsigned x) {
  return __uint_as_float((x & 0xFFFFu) << 16);
}
static __device__ __forceinline__ float bfhi(unsigned x) {
  return __uint_as_float(x & 0xFFFF0000u);
}

// async 16B global->LDS (LDS dest = wave-uniform base + lane*16)
static __device__ __forceinline__ void gload16(const u16* g, u16* l) {
  __builtin_amdgcn_global_load_lds(
      (const __attribute__((address_space(1))) void*)g,
      (__attribute__((address_space(3))) void*)l, 16, 0, 0);
}

// pack 8 bf16 (as uint4) scaled by wv[0..7] back to 8 bf16 (uint4)
static __device__ __forceinline__ uint4 scale8(uint4 v, const float* wv) {
  unsigned out[4];
  const unsigned* in = (const unsigned*)&v;
  #pragma unroll
  for (int i = 0; i < 4; ++i) {
    float lo = bflo(in[i]) * wv[2*i];
    float hi = bfhi(in[i]) * wv[2*i+1];
    __hip_bfloat162 pk = __float22bfloat162_rn(float2{lo, hi});
    out[i] = *(unsigned*)&pk;
  }
  return uint4{out[0], out[1], out[2], out[3]};
}

// K1: phi = sqrt(2/N)*cos(2*(x@W+b)); writes phi [B][N] f32, phiB [B][N] bf16, phiTB [N][B] bf16
__global__ __launch_bounds__(256) void phi_kernel(
    const float* __restrict__ x, const float* __restrict__ rw,
    const float* __restrict__ rb, float* __restrict__ phi,
    u16* __restrict__ phiB, u16* __restrict__ phiTB)
{
  __shared__ float xs[64][17];
  __shared__ float wsh[16][68];
  __shared__ float ts[64][65];
  const int b0 = blockIdx.x * 64, i0 = blockIdx.y * 64;
  const int tid = threadIdx.x;
  const int tr = tid >> 4, tc = tid & 15;
  float acc[4][4] = {};
  for (int k0 = 0; k0 < FEAT; k0 += 16) {
    {
      int bb = tid >> 2, kk = (tid & 3) << 2;
      float4 v = *(const float4*)(x + (size_t)(b0 + bb) * FEAT + k0 + kk);
      xs[bb][kk] = v.x; xs[bb][kk+1] = v.y; xs[bb][kk+2] = v.z; xs[bb][kk+3] = v.w;
      int k2 = tid >> 4, ii = (tid & 15) << 2;
      *(float4*)(&wsh[k2][ii]) = *(const float4*)(rw + (size_t)(k0 + k2) * NIND + i0 + ii);
    }
    __syncthreads();
    #pragma unroll
    for (int q = 0; q < 16; ++q) {
      float a[4];
      #pragma unroll
      for (int r = 0; r < 4; ++r) a[r] = xs[tr*4+r][q];
      float4 b4 = *(const float4*)(&wsh[q][tc*4]);
      float bv[4] = {b4.x, b4.y, b4.z, b4.w};
      #pragma unroll
      for (int r = 0; r < 4; ++r)
        #pragma unroll
        for (int c = 0; c < 4; ++c) acc[r][c] += a[r] * bv[c];
    }
    __syncthreads();
  }
  const float SC = 0.04419417382415922f;   // sqrt(2/1024)
  float4 rb4 = *(const float4*)(rb + i0 + tc*4);
  float rbl[4] = {rb4.x, rb4.y, rb4.z, rb4.w};
  #pragma unroll
  for (int r = 0; r < 4; ++r) {
    float vals[4];
    #pragma unroll
    for (int c = 0; c < 4; ++c) {
      float pr = 2.0f * (acc[r][c] + rbl[c]);
      vals[c] = SC * cosf(pr);
      ts[tr*4+r][tc*4+c] = vals[c];
    }
    float4 o = make_float4(vals[0], vals[1], vals[2], vals[3]);
    *(float4*)(phi + (size_t)(b0 + tr*4 + r) * NIND + i0 + tc*4) = o;
    uint2 ob;
    ob.x = (f2bf(o.x) & 0xFFFFu) | (f2bf(o.y) << 16);
    ob.y = (f2bf(o.z) & 0xFFFFu) | (f2bf(o.w) << 16);
    *(uint2*)(phiB + (size_t)(b0 + tr*4 + r) * NIND + i0 + tc*4) = ob;
  }
  __syncthreads();
  #pragma unroll
  for (int rep = 0; rep < 4; ++rep) {
    int ii = tr*4 + rep;
    int bb2 = tc*4;
    float4 o = make_float4(ts[bb2][ii], ts[bb2+1][ii], ts[bb2+2][ii], ts[bb2+3][ii]);
    uint2 ob;
    ob.x = (f2bf(o.x) & 0xFFFFu) | (f2bf(o.y) << 16);
    ob.y = (f2bf(o.z) & 0xFFFFu) | (f2bf(o.w) << 16);
    *(uint2*)(phiTB + (size_t)(i0 + ii) * BATCH + b0 + bb2) = ob;
  }
}

// K2: tiled logits GEMM + in-block softmax -> wmat[k][b] = p(1-p)
__global__ __launch_bounds__(256) void logits_kernel(
    const float* __restrict__ phi, const float* __restrict__ bw,
    const float* __restrict__ bbias, float* __restrict__ out,
    float* __restrict__ wmat)
{
  __shared__ float ph[64][132];
  __shared__ float bwl[16][132];
  __shared__ float lg[64][17];
  const int b0 = blockIdx.x * 64;
  const int tid = threadIdx.x;
  const int bl = tid & 63, kq = tid >> 6;
  float acc[4] = {};
  for (int kb = 0; kb < NIND; kb += 128) {
    #pragma unroll
    for (int i = 0; i < 8; ++i) {
      int f = i * 256 + tid;
      int row = f >> 5, c4 = (f & 31) << 2;
      *(float4*)(&ph[row][c4]) = *(const float4*)(phi + (size_t)(b0 + row) * NIND + kb + c4);
    }
    #pragma unroll
    for (int i = 0; i < 2; ++i) {
      int f = i * 256 + tid;
      int row = f >> 5, c4 = (f & 31) << 2;
      *(float4*)(&bwl[row][c4]) = *(const float4*)(bw + (size_t)row * NIND + kb + c4);
    }
    __syncthreads();
    #pragma unroll 8
    for (int q = 0; q < 128; q += 4) {
      float4 a = *(const float4*)(&ph[bl][q]);
      #pragma unroll
      for (int j = 0; j < 4; ++j) {
        float4 b4 = *(const float4*)(&bwl[kq*4+j][q]);
        acc[j] += a.x*b4.x + a.y*b4.y + a.z*b4.z + a.w*b4.w;
      }
    }
    __syncthreads();
  }
  #pragma unroll
  for (int j = 0; j < 4; ++j) {
    float v = acc[j] + bbias[kq*4+j];
    lg[bl][kq*4+j] = v;
    out[(size_t)(b0 + bl) * NCLS + kq*4 + j] = v;
  }
  __syncthreads();
  if (tid < 64) {
    float mx = -1e30f;
    #pragma unroll
    for (int k = 0; k < 16; ++k) mx = fmaxf(mx, lg[tid][k]);
    float s = 0.f, ex[16];
    #pragma unroll
    for (int k = 0; k < 16; ++k) { ex[k] = expf(lg[tid][k] - mx); s += ex[k]; }
    float inv = 1.0f / s;
    #pragma unroll
    for (int k = 0; k < 16; ++k) {
      float p = ex[k] * inv;
      wmat[(size_t)k * BATCH + b0 + tid] = p * (1.0f - p);
    }
  }
}

// K3: MFMA bf16 gram -> Pb bf16. A = (w*phi) via reg-staging; B = raw phi via gload_lds.
__global__ __launch_bounds__(256) void gram_kernel(
    const u16* __restrict__ phiTB, const float* __restrict__ wmat,
    const float* __restrict__ prec, u16* __restrict__ Pb)
{
  __shared__ u16 Als[128 * 64];
  __shared__ u16 Bls[128 * 64];
  int p = blockIdx.x;
  int ti = 0;
  while ((ti + 1) * (ti + 2) / 2 <= p) ++ti;
  int tj = p - ti * (ti + 1) / 2;
  const int k = blockIdx.y;
  const int i0 = ti * 128, j0 = tj * 128;
  const bool diag = (ti == tj);
  const int tid = threadIdx.x;
  const int wid = tid >> 6, lane = tid & 63;
  const int wr = wid >> 1, wc = wid & 1;
  const u16* Ag = phiTB + (size_t)i0 * BATCH;
  const u16* Bg = phiTB + (size_t)j0 * BATCH;
  const float* sw = wmat + (size_t)k * BATCH;
  f32x4 acc[4][4];
  #pragma unroll
  for (int m = 0; m < 4; ++m)
    #pragma unroll
    for (int n = 0; n < 4; ++n) acc[m][n] = (f32x4){0.f, 0.f, 0.f, 0.f};
  const int kc8 = tid & 7;
  for (int b0 = 0; b0 < BATCH; b0 += 64) {
    #pragma unroll
    for (int c = 0; c < 4; ++c) {
      int f = c * 256 + tid;
      int row = f >> 3, s = f & 7;
      int sc = (s ^ (row & 7)) << 3;
      gload16(Bg + (size_t)row * BATCH + b0 + sc, Bls + ((c * 256 + wid * 64) << 3));
    }
    const int bcol = b0 + kc8 * 8;
    float4 w0 = *(const float4*)(sw + bcol);
    float4 w1 = *(const float4*)(sw + bcol + 4);
    float wv[8] = {w0.x, w0.y, w0.z, w0.w, w1.x, w1.y, w1.z, w1.w};
    #pragma unroll
    for (int c = 0; c < 4; ++c) {
      int row = c * 32 + (tid >> 3);
      int idx = (row * 64 + kc8 * 8) ^ ((row & 7) << 3);
      uint4 va = *(const uint4*)(Ag + (size_t)row * BATCH + bcol);
      *(uint4*)(&Als[idx]) = scale8(va, wv);
    }
    __syncthreads();
    #pragma unroll
    for (int ks = 0; ks < 2; ++ks) {
      bf16x8 af[4], bfr[4];
      #pragma unroll
      for (int m = 0; m < 4; ++m) {
        int row = wr * 64 + m * 16 + (lane & 15);
        int kb = ks * 32 + (lane >> 4) * 8;
        int idx = (row * 64 + kb) ^ ((row & 7) << 3);
        af[m] = *(const bf16x8*)(&Als[idx]);
      }
      #pragma unroll
      for (int n = 0; n < 4; ++n) {
        int row = wc * 64 + n * 16 + (lane & 15);
        int kb = ks * 32 + (lane >> 4) * 8;
        int idx = (row * 64 + kb) ^ ((row & 7) << 3);
        bfr[n] = *(const bf16x8*)(&Bls[idx]);
      }
      #pragma unroll
      for (int m = 0; m < 4; ++m)
        #pragma unroll
        for (int n = 0; n < 4; ++n)
          acc[m][n] = __builtin_amdgcn_mfma_f32_16x16x32_bf16(af[m], bfr[n], acc[m][n], 0, 0, 0);
    }
    __syncthreads();
  }
  const size_t kb2 = (size_t)k * NIND * NIND;
  #pragma unroll
  for (int m = 0; m < 4; ++m) {
    #pragma unroll
    for (int n = 0; n < 4; ++n) {
      #pragma unroll
      for (int r = 0; r < 4; ++r) {
        int gi = i0 + wr * 64 + m * 16 + (lane >> 4) * 4 + r;
        int gj = j0 + wc * 64 + n * 16 + (lane & 15);
        size_t idx = kb2 + (size_t)gi * NIND + gj;
        float v = acc[m][n][r] + prec[idx];
        u16 bv = (u16)f2bf(v);
        Pb[idx] = bv;
        if (!diag) Pb[kb2 + (size_t)gj * NIND + gi] = bv;
      }
    }
  }
}

// K4: Gershgorin bound per class: gmax[k] = max_i sum_j |P_ij| (certified >= lambda_max)
__global__ __launch_bounds__(256) void gersh_kernel(
    const u16* __restrict__ Pb, unsigned* __restrict__ gmax)
{
  __shared__ float psum[64][17];
  const int k = blockIdx.y, rbk = blockIdx.x;
  const int tid = threadIdx.x;
  const size_t mb = (size_t)k * NIND * NIND;
  #pragma unroll
  for (int p = 0; p < 4; ++p) {
    int rl = p * 16 + (tid >> 4);
    int row = rbk * 64 + rl;
    int ch = tid & 15;
    float s = 0.f;
    const u16* base = Pb + mb + (size_t)row * NIND + ch * 64;
    #pragma unroll
    for (int c8 = 0; c8 < 8; ++c8) {
      uint4 u = *(const uint4*)(base + c8 * 8);
      const unsigned* uu = (const unsigned*)&u;
      #pragma unroll
      for (int q = 0; q < 4; ++q)
        s += fabsf(bflo(uu[q])) + fabsf(bfhi(uu[q]));
    }
    psum[rl][ch] = s;
  }
  __syncthreads();
  if (tid < 64) {
    float s = 0.f;
    #pragma unroll
    for (int j = 0; j < 16; ++j) s += psum[tid][j];
    psum[tid][16] = s;
  }
  __syncthreads();
  if (tid == 0) {
    float mx = 0.f;
    for (int t = 0; t < 64; ++t) mx = fmaxf(mx, psum[t][16]);
    atomicMax(gmax + k, __float_as_uint(mx));
  }
}

// K5: X1 = 2a*I - a^2 * Pb with a = 2/(1+G)
__global__ __launch_bounds__(256) void xinit_kernel(
    const u16* __restrict__ Pb, const unsigned* __restrict__ gmax, u16* __restrict__ X)
{
  const int k = blockIdx.y;
  float lb = __uint_as_float(gmax[k]) * 1.001f + 0.01f;
  if (lb < 1.05f) lb = 1.05f;
  float al = 2.0f / (1.0f + lb);
  float a2 = al * al, two_a = 2.0f * al;
  size_t flat = ((size_t)blockIdx.x * 256 + threadIdx.x) * 8;
  int i = (int)(flat >> 10), j0 = (int)(flat & 1023);
  const size_t mb = (size_t)k * NIND * NIND;
  uint4 u = *(const uint4*)(Pb + mb + flat);
  const unsigned* uu = (const unsigned*)&u;
  unsigned ow[4];
  #pragma unroll
  for (int q = 0; q < 4; ++q) {
    float lo = -a2 * bflo(uu[q]);
    float hi = -a2 * bfhi(uu[q]);
    int cj = j0 + 2 * q;
    if (i == cj) lo += two_a;
    if (i == cj + 1) hi += two_a;
    ow[q] = (f2bf(lo) & 0xFFFFu) | (f2bf(hi) << 16);
  }
  *(uint4*)(X + mb + flat) = uint4{ow[0], ow[1], ow[2], ow[3]};
}

// K6: C = A (*) B^T; mode 1: C = 2*Xadd - A(*)B^T. Full 64 tiles (coalesced writes).
// XCD-aware tile map: linear id = bx + 64*k, 64%8==0 -> XCD = bx%8. ti = bx&7 makes
// each XCD own one ti-row per class: its A row-panel stays L2-resident across all tj.
__global__ __launch_bounds__(256) void ntgemm_kernel(
    const u16* __restrict__ A, const u16* __restrict__ B,
    const u16* __restrict__ Xadd, u16* __restrict__ C, int mode)
{
  __shared__ u16 Als[128 * 64];
  __shared__ u16 Bls[128 * 64];
  const int k = blockIdx.y;
  const int ti = blockIdx.x & 7, tj = blockIdx.x >> 3;   // XCD swizzle (T1)
  const int i0 = ti * 128, j0 = tj * 128;
  const int tid = threadIdx.x;
  const int wid = tid >> 6, lane = tid & 63;
  const int wr = wid >> 1, wc = wid & 1;
  const size_t mb = (size_t)k * NIND * NIND;
  const u16* Ag = A + mb + (size_t)i0 * NIND;
  const u16* Bg = B + mb + (size_t)j0 * NIND;
  f32x4 acc[4][4];
  #pragma unroll
  for (int m = 0; m < 4; ++m)
    #pragma unroll
    for (int n = 0; n < 4; ++n) acc[m][n] = (f32x4){0.f, 0.f, 0.f, 0.f};
  for (int kb = 0; kb < NIND; kb += 64) {
    #pragma unroll
    for (int c = 0; c < 4; ++c) {
      int f = c * 256 + tid;
      int row = f >> 3, s = f & 7;
      int sc = (s ^ (row & 7)) << 3;
      gload16(Ag + (size_t)row * NIND + kb + sc, Als + ((c * 256 + wid * 64) << 3));
      gload16(Bg + (size_t)row * NIND + kb + sc, Bls + ((c * 256 + wid * 64) << 3));
    }
    __syncthreads();
    #pragma unroll
    for (int ks = 0; ks < 2; ++ks) {
      bf16x8 af[4], bfr[4];
      #pragma unroll
      for (int m = 0; m < 4; ++m) {
        int row = wr * 64 + m * 16 + (lane & 15);
        int kq = ks * 32 + (lane >> 4) * 8;
        int idx = (row * 64 + kq) ^ ((row & 7) << 3);
        af[m] = *(const bf16x8*)(&Als[idx]);
      }
      #pragma unroll
      for (int n = 0; n < 4; ++n) {
        int row = wc * 64 + n * 16 + (lane & 15);
        int kq = ks * 32 + (lane >> 4) * 8;
        int idx = (row * 64 + kq) ^ ((row & 7) << 3);
        bfr[n] = *(const bf16x8*)(&Bls[idx]);
      }
      #pragma unroll
      for (int m = 0; m < 4; ++m)
        #pragma unroll
        for (int n = 0; n < 4; ++n)
          acc[m][n] = __builtin_amdgcn_mfma_f32_16x16x32_bf16(af[m], bfr[n], acc[m][n], 0, 0, 0);
    }
    __syncthreads();
  }
  #pragma unroll
  for (int m = 0; m < 4; ++m) {
    #pragma unroll
    for (int n = 0; n < 4; ++n) {
      #pragma unroll
      for (int r = 0; r < 4; ++r) {
        int gi = i0 + wr * 64 + m * 16 + (lane >> 4) * 4 + r;
        int gj = j0 + wc * 64 + n * 16 + (lane & 15);
        size_t idx = mb + (size_t)gi * NIND + gj;
        float v = acc[m][n][r];
        if (mode) v = 2.0f * bflo((unsigned)Xadd[idx]) - v;
        C[idx] = (u16)f2bf(v);
      }
    }
  }
}

// K7: variance GEMM: C = phi (*) M^T; epilogue * phi[b][i], row-reduce -> partial
__global__ __launch_bounds__(256) void vgemm_kernel(
    const u16* __restrict__ phiB, const u16* __restrict__ M,
    float* __restrict__ partial)
{
  __shared__ u16 Als[128 * 64];
  __shared__ u16 Bls[128 * 64];
  __shared__ float red[128][33];
  const int btile = blockIdx.x >> 3, It = blockIdx.x & 7;
  const int k = blockIdx.y;
  const int b0 = btile * 128, i0 = It * 128;
  const int tid = threadIdx.x;
  const int wid = tid >> 6, lane = tid & 63;
  const int wr = wid >> 1, wc = wid & 1;
  const int q = lane >> 4, l15 = lane & 15;
  const u16* Ag = phiB + (size_t)b0 * NIND;
  const u16* Bg = M + (size_t)k * NIND * NIND + (size_t)i0 * NIND;
  f32x4 acc[4][4];
  #pragma unroll
  for (int m = 0; m < 4; ++m)
    #pragma unroll
    for (int n = 0; n < 4; ++n) acc[m][n] = (f32x4){0.f, 0.f, 0.f, 0.f};
  for (int kb = 0; kb < NIND; kb += 64) {
    #pragma unroll
    for (int c = 0; c < 4; ++c) {
      int f = c * 256 + tid;
      int row = f >> 3, s = f & 7;
      int sc = (s ^ (row & 7)) << 3;
      gload16(Ag + (size_t)row * NIND + kb + sc, Als + ((c * 256 + wid * 64) << 3));
      gload16(Bg + (size_t)row * NIND + kb + sc, Bls + ((c * 256 + wid * 64) << 3));
    }
    __syncthreads();
    #pragma unroll
    for (int ks = 0; ks < 2; ++ks) {
      bf16x8 af[4], bfr[4];
      #pragma unroll
      for (int m = 0; m < 4; ++m) {
        int row = wr * 64 + m * 16 + l15;
        int kq = ks * 32 + q * 8;
        int idx = (row * 64 + kq) ^ ((row & 7) << 3);
        af[m] = *(const bf16x8*)(&Als[idx]);
      }
      #pragma unroll
      for (int n = 0; n < 4; ++n) {
        int row = wc * 64 + n * 16 + l15;
        int kq = ks * 32 + q * 8;
        int idx = (row * 64 + kq) ^ ((row & 7) << 3);
        bfr[n] = *(const bf16x8*)(&Bls[idx]);
      }
      #pragma unroll
      for (int m = 0; m < 4; ++m)
        #pragma unroll
        for (int n = 0; n < 4; ++n)
          acc[m][n] = __builtin_amdgcn_mfma_f32_16x16x32_bf16(af[m], bfr[n], acc[m][n], 0, 0, 0);
    }
    __syncthreads();
  }
  float vs[4][4] = {};
  #pragma unroll
  for (int m = 0; m < 4; ++m) {
    #pragma unroll
    for (int r = 0; r < 4; ++r) {
      int gb = b0 + wr * 64 + m * 16 + q * 4 + r;
      #pragma unroll
      for (int n = 0; n < 4; ++n) {
        int gi = i0 + wc * 64 + n * 16 + l15;
        float pv = bflo((unsigned)phiB[(size_t)gb * NIND + gi]);
        vs[m][r] += acc[m][n][r] * pv;
      }
    }
  }
  #pragma unroll
  for (int m = 0; m < 4; ++m)
    #pragma unroll
    for (int r = 0; r < 4; ++r)
      red[wr * 64 + m * 16 + q * 4 + r][wc * 16 + l15] = vs[m][r];
  __syncthreads();
  if (tid < 128) {
    float s = 0.f;
    #pragma unroll
    for (int t = 0; t < 32; ++t) s += red[tid][t];
    partial[((size_t)It * NCLS + k) * BATCH + b0 + tid] = s;
  }
}

// K8: out variances[b][k] = sum_It partial[It][k][b]
__global__ __launch_bounds__(256) void reduce_kernel(
    const float* __restrict__ partial, float* __restrict__ out)
{
  int t = blockIdx.x * 256 + threadIdx.x;
  int k = t >> 11, b = t & 2047;
  float s = 0.f;
  #pragma unroll
  for (int It = 0; It < 8; ++It)
    s += partial[((size_t)It * NCLS + k) * BATCH + b];
  out[(size_t)BATCH * NCLS + (size_t)b * NCLS + k] = s;
}

extern "C" void kernel_launch(void* const* d_in, const int* in_sizes, int n_in,
                              void* d_out, int out_size, void* d_ws, size_t ws_size,
                              hipStream_t stream)
{
  (void)in_sizes; (void)n_in; (void)ws_size;
  const float* x   = (const float*)d_in[0];
  const float* rw  = (const float*)d_in[1];
  const float* rb  = (const float*)d_in[2];
  const float* bw  = (const float*)d_in[3];
  const float* bb  = (const float*)d_in[4];
  const float* prc = (const float*)d_in[5];
  float* out = (float*)d_out;
  char* ws = (char*)d_ws;
  size_t off = 0;
  auto alloc = [&](size_t bytes) -> void* {
    void* p = ws + off;
    off = (off + bytes + 255) & ~(size_t)255;
    return p;
  };
  const size_t MSZ = (size_t)NCLS * NIND * NIND * 2;   // 32MB bf16 matrix
  float* phi    = (float*)alloc((size_t)BATCH * NIND * 4);
  u16*   phiB   = (u16*)  alloc((size_t)BATCH * NIND * 2);
  u16*   phiTB  = (u16*)  alloc((size_t)NIND * BATCH * 2);
  float* wmat   = (float*)alloc((size_t)NCLS * BATCH * 4);
  u16*   Pb     = (u16*)  alloc(MSZ);
  unsigned* gbound = (unsigned*)alloc((size_t)NCLS * 4);
  float* partial = (float*)alloc((size_t)8 * NCLS * BATCH * 4);
  u16*   Xa     = (u16*)alloc(MSZ);
  u16*   B2     = (u16*)alloc(MSZ);
  u16*   BY     = (u16*)alloc(MSZ);

  hipMemsetAsync(d_out, 0, (size_t)out_size * sizeof(float), stream);
  hipMemsetAsync(gbound, 0, (size_t)NCLS * 4, stream);
  phi_kernel<<<dim3(BATCH/64, NIND/64), 256, 0, stream>>>(x, rw, rb, phi, phiB, phiTB);
  logits_kernel<<<dim3(BATCH/64), 256, 0, stream>>>(phi, bw, bb, out, wmat);
  gram_kernel<<<dim3(36, NCLS), 256, 0, stream>>>(phiTB, wmat, prc, Pb);
  gersh_kernel<<<dim3(16, NCLS), 256, 0, stream>>>(Pb, gbound);
  xinit_kernel<<<dim3(512, NCLS), 256, 0, stream>>>(Pb, gbound, Xa);
  const dim3 gg(64, NCLS);
  // 4 Newton iterations (X symmetric): YT = X*P ; X' = 2X - X*YT^T
  ntgemm_kernel<<<gg, 256, 0, stream>>>(Xa, Pb, (u16*)nullptr, BY, 0);
  ntgemm_kernel<<<gg, 256, 0, stream>>>(Xa, BY, Xa, B2, 1);
  ntgemm_kernel<<<gg, 256, 0, stream>>>(B2, Pb, (u16*)nullptr, BY, 0);
  ntgemm_kernel<<<gg, 256, 0, stream>>>(B2, BY, B2, Xa, 1);
  ntgemm_kernel<<<gg, 256, 0, stream>>>(Xa, Pb, (u16*)nullptr, BY, 0);
  ntgemm_kernel<<<gg, 256, 0, stream>>>(Xa, BY, Xa, B2, 1);
  ntgemm_kernel<<<gg, 256, 0, stream>>>(B2, Pb, (u16*)nullptr, BY, 0);
  ntgemm_kernel<<<gg, 256, 0, stream>>>(B2, BY, B2, Xa, 1);
  // variances: var_b = phi^T M phi, M = Xa
  vgemm_kernel<<<dim3(128, NCLS), 256, 0, stream>>>(phiB, Xa, partial);
  reduce_kernel<<<dim3(128), 256, 0, stream>>>(partial, out);
}

// Round 13
// 708.061 us; speedup vs baseline: 1.3940x; 1.1956x over previous
//
#include <hip/hip_runtime.h>
#include <hip/hip_bf16.h>

#define BATCH 2048
#define FEAT  768
#define NIND  1024
#define NCLS  16

typedef unsigned short u16;
typedef __attribute__((ext_vector_type(8))) __bf16 bf16x8;
typedef __attribute__((ext_vector_type(4))) float f32x4;

static __device__ __forceinline__ unsigned f2bf(float f) {
  unsigned u = __float_as_uint(f);
  unsigned r = ((u >> 16) & 1u) + 0x7FFFu;
  return (u + r) >> 16;                       // RNE bf16 in low 16 bits
}
static __device__ __forceinline__ float bflo(unsigned x) {
  return __uint_as_float((x & 0xFFFFu) << 16);
}
static __device__ __forceinline__ float bfhi(unsigned x) {
  return __uint_as_float(x & 0xFFFF0000u);
}

// async 16B global->LDS (LDS dest = wave-uniform base + lane*16)
static __device__ __forceinline__ void gload16(const u16* g, u16* l) {
  __builtin_amdgcn_global_load_lds(
      (const __attribute__((address_space(1))) void*)g,
      (__attribute__((address_space(3))) void*)l, 16, 0, 0);
}

// pack 8 bf16 (as uint4) scaled by wv[0..7] back to 8 bf16 (uint4)
static __device__ __forceinline__ uint4 scale8(uint4 v, const float* wv) {
  unsigned out[4];
  const unsigned* in = (const unsigned*)&v;
  #pragma unroll
  for (int i = 0; i < 4; ++i) {
    float lo = bflo(in[i]) * wv[2*i];
    float hi = bfhi(in[i]) * wv[2*i+1];
    __hip_bfloat162 pk = __float22bfloat162_rn(float2{lo, hi});
    out[i] = *(unsigned*)&pk;
  }
  return uint4{out[0], out[1], out[2], out[3]};
}

// K1: phi = sqrt(2/N)*cos(2*(x@W+b)); writes phi [B][N] f32, phiB [B][N] bf16, phiTB [N][B] bf16
__global__ __launch_bounds__(256) void phi_kernel(
    const float* __restrict__ x, const float* __restrict__ rw,
    const float* __restrict__ rb, float* __restrict__ phi,
    u16* __restrict__ phiB, u16* __restrict__ phiTB)
{
  __shared__ float xs[64][17];
  __shared__ float wsh[16][68];
  __shared__ float ts[64][65];
  const int b0 = blockIdx.x * 64, i0 = blockIdx.y * 64;
  const int tid = threadIdx.x;
  const int tr = tid >> 4, tc = tid & 15;
  float acc[4][4] = {};
  for (int k0 = 0; k0 < FEAT; k0 += 16) {
    {
      int bb = tid >> 2, kk = (tid & 3) << 2;
      float4 v = *(const float4*)(x + (size_t)(b0 + bb) * FEAT + k0 + kk);
      xs[bb][kk] = v.x; xs[bb][kk+1] = v.y; xs[bb][kk+2] = v.z; xs[bb][kk+3] = v.w;
      int k2 = tid >> 4, ii = (tid & 15) << 2;
      *(float4*)(&wsh[k2][ii]) = *(const float4*)(rw + (size_t)(k0 + k2) * NIND + i0 + ii);
    }
    __syncthreads();
    #pragma unroll
    for (int q = 0; q < 16; ++q) {
      float a[4];
      #pragma unroll
      for (int r = 0; r < 4; ++r) a[r] = xs[tr*4+r][q];
      float4 b4 = *(const float4*)(&wsh[q][tc*4]);
      float bv[4] = {b4.x, b4.y, b4.z, b4.w};
      #pragma unroll
      for (int r = 0; r < 4; ++r)
        #pragma unroll
        for (int c = 0; c < 4; ++c) acc[r][c] += a[r] * bv[c];
    }
    __syncthreads();
  }
  const float SC = 0.04419417382415922f;   // sqrt(2/1024)
  float4 rb4 = *(const float4*)(rb + i0 + tc*4);
  float rbl[4] = {rb4.x, rb4.y, rb4.z, rb4.w};
  #pragma unroll
  for (int r = 0; r < 4; ++r) {
    float vals[4];
    #pragma unroll
    for (int c = 0; c < 4; ++c) {
      float pr = 2.0f * (acc[r][c] + rbl[c]);
      vals[c] = SC * cosf(pr);
      ts[tr*4+r][tc*4+c] = vals[c];
    }
    float4 o = make_float4(vals[0], vals[1], vals[2], vals[3]);
    *(float4*)(phi + (size_t)(b0 + tr*4 + r) * NIND + i0 + tc*4) = o;
    uint2 ob;
    ob.x = (f2bf(o.x) & 0xFFFFu) | (f2bf(o.y) << 16);
    ob.y = (f2bf(o.z) & 0xFFFFu) | (f2bf(o.w) << 16);
    *(uint2*)(phiB + (size_t)(b0 + tr*4 + r) * NIND + i0 + tc*4) = ob;
  }
  __syncthreads();
  #pragma unroll
  for (int rep = 0; rep < 4; ++rep) {
    int ii = tr*4 + rep;
    int bb2 = tc*4;
    float4 o = make_float4(ts[bb2][ii], ts[bb2+1][ii], ts[bb2+2][ii], ts[bb2+3][ii]);
    uint2 ob;
    ob.x = (f2bf(o.x) & 0xFFFFu) | (f2bf(o.y) << 16);
    ob.y = (f2bf(o.z) & 0xFFFFu) | (f2bf(o.w) << 16);
    *(uint2*)(phiTB + (size_t)(i0 + ii) * BATCH + b0 + bb2) = ob;
  }
}

// K2: tiled logits GEMM + in-block softmax -> wmat[k][b] = p(1-p)
__global__ __launch_bounds__(256) void logits_kernel(
    const float* __restrict__ phi, const float* __restrict__ bw,
    const float* __restrict__ bbias, float* __restrict__ out,
    float* __restrict__ wmat)
{
  __shared__ float ph[64][132];
  __shared__ float bwl[16][132];
  __shared__ float lg[64][17];
  const int b0 = blockIdx.x * 64;
  const int tid = threadIdx.x;
  const int bl = tid & 63, kq = tid >> 6;
  float acc[4] = {};
  for (int kb = 0; kb < NIND; kb += 128) {
    #pragma unroll
    for (int i = 0; i < 8; ++i) {
      int f = i * 256 + tid;
      int row = f >> 5, c4 = (f & 31) << 2;
      *(float4*)(&ph[row][c4]) = *(const float4*)(phi + (size_t)(b0 + row) * NIND + kb + c4);
    }
    #pragma unroll
    for (int i = 0; i < 2; ++i) {
      int f = i * 256 + tid;
      int row = f >> 5, c4 = (f & 31) << 2;
      *(float4*)(&bwl[row][c4]) = *(const float4*)(bw + (size_t)row * NIND + kb + c4);
    }
    __syncthreads();
    #pragma unroll 8
    for (int q = 0; q < 128; q += 4) {
      float4 a = *(const float4*)(&ph[bl][q]);
      #pragma unroll
      for (int j = 0; j < 4; ++j) {
        float4 b4 = *(const float4*)(&bwl[kq*4+j][q]);
        acc[j] += a.x*b4.x + a.y*b4.y + a.z*b4.z + a.w*b4.w;
      }
    }
    __syncthreads();
  }
  #pragma unroll
  for (int j = 0; j < 4; ++j) {
    float v = acc[j] + bbias[kq*4+j];
    lg[bl][kq*4+j] = v;
    out[(size_t)(b0 + bl) * NCLS + kq*4 + j] = v;
  }
  __syncthreads();
  if (tid < 64) {
    float mx = -1e30f;
    #pragma unroll
    for (int k = 0; k < 16; ++k) mx = fmaxf(mx, lg[tid][k]);
    float s = 0.f, ex[16];
    #pragma unroll
    for (int k = 0; k < 16; ++k) { ex[k] = expf(lg[tid][k] - mx); s += ex[k]; }
    float inv = 1.0f / s;
    #pragma unroll
    for (int k = 0; k < 16; ++k) {
      float p = ex[k] * inv;
      wmat[(size_t)k * BATCH + b0 + tid] = p * (1.0f - p);
    }
  }
}

// K3: MFMA bf16 gram -> Pb bf16. A = (w*phi) via reg-staging; B = raw phi via gload_lds.
__global__ __launch_bounds__(256) void gram_kernel(
    const u16* __restrict__ phiTB, const float* __restrict__ wmat,
    const float* __restrict__ prec, u16* __restrict__ Pb)
{
  __shared__ u16 Als[128 * 64];
  __shared__ u16 Bls[128 * 64];
  int p = blockIdx.x;
  int ti = 0;
  while ((ti + 1) * (ti + 2) / 2 <= p) ++ti;
  int tj = p - ti * (ti + 1) / 2;
  const int k = blockIdx.y;
  const int i0 = ti * 128, j0 = tj * 128;
  const bool diag = (ti == tj);
  const int tid = threadIdx.x;
  const int wid = tid >> 6, lane = tid & 63;
  const int wr = wid >> 1, wc = wid & 1;
  const u16* Ag = phiTB + (size_t)i0 * BATCH;
  const u16* Bg = phiTB + (size_t)j0 * BATCH;
  const float* sw = wmat + (size_t)k * BATCH;
  f32x4 acc[4][4];
  #pragma unroll
  for (int m = 0; m < 4; ++m)
    #pragma unroll
    for (int n = 0; n < 4; ++n) acc[m][n] = (f32x4){0.f, 0.f, 0.f, 0.f};
  const int kc8 = tid & 7;
  for (int b0 = 0; b0 < BATCH; b0 += 64) {
    #pragma unroll
    for (int c = 0; c < 4; ++c) {
      int f = c * 256 + tid;
      int row = f >> 3, s = f & 7;
      int sc = (s ^ (row & 7)) << 3;
      gload16(Bg + (size_t)row * BATCH + b0 + sc, Bls + ((c * 256 + wid * 64) << 3));
    }
    const int bcol = b0 + kc8 * 8;
    float4 w0 = *(const float4*)(sw + bcol);
    float4 w1 = *(const float4*)(sw + bcol + 4);
    float wv[8] = {w0.x, w0.y, w0.z, w0.w, w1.x, w1.y, w1.z, w1.w};
    #pragma unroll
    for (int c = 0; c < 4; ++c) {
      int row = c * 32 + (tid >> 3);
      int idx = (row * 64 + kc8 * 8) ^ ((row & 7) << 3);
      uint4 va = *(const uint4*)(Ag + (size_t)row * BATCH + bcol);
      *(uint4*)(&Als[idx]) = scale8(va, wv);
    }
    __syncthreads();
    #pragma unroll
    for (int ks = 0; ks < 2; ++ks) {
      bf16x8 af[4], bfr[4];
      #pragma unroll
      for (int m = 0; m < 4; ++m) {
        int row = wr * 64 + m * 16 + (lane & 15);
        int kb = ks * 32 + (lane >> 4) * 8;
        int idx = (row * 64 + kb) ^ ((row & 7) << 3);
        af[m] = *(const bf16x8*)(&Als[idx]);
      }
      #pragma unroll
      for (int n = 0; n < 4; ++n) {
        int row = wc * 64 + n * 16 + (lane & 15);
        int kb = ks * 32 + (lane >> 4) * 8;
        int idx = (row * 64 + kb) ^ ((row & 7) << 3);
        bfr[n] = *(const bf16x8*)(&Bls[idx]);
      }
      #pragma unroll
      for (int m = 0; m < 4; ++m)
        #pragma unroll
        for (int n = 0; n < 4; ++n)
          acc[m][n] = __builtin_amdgcn_mfma_f32_16x16x32_bf16(af[m], bfr[n], acc[m][n], 0, 0, 0);
    }
    __syncthreads();
  }
  const size_t kb2 = (size_t)k * NIND * NIND;
  #pragma unroll
  for (int m = 0; m < 4; ++m) {
    #pragma unroll
    for (int n = 0; n < 4; ++n) {
      #pragma unroll
      for (int r = 0; r < 4; ++r) {
        int gi = i0 + wr * 64 + m * 16 + (lane >> 4) * 4 + r;
        int gj = j0 + wc * 64 + n * 16 + (lane & 15);
        size_t idx = kb2 + (size_t)gi * NIND + gj;
        float v = acc[m][n][r] + prec[idx];
        u16 bv = (u16)f2bf(v);
        Pb[idx] = bv;
        if (!diag) Pb[kb2 + (size_t)gj * NIND + gi] = bv;
      }
    }
  }
}

// K4: Gershgorin bound per class: gmax[k] = max_i sum_j |P_ij| (certified >= lambda_max)
__global__ __launch_bounds__(256) void gersh_kernel(
    const u16* __restrict__ Pb, unsigned* __restrict__ gmax)
{
  __shared__ float psum[64][17];
  const int k = blockIdx.y, rbk = blockIdx.x;
  const int tid = threadIdx.x;
  const size_t mb = (size_t)k * NIND * NIND;
  #pragma unroll
  for (int p = 0; p < 4; ++p) {
    int rl = p * 16 + (tid >> 4);
    int row = rbk * 64 + rl;
    int ch = tid & 15;
    float s = 0.f;
    const u16* base = Pb + mb + (size_t)row * NIND + ch * 64;
    #pragma unroll
    for (int c8 = 0; c8 < 8; ++c8) {
      uint4 u = *(const uint4*)(base + c8 * 8);
      const unsigned* uu = (const unsigned*)&u;
      #pragma unroll
      for (int q = 0; q < 4; ++q)
        s += fabsf(bflo(uu[q])) + fabsf(bfhi(uu[q]));
    }
    psum[rl][ch] = s;
  }
  __syncthreads();
  if (tid < 64) {
    float s = 0.f;
    #pragma unroll
    for (int j = 0; j < 16; ++j) s += psum[tid][j];
    psum[tid][16] = s;
  }
  __syncthreads();
  if (tid == 0) {
    float mx = 0.f;
    for (int t = 0; t < 64; ++t) mx = fmaxf(mx, psum[t][16]);
    atomicMax(gmax + k, __float_as_uint(mx));
  }
}

// K5: Chebyshev degree-3 initializer: X1 = a3*P^3 + a2*P^2 + a1*P + a0*I with
// coefficients minimizing max|1-lam*p(lam)| over [1,G] (residual = 1/T4((G+1)/(G-1))).
__global__ __launch_bounds__(256) void cheb_kernel(
    const u16* __restrict__ Pb, const u16* __restrict__ Psq,
    const u16* __restrict__ Pcb, const unsigned* __restrict__ gmax,
    u16* __restrict__ X)
{
  const int k = blockIdx.y;
  float G = __uint_as_float(gmax[k]) * 1.001f + 0.01f;
  if (G < 1.05f) G = 1.05f;
  float s = 1.0f + G, dd = G - 1.0f;
  float s2 = s * s, d2 = dd * dd;
  float D = 8.0f * s2 * s2 - 8.0f * d2 * s2 + d2 * d2;   // d^4 * T4((G+1)/(G-1))
  float a3 = -128.0f / D;
  float a2 = 256.0f * s / D;
  float a1 = -(192.0f * s2 - 32.0f * d2) / D;
  float a0 = (64.0f * s2 * s - 32.0f * d2 * s) / D;
  size_t flat = ((size_t)blockIdx.x * 256 + threadIdx.x) * 8;
  int i = (int)(flat >> 10), j0 = (int)(flat & 1023);
  const size_t mb = (size_t)k * NIND * NIND;
  uint4 up = *(const uint4*)(Pb + mb + flat);
  uint4 uq = *(const uint4*)(Psq + mb + flat);
  uint4 uc = *(const uint4*)(Pcb + mb + flat);
  const unsigned* pp = (const unsigned*)&up;
  const unsigned* qq = (const unsigned*)&uq;
  const unsigned* cc = (const unsigned*)&uc;
  unsigned ow[4];
  #pragma unroll
  for (int q = 0; q < 4; ++q) {
    float lo = a3 * bflo(cc[q]) + a2 * bflo(qq[q]) + a1 * bflo(pp[q]);
    float hi = a3 * bfhi(cc[q]) + a2 * bfhi(qq[q]) + a1 * bfhi(pp[q]);
    int cj = j0 + 2 * q;
    if (i == cj) lo += a0;
    if (i == cj + 1) hi += a0;
    ow[q] = (f2bf(lo) & 0xFFFFu) | (f2bf(hi) << 16);
  }
  *(uint4*)(X + mb + flat) = uint4{ow[0], ow[1], ow[2], ow[3]};
}

// K6: C = A (*) B^T; mode 1: C = 2*Xadd - A(*)B^T. Full 64 tiles (coalesced writes).
// XCD-aware tile map: ti = bx&7 -> each XCD owns one ti-row per class (A L2-resident).
__global__ __launch_bounds__(256) void ntgemm_kernel(
    const u16* __restrict__ A, const u16* __restrict__ B,
    const u16* __restrict__ Xadd, u16* __restrict__ C, int mode)
{
  __shared__ u16 Als[128 * 64];
  __shared__ u16 Bls[128 * 64];
  const int k = blockIdx.y;
  const int ti = blockIdx.x & 7, tj = blockIdx.x >> 3;   // XCD swizzle (T1)
  const int i0 = ti * 128, j0 = tj * 128;
  const int tid = threadIdx.x;
  const int wid = tid >> 6, lane = tid & 63;
  const int wr = wid >> 1, wc = wid & 1;
  const size_t mb = (size_t)k * NIND * NIND;
  const u16* Ag = A + mb + (size_t)i0 * NIND;
  const u16* Bg = B + mb + (size_t)j0 * NIND;
  f32x4 acc[4][4];
  #pragma unroll
  for (int m = 0; m < 4; ++m)
    #pragma unroll
    for (int n = 0; n < 4; ++n) acc[m][n] = (f32x4){0.f, 0.f, 0.f, 0.f};
  for (int kb = 0; kb < NIND; kb += 64) {
    #pragma unroll
    for (int c = 0; c < 4; ++c) {
      int f = c * 256 + tid;
      int row = f >> 3, s = f & 7;
      int sc = (s ^ (row & 7)) << 3;
      gload16(Ag + (size_t)row * NIND + kb + sc, Als + ((c * 256 + wid * 64) << 3));
      gload16(Bg + (size_t)row * NIND + kb + sc, Bls + ((c * 256 + wid * 64) << 3));
    }
    __syncthreads();
    #pragma unroll
    for (int ks = 0; ks < 2; ++ks) {
      bf16x8 af[4], bfr[4];
      #pragma unroll
      for (int m = 0; m < 4; ++m) {
        int row = wr * 64 + m * 16 + (lane & 15);
        int kq = ks * 32 + (lane >> 4) * 8;
        int idx = (row * 64 + kq) ^ ((row & 7) << 3);
        af[m] = *(const bf16x8*)(&Als[idx]);
      }
      #pragma unroll
      for (int n = 0; n < 4; ++n) {
        int row = wc * 64 + n * 16 + (lane & 15);
        int kq = ks * 32 + (lane >> 4) * 8;
        int idx = (row * 64 + kq) ^ ((row & 7) << 3);
        bfr[n] = *(const bf16x8*)(&Bls[idx]);
      }
      #pragma unroll
      for (int m = 0; m < 4; ++m)
        #pragma unroll
        for (int n = 0; n < 4; ++n)
          acc[m][n] = __builtin_amdgcn_mfma_f32_16x16x32_bf16(af[m], bfr[n], acc[m][n], 0, 0, 0);
    }
    __syncthreads();
  }
  #pragma unroll
  for (int m = 0; m < 4; ++m) {
    #pragma unroll
    for (int n = 0; n < 4; ++n) {
      #pragma unroll
      for (int r = 0; r < 4; ++r) {
        int gi = i0 + wr * 64 + m * 16 + (lane >> 4) * 4 + r;
        int gj = j0 + wc * 64 + n * 16 + (lane & 15);
        size_t idx = mb + (size_t)gi * NIND + gj;
        float v = acc[m][n][r];
        if (mode) v = 2.0f * bflo((unsigned)Xadd[idx]) - v;
        C[idx] = (u16)f2bf(v);
      }
    }
  }
}

// K7: variance GEMM: C = phi (*) M^T; epilogue * phi[b][i], row-reduce -> partial
__global__ __launch_bounds__(256) void vgemm_kernel(
    const u16* __restrict__ phiB, const u16* __restrict__ M,
    float* __restrict__ partial)
{
  __shared__ u16 Als[128 * 64];
  __shared__ u16 Bls[128 * 64];
  __shared__ float red[128][33];
  const int btile = blockIdx.x >> 3, It = blockIdx.x & 7;
  const int k = blockIdx.y;
  const int b0 = btile * 128, i0 = It * 128;
  const int tid = threadIdx.x;
  const int wid = tid >> 6, lane = tid & 63;
  const int wr = wid >> 1, wc = wid & 1;
  const int q = lane >> 4, l15 = lane & 15;
  const u16* Ag = phiB + (size_t)b0 * NIND;
  const u16* Bg = M + (size_t)k * NIND * NIND + (size_t)i0 * NIND;
  f32x4 acc[4][4];
  #pragma unroll
  for (int m = 0; m < 4; ++m)
    #pragma unroll
    for (int n = 0; n < 4; ++n) acc[m][n] = (f32x4){0.f, 0.f, 0.f, 0.f};
  for (int kb = 0; kb < NIND; kb += 64) {
    #pragma unroll
    for (int c = 0; c < 4; ++c) {
      int f = c * 256 + tid;
      int row = f >> 3, s = f & 7;
      int sc = (s ^ (row & 7)) << 3;
      gload16(Ag + (size_t)row * NIND + kb + sc, Als + ((c * 256 + wid * 64) << 3));
      gload16(Bg + (size_t)row * NIND + kb + sc, Bls + ((c * 256 + wid * 64) << 3));
    }
    __syncthreads();
    #pragma unroll
    for (int ks = 0; ks < 2; ++ks) {
      bf16x8 af[4], bfr[4];
      #pragma unroll
      for (int m = 0; m < 4; ++m) {
        int row = wr * 64 + m * 16 + l15;
        int kq = ks * 32 + q * 8;
        int idx = (row * 64 + kq) ^ ((row & 7) << 3);
        af[m] = *(const bf16x8*)(&Als[idx]);
      }
      #pragma unroll
      for (int n = 0; n < 4; ++n) {
        int row = wc * 64 + n * 16 + l15;
        int kq = ks * 32 + q * 8;
        int idx = (row * 64 + kq) ^ ((row & 7) << 3);
        bfr[n] = *(const bf16x8*)(&Bls[idx]);
      }
      #pragma unroll
      for (int m = 0; m < 4; ++m)
        #pragma unroll
        for (int n = 0; n < 4; ++n)
          acc[m][n] = __builtin_amdgcn_mfma_f32_16x16x32_bf16(af[m], bfr[n], acc[m][n], 0, 0, 0);
    }
    __syncthreads();
  }
  float vs[4][4] = {};
  #pragma unroll
  for (int m = 0; m < 4; ++m) {
    #pragma unroll
    for (int r = 0; r < 4; ++r) {
      int gb = b0 + wr * 64 + m * 16 + q * 4 + r;
      #pragma unroll
      for (int n = 0; n < 4; ++n) {
        int gi = i0 + wc * 64 + n * 16 + l15;
        float pv = bflo((unsigned)phiB[(size_t)gb * NIND + gi]);
        vs[m][r] += acc[m][n][r] * pv;
      }
    }
  }
  #pragma unroll
  for (int m = 0; m < 4; ++m)
    #pragma unroll
    for (int r = 0; r < 4; ++r)
      red[wr * 64 + m * 16 + q * 4 + r][wc * 16 + l15] = vs[m][r];
  __syncthreads();
  if (tid < 128) {
    float s = 0.f;
    #pragma unroll
    for (int t = 0; t < 32; ++t) s += red[tid][t];
    partial[((size_t)It * NCLS + k) * BATCH + b0 + tid] = s;
  }
}

// K8: out variances[b][k] = sum_It partial[It][k][b]
__global__ __launch_bounds__(256) void reduce_kernel(
    const float* __restrict__ partial, float* __restrict__ out)
{
  int t = blockIdx.x * 256 + threadIdx.x;
  int k = t >> 11, b = t & 2047;
  float s = 0.f;
  #pragma unroll
  for (int It = 0; It < 8; ++It)
    s += partial[((size_t)It * NCLS + k) * BATCH + b];
  out[(size_t)BATCH * NCLS + (size_t)b * NCLS + k] = s;
}

extern "C" void kernel_launch(void* const* d_in, const int* in_sizes, int n_in,
                              void* d_out, int out_size, void* d_ws, size_t ws_size,
                              hipStream_t stream)
{
  (void)in_sizes; (void)n_in; (void)ws_size;
  const float* x   = (const float*)d_in[0];
  const float* rw  = (const float*)d_in[1];
  const float* rb  = (const float*)d_in[2];
  const float* bw  = (const float*)d_in[3];
  const float* bb  = (const float*)d_in[4];
  const float* prc = (const float*)d_in[5];
  float* out = (float*)d_out;
  char* ws = (char*)d_ws;
  size_t off = 0;
  auto alloc = [&](size_t bytes) -> void* {
    void* p = ws + off;
    off = (off + bytes + 255) & ~(size_t)255;
    return p;
  };
  const size_t MSZ = (size_t)NCLS * NIND * NIND * 2;   // 32MB bf16 matrix
  float* phi    = (float*)alloc((size_t)BATCH * NIND * 4);
  u16*   phiB   = (u16*)  alloc((size_t)BATCH * NIND * 2);
  u16*   phiTB  = (u16*)  alloc((size_t)NIND * BATCH * 2);
  float* wmat   = (float*)alloc((size_t)NCLS * BATCH * 4);
  u16*   Pb     = (u16*)  alloc(MSZ);
  unsigned* gbound = (unsigned*)alloc((size_t)NCLS * 4);
  float* partial = (float*)alloc((size_t)8 * NCLS * BATCH * 4);
  u16*   Xa     = (u16*)alloc(MSZ);
  u16*   B2     = (u16*)alloc(MSZ);
  u16*   BY     = (u16*)alloc(MSZ);

  hipMemsetAsync(d_out, 0, (size_t)out_size * sizeof(float), stream);
  hipMemsetAsync(gbound, 0, (size_t)NCLS * 4, stream);
  phi_kernel<<<dim3(BATCH/64, NIND/64), 256, 0, stream>>>(x, rw, rb, phi, phiB, phiTB);
  logits_kernel<<<dim3(BATCH/64), 256, 0, stream>>>(phi, bw, bb, out, wmat);
  gram_kernel<<<dim3(36, NCLS), 256, 0, stream>>>(phiTB, wmat, prc, Pb);
  gersh_kernel<<<dim3(16, NCLS), 256, 0, stream>>>(Pb, gbound);
  const dim3 gg(64, NCLS);
  // Chebyshev degree-3 init: Psq = P^2, Pcb = P^3 (P symmetric -> A(*)B^T works)
  ntgemm_kernel<<<gg, 256, 0, stream>>>(Pb, Pb, (u16*)nullptr, BY, 0);   // BY = P^2
  ntgemm_kernel<<<gg, 256, 0, stream>>>(BY, Pb, (u16*)nullptr, B2, 0);   // B2 = P^3
  cheb_kernel<<<dim3(512, NCLS), 256, 0, stream>>>(Pb, BY, B2, gbound, Xa);
  // 2 Newton iterations: BY = X*P ; X' = 2X - X*BY^T
  ntgemm_kernel<<<gg, 256, 0, stream>>>(Xa, Pb, (u16*)nullptr, BY, 0);
  ntgemm_kernel<<<gg, 256, 0, stream>>>(Xa, BY, Xa, B2, 1);
  ntgemm_kernel<<<gg, 256, 0, stream>>>(B2, Pb, (u16*)nullptr, BY, 0);
  ntgemm_kernel<<<gg, 256, 0, stream>>>(B2, BY, B2, Xa, 1);
  // variances: var_b = phi^T M phi, M = Xa
  vgemm_kernel<<<dim3(128, NCLS), 256, 0, stream>>>(phiB, Xa, partial);
  reduce_kernel<<<dim3(128), 256, 0, stream>>>(partial, out);
}

// Round 14
// 647.702 us; speedup vs baseline: 1.5239x; 1.0932x over previous
//
#include <hip/hip_runtime.h>
#include <hip/hip_bf16.h>

#define BATCH 2048
#define FEAT  768
#define NIND  1024
#define NCLS  16

typedef unsigned short u16;
typedef __attribute__((ext_vector_type(8))) __bf16 bf16x8;
typedef __attribute__((ext_vector_type(4))) float f32x4;

static __device__ __forceinline__ unsigned f2bf(float f) {
  unsigned u = __float_as_uint(f);
  unsigned r = ((u >> 16) & 1u) + 0x7FFFu;
  return (u + r) >> 16;                       // RNE bf16 in low 16 bits
}
static __device__ __forceinline__ float bflo(unsigned x) {
  return __uint_as_float((x & 0xFFFFu) << 16);
}
static __device__ __forceinline__ float bfhi(unsigned x) {
  return __uint_as_float(x & 0xFFFF0000u);
}

// async 16B global->LDS (LDS dest = wave-uniform base + lane*16)
static __device__ __forceinline__ void gload16(const u16* g, u16* l) {
  __builtin_amdgcn_global_load_lds(
      (const __attribute__((address_space(1))) void*)g,
      (__attribute__((address_space(3))) void*)l, 16, 0, 0);
}

// pack 8 bf16 (as uint4) scaled by wv[0..7] back to 8 bf16 (uint4)
static __device__ __forceinline__ uint4 scale8(uint4 v, const float* wv) {
  unsigned out[4];
  const unsigned* in = (const unsigned*)&v;
  #pragma unroll
  for (int i = 0; i < 4; ++i) {
    float lo = bflo(in[i]) * wv[2*i];
    float hi = bfhi(in[i]) * wv[2*i+1];
    __hip_bfloat162 pk = __float22bfloat162_rn(float2{lo, hi});
    out[i] = *(unsigned*)&pk;
  }
  return uint4{out[0], out[1], out[2], out[3]};
}

// K1: phi = sqrt(2/N)*cos(2*(x@W+b)); writes phi [B][N] f32, phiB [B][N] bf16, phiTB [N][B] bf16
__global__ __launch_bounds__(256) void phi_kernel(
    const float* __restrict__ x, const float* __restrict__ rw,
    const float* __restrict__ rb, float* __restrict__ phi,
    u16* __restrict__ phiB, u16* __restrict__ phiTB)
{
  __shared__ float xs[64][17];
  __shared__ float wsh[16][68];
  __shared__ float ts[64][65];
  const int b0 = blockIdx.x * 64, i0 = blockIdx.y * 64;
  const int tid = threadIdx.x;
  const int tr = tid >> 4, tc = tid & 15;
  float acc[4][4] = {};
  for (int k0 = 0; k0 < FEAT; k0 += 16) {
    {
      int bb = tid >> 2, kk = (tid & 3) << 2;
      float4 v = *(const float4*)(x + (size_t)(b0 + bb) * FEAT + k0 + kk);
      xs[bb][kk] = v.x; xs[bb][kk+1] = v.y; xs[bb][kk+2] = v.z; xs[bb][kk+3] = v.w;
      int k2 = tid >> 4, ii = (tid & 15) << 2;
      *(float4*)(&wsh[k2][ii]) = *(const float4*)(rw + (size_t)(k0 + k2) * NIND + i0 + ii);
    }
    __syncthreads();
    #pragma unroll
    for (int q = 0; q < 16; ++q) {
      float a[4];
      #pragma unroll
      for (int r = 0; r < 4; ++r) a[r] = xs[tr*4+r][q];
      float4 b4 = *(const float4*)(&wsh[q][tc*4]);
      float bv[4] = {b4.x, b4.y, b4.z, b4.w};
      #pragma unroll
      for (int r = 0; r < 4; ++r)
        #pragma unroll
        for (int c = 0; c < 4; ++c) acc[r][c] += a[r] * bv[c];
    }
    __syncthreads();
  }
  const float SC = 0.04419417382415922f;   // sqrt(2/1024)
  float4 rb4 = *(const float4*)(rb + i0 + tc*4);
  float rbl[4] = {rb4.x, rb4.y, rb4.z, rb4.w};
  #pragma unroll
  for (int r = 0; r < 4; ++r) {
    float vals[4];
    #pragma unroll
    for (int c = 0; c < 4; ++c) {
      float pr = 2.0f * (acc[r][c] + rbl[c]);
      vals[c] = SC * cosf(pr);
      ts[tr*4+r][tc*4+c] = vals[c];
    }
    float4 o = make_float4(vals[0], vals[1], vals[2], vals[3]);
    *(float4*)(phi + (size_t)(b0 + tr*4 + r) * NIND + i0 + tc*4) = o;
    uint2 ob;
    ob.x = (f2bf(o.x) & 0xFFFFu) | (f2bf(o.y) << 16);
    ob.y = (f2bf(o.z) & 0xFFFFu) | (f2bf(o.w) << 16);
    *(uint2*)(phiB + (size_t)(b0 + tr*4 + r) * NIND + i0 + tc*4) = ob;
  }
  __syncthreads();
  #pragma unroll
  for (int rep = 0; rep < 4; ++rep) {
    int ii = tr*4 + rep;
    int bb2 = tc*4;
    float4 o = make_float4(ts[bb2][ii], ts[bb2+1][ii], ts[bb2+2][ii], ts[bb2+3][ii]);
    uint2 ob;
    ob.x = (f2bf(o.x) & 0xFFFFu) | (f2bf(o.y) << 16);
    ob.y = (f2bf(o.z) & 0xFFFFu) | (f2bf(o.w) << 16);
    *(uint2*)(phiTB + (size_t)(i0 + ii) * BATCH + b0 + bb2) = ob;
  }
}

// K2: tiled logits GEMM + in-block softmax -> wmat[k][b] = p(1-p)
__global__ __launch_bounds__(256) void logits_kernel(
    const float* __restrict__ phi, const float* __restrict__ bw,
    const float* __restrict__ bbias, float* __restrict__ out,
    float* __restrict__ wmat)
{
  __shared__ float ph[64][132];
  __shared__ float bwl[16][132];
  __shared__ float lg[64][17];
  const int b0 = blockIdx.x * 64;
  const int tid = threadIdx.x;
  const int bl = tid & 63, kq = tid >> 6;
  float acc[4] = {};
  for (int kb = 0; kb < NIND; kb += 128) {
    #pragma unroll
    for (int i = 0; i < 8; ++i) {
      int f = i * 256 + tid;
      int row = f >> 5, c4 = (f & 31) << 2;
      *(float4*)(&ph[row][c4]) = *(const float4*)(phi + (size_t)(b0 + row) * NIND + kb + c4);
    }
    #pragma unroll
    for (int i = 0; i < 2; ++i) {
      int f = i * 256 + tid;
      int row = f >> 5, c4 = (f & 31) << 2;
      *(float4*)(&bwl[row][c4]) = *(const float4*)(bw + (size_t)row * NIND + kb + c4);
    }
    __syncthreads();
    #pragma unroll 8
    for (int q = 0; q < 128; q += 4) {
      float4 a = *(const float4*)(&ph[bl][q]);
      #pragma unroll
      for (int j = 0; j < 4; ++j) {
        float4 b4 = *(const float4*)(&bwl[kq*4+j][q]);
        acc[j] += a.x*b4.x + a.y*b4.y + a.z*b4.z + a.w*b4.w;
      }
    }
    __syncthreads();
  }
  #pragma unroll
  for (int j = 0; j < 4; ++j) {
    float v = acc[j] + bbias[kq*4+j];
    lg[bl][kq*4+j] = v;
    out[(size_t)(b0 + bl) * NCLS + kq*4 + j] = v;
  }
  __syncthreads();
  if (tid < 64) {
    float mx = -1e30f;
    #pragma unroll
    for (int k = 0; k < 16; ++k) mx = fmaxf(mx, lg[tid][k]);
    float s = 0.f, ex[16];
    #pragma unroll
    for (int k = 0; k < 16; ++k) { ex[k] = expf(lg[tid][k] - mx); s += ex[k]; }
    float inv = 1.0f / s;
    #pragma unroll
    for (int k = 0; k < 16; ++k) {
      float p = ex[k] * inv;
      wmat[(size_t)k * BATCH + b0 + tid] = p * (1.0f - p);
    }
  }
}

// K2b: phiW[k][i][b] = bf16(wmat[k][b] * phi[i][b])  (from bf16 phiTB)
__global__ __launch_bounds__(256) void scalew_kernel(
    const u16* __restrict__ phiTB, const float* __restrict__ wmat,
    u16* __restrict__ phiW)
{
  const int k = blockIdx.y;
  size_t flat = ((size_t)blockIdx.x * 256 + threadIdx.x) * 8;
  int b = (int)(flat & 2047);
  uint4 pv = *(const uint4*)(phiTB + flat);
  float4 w0 = *(const float4*)(wmat + (size_t)k * BATCH + b);
  float4 w1 = *(const float4*)(wmat + (size_t)k * BATCH + b + 4);
  float wv[8] = {w0.x, w0.y, w0.z, w0.w, w1.x, w1.y, w1.z, w1.w};
  *(uint4*)(phiW + (size_t)k * NIND * BATCH + flat) = scale8(pv, wv);
}

// K3 v6: MFMA bf16 gram -> Pb bf16. BOTH operands via gload_lds (A = phiW, B = phiTB).
__global__ __launch_bounds__(256) void gram_kernel(
    const u16* __restrict__ phiW, const u16* __restrict__ phiTB,
    const float* __restrict__ prec, u16* __restrict__ Pb)
{
  __shared__ u16 Als[128 * 64];
  __shared__ u16 Bls[128 * 64];
  int p = blockIdx.x;
  int ti = 0;
  while ((ti + 1) * (ti + 2) / 2 <= p) ++ti;
  int tj = p - ti * (ti + 1) / 2;
  const int k = blockIdx.y;
  const int i0 = ti * 128, j0 = tj * 128;
  const bool diag = (ti == tj);
  const int tid = threadIdx.x;
  const int wid = tid >> 6, lane = tid & 63;
  const int wr = wid >> 1, wc = wid & 1;
  const u16* Ag = phiW + (size_t)k * NIND * BATCH + (size_t)i0 * BATCH;
  const u16* Bg = phiTB + (size_t)j0 * BATCH;
  f32x4 acc[4][4];
  #pragma unroll
  for (int m = 0; m < 4; ++m)
    #pragma unroll
    for (int n = 0; n < 4; ++n) acc[m][n] = (f32x4){0.f, 0.f, 0.f, 0.f};
  for (int b0 = 0; b0 < BATCH; b0 += 64) {
    #pragma unroll
    for (int c = 0; c < 4; ++c) {
      int f = c * 256 + tid;
      int row = f >> 3, s = f & 7;
      int sc = (s ^ (row & 7)) << 3;
      gload16(Ag + (size_t)row * BATCH + b0 + sc, Als + ((c * 256 + wid * 64) << 3));
      gload16(Bg + (size_t)row * BATCH + b0 + sc, Bls + ((c * 256 + wid * 64) << 3));
    }
    __syncthreads();
    #pragma unroll
    for (int ks = 0; ks < 2; ++ks) {
      bf16x8 af[4], bfr[4];
      #pragma unroll
      for (int m = 0; m < 4; ++m) {
        int row = wr * 64 + m * 16 + (lane & 15);
        int kb = ks * 32 + (lane >> 4) * 8;
        int idx = (row * 64 + kb) ^ ((row & 7) << 3);
        af[m] = *(const bf16x8*)(&Als[idx]);
      }
      #pragma unroll
      for (int n = 0; n < 4; ++n) {
        int row = wc * 64 + n * 16 + (lane & 15);
        int kb = ks * 32 + (lane >> 4) * 8;
        int idx = (row * 64 + kb) ^ ((row & 7) << 3);
        bfr[n] = *(const bf16x8*)(&Bls[idx]);
      }
      #pragma unroll
      for (int m = 0; m < 4; ++m)
        #pragma unroll
        for (int n = 0; n < 4; ++n)
          acc[m][n] = __builtin_amdgcn_mfma_f32_16x16x32_bf16(af[m], bfr[n], acc[m][n], 0, 0, 0);
    }
    __syncthreads();
  }
  const size_t kb2 = (size_t)k * NIND * NIND;
  #pragma unroll
  for (int m = 0; m < 4; ++m) {
    #pragma unroll
    for (int n = 0; n < 4; ++n) {
      #pragma unroll
      for (int r = 0; r < 4; ++r) {
        int gi = i0 + wr * 64 + m * 16 + (lane >> 4) * 4 + r;
        int gj = j0 + wc * 64 + n * 16 + (lane & 15);
        size_t idx = kb2 + (size_t)gi * NIND + gj;
        float v = acc[m][n][r] + prec[idx];
        u16 bv = (u16)f2bf(v);
        Pb[idx] = bv;
        if (!diag) Pb[kb2 + (size_t)gj * NIND + gi] = bv;
      }
    }
  }
}

// K4: Gershgorin bound per class: gmax[k] = max_i sum_j |P_ij| (certified >= lambda_max)
__global__ __launch_bounds__(256) void gersh_kernel(
    const u16* __restrict__ Pb, unsigned* __restrict__ gmax)
{
  __shared__ float psum[64][17];
  const int k = blockIdx.y, rbk = blockIdx.x;
  const int tid = threadIdx.x;
  const size_t mb = (size_t)k * NIND * NIND;
  #pragma unroll
  for (int p = 0; p < 4; ++p) {
    int rl = p * 16 + (tid >> 4);
    int row = rbk * 64 + rl;
    int ch = tid & 15;
    float s = 0.f;
    const u16* base = Pb + mb + (size_t)row * NIND + ch * 64;
    #pragma unroll
    for (int c8 = 0; c8 < 8; ++c8) {
      uint4 u = *(const uint4*)(base + c8 * 8);
      const unsigned* uu = (const unsigned*)&u;
      #pragma unroll
      for (int q = 0; q < 4; ++q)
        s += fabsf(bflo(uu[q])) + fabsf(bfhi(uu[q]));
    }
    psum[rl][ch] = s;
  }
  __syncthreads();
  if (tid < 64) {
    float s = 0.f;
    #pragma unroll
    for (int j = 0; j < 16; ++j) s += psum[tid][j];
    psum[tid][16] = s;
  }
  __syncthreads();
  if (tid == 0) {
    float mx = 0.f;
    for (int t = 0; t < 64; ++t) mx = fmaxf(mx, psum[t][16]);
    atomicMax(gmax + k, __float_as_uint(mx));
  }
}

// K5: Chebyshev degree-2 initializer: X1 = b2*P^2 + b1*P + b0*I minimizing
// max|1 - lam*p(lam)| over [1,G]; residual = 1/T3((G+1)/(G-1)).
__global__ __launch_bounds__(256) void cheb_kernel(
    const u16* __restrict__ Pb, const u16* __restrict__ Psq,
    const unsigned* __restrict__ gmax, u16* __restrict__ X)
{
  const int k = blockIdx.y;
  float G = __uint_as_float(gmax[k]) * 1.001f + 0.01f;
  if (G < 1.05f) G = 1.05f;
  float s = G + 1.0f, dd = G - 1.0f;
  float D3 = 4.0f * s * s * s - 3.0f * s * dd * dd;
  float b2 = 32.0f / D3;
  float b1 = -48.0f * s / D3;
  float b0 = (24.0f * s * s - 6.0f * dd * dd) / D3;
  size_t flat = ((size_t)blockIdx.x * 256 + threadIdx.x) * 8;
  int i = (int)(flat >> 10), j0 = (int)(flat & 1023);
  const size_t mb = (size_t)k * NIND * NIND;
  uint4 up = *(const uint4*)(Pb + mb + flat);
  uint4 uq = *(const uint4*)(Psq + mb + flat);
  const unsigned* pp = (const unsigned*)&up;
  const unsigned* qq = (const unsigned*)&uq;
  unsigned ow[4];
  #pragma unroll
  for (int q = 0; q < 4; ++q) {
    float lo = b2 * bflo(qq[q]) + b1 * bflo(pp[q]);
    float hi = b2 * bfhi(qq[q]) + b1 * bfhi(pp[q]);
    int cj = j0 + 2 * q;
    if (i == cj) lo += b0;
    if (i == cj + 1) hi += b0;
    ow[q] = (f2bf(lo) & 0xFFFFu) | (f2bf(hi) << 16);
  }
  *(uint4*)(X + mb + flat) = uint4{ow[0], ow[1], ow[2], ow[3]};
}

// K6: C = A (*) B^T; mode 1: C = 2*Xadd - A(*)B^T. Full 64 tiles (coalesced writes).
// XCD-aware tile map: ti = bx&7 -> each XCD owns one ti-row per class (A L2-resident).
__global__ __launch_bounds__(256) void ntgemm_kernel(
    const u16* __restrict__ A, const u16* __restrict__ B,
    const u16* __restrict__ Xadd, u16* __restrict__ C, int mode)
{
  __shared__ u16 Als[128 * 64];
  __shared__ u16 Bls[128 * 64];
  const int k = blockIdx.y;
  const int ti = blockIdx.x & 7, tj = blockIdx.x >> 3;   // XCD swizzle (T1)
  const int i0 = ti * 128, j0 = tj * 128;
  const int tid = threadIdx.x;
  const int wid = tid >> 6, lane = tid & 63;
  const int wr = wid >> 1, wc = wid & 1;
  const size_t mb = (size_t)k * NIND * NIND;
  const u16* Ag = A + mb + (size_t)i0 * NIND;
  const u16* Bg = B + mb + (size_t)j0 * NIND;
  f32x4 acc[4][4];
  #pragma unroll
  for (int m = 0; m < 4; ++m)
    #pragma unroll
    for (int n = 0; n < 4; ++n) acc[m][n] = (f32x4){0.f, 0.f, 0.f, 0.f};
  for (int kb = 0; kb < NIND; kb += 64) {
    #pragma unroll
    for (int c = 0; c < 4; ++c) {
      int f = c * 256 + tid;
      int row = f >> 3, s = f & 7;
      int sc = (s ^ (row & 7)) << 3;
      gload16(Ag + (size_t)row * NIND + kb + sc, Als + ((c * 256 + wid * 64) << 3));
      gload16(Bg + (size_t)row * NIND + kb + sc, Bls + ((c * 256 + wid * 64) << 3));
    }
    __syncthreads();
    #pragma unroll
    for (int ks = 0; ks < 2; ++ks) {
      bf16x8 af[4], bfr[4];
      #pragma unroll
      for (int m = 0; m < 4; ++m) {
        int row = wr * 64 + m * 16 + (lane & 15);
        int kq = ks * 32 + (lane >> 4) * 8;
        int idx = (row * 64 + kq) ^ ((row & 7) << 3);
        af[m] = *(const bf16x8*)(&Als[idx]);
      }
      #pragma unroll
      for (int n = 0; n < 4; ++n) {
        int row = wc * 64 + n * 16 + (lane & 15);
        int kq = ks * 32 + (lane >> 4) * 8;
        int idx = (row * 64 + kq) ^ ((row & 7) << 3);
        bfr[n] = *(const bf16x8*)(&Bls[idx]);
      }
      #pragma unroll
      for (int m = 0; m < 4; ++m)
        #pragma unroll
        for (int n = 0; n < 4; ++n)
          acc[m][n] = __builtin_amdgcn_mfma_f32_16x16x32_bf16(af[m], bfr[n], acc[m][n], 0, 0, 0);
    }
    __syncthreads();
  }
  #pragma unroll
  for (int m = 0; m < 4; ++m) {
    #pragma unroll
    for (int n = 0; n < 4; ++n) {
      #pragma unroll
      for (int r = 0; r < 4; ++r) {
        int gi = i0 + wr * 64 + m * 16 + (lane >> 4) * 4 + r;
        int gj = j0 + wc * 64 + n * 16 + (lane & 15);
        size_t idx = mb + (size_t)gi * NIND + gj;
        float v = acc[m][n][r];
        if (mode) v = 2.0f * bflo((unsigned)Xadd[idx]) - v;
        C[idx] = (u16)f2bf(v);
      }
    }
  }
}

// K7: variance GEMM: C = phi (*) M^T; epilogue * phi[b][i], row-reduce -> partial
__global__ __launch_bounds__(256) void vgemm_kernel(
    const u16* __restrict__ phiB, const u16* __restrict__ M,
    float* __restrict__ partial)
{
  __shared__ u16 Als[128 * 64];
  __shared__ u16 Bls[128 * 64];
  __shared__ float red[128][33];
  const int btile = blockIdx.x >> 3, It = blockIdx.x & 7;
  const int k = blockIdx.y;
  const int b0 = btile * 128, i0 = It * 128;
  const int tid = threadIdx.x;
  const int wid = tid >> 6, lane = tid & 63;
  const int wr = wid >> 1, wc = wid & 1;
  const int q = lane >> 4, l15 = lane & 15;
  const u16* Ag = phiB + (size_t)b0 * NIND;
  const u16* Bg = M + (size_t)k * NIND * NIND + (size_t)i0 * NIND;
  f32x4 acc[4][4];
  #pragma unroll
  for (int m = 0; m < 4; ++m)
    #pragma unroll
    for (int n = 0; n < 4; ++n) acc[m][n] = (f32x4){0.f, 0.f, 0.f, 0.f};
  for (int kb = 0; kb < NIND; kb += 64) {
    #pragma unroll
    for (int c = 0; c < 4; ++c) {
      int f = c * 256 + tid;
      int row = f >> 3, s = f & 7;
      int sc = (s ^ (row & 7)) << 3;
      gload16(Ag + (size_t)row * NIND + kb + sc, Als + ((c * 256 + wid * 64) << 3));
      gload16(Bg + (size_t)row * NIND + kb + sc, Bls + ((c * 256 + wid * 64) << 3));
    }
    __syncthreads();
    #pragma unroll
    for (int ks = 0; ks < 2; ++ks) {
      bf16x8 af[4], bfr[4];
      #pragma unroll
      for (int m = 0; m < 4; ++m) {
        int row = wr * 64 + m * 16 + l15;
        int kq = ks * 32 + q * 8;
        int idx = (row * 64 + kq) ^ ((row & 7) << 3);
        af[m] = *(const bf16x8*)(&Als[idx]);
      }
      #pragma unroll
      for (int n = 0; n < 4; ++n) {
        int row = wc * 64 + n * 16 + l15;
        int kq = ks * 32 + q * 8;
        int idx = (row * 64 + kq) ^ ((row & 7) << 3);
        bfr[n] = *(const bf16x8*)(&Bls[idx]);
      }
      #pragma unroll
      for (int m = 0; m < 4; ++m)
        #pragma unroll
        for (int n = 0; n < 4; ++n)
          acc[m][n] = __builtin_amdgcn_mfma_f32_16x16x32_bf16(af[m], bfr[n], acc[m][n], 0, 0, 0);
    }
    __syncthreads();
  }
  float vs[4][4] = {};
  #pragma unroll
  for (int m = 0; m < 4; ++m) {
    #pragma unroll
    for (int r = 0; r < 4; ++r) {
      int gb = b0 + wr * 64 + m * 16 + q * 4 + r;
      #pragma unroll
      for (int n = 0; n < 4; ++n) {
        int gi = i0 + wc * 64 + n * 16 + l15;
        float pv = bflo((unsigned)phiB[(size_t)gb * NIND + gi]);
        vs[m][r] += acc[m][n][r] * pv;
      }
    }
  }
  #pragma unroll
  for (int m = 0; m < 4; ++m)
    #pragma unroll
    for (int r = 0; r < 4; ++r)
      red[wr * 64 + m * 16 + q * 4 + r][wc * 16 + l15] = vs[m][r];
  __syncthreads();
  if (tid < 128) {
    float s = 0.f;
    #pragma unroll
    for (int t = 0; t < 32; ++t) s += red[tid][t];
    partial[((size_t)It * NCLS + k) * BATCH + b0 + tid] = s;
  }
}

// K8: out variances[b][k] = sum_It partial[It][k][b]
__global__ __launch_bounds__(256) void reduce_kernel(
    const float* __restrict__ partial, float* __restrict__ out)
{
  int t = blockIdx.x * 256 + threadIdx.x;
  int k = t >> 11, b = t & 2047;
  float s = 0.f;
  #pragma unroll
  for (int It = 0; It < 8; ++It)
    s += partial[((size_t)It * NCLS + k) * BATCH + b];
  out[(size_t)BATCH * NCLS + (size_t)b * NCLS + k] = s;
}

extern "C" void kernel_launch(void* const* d_in, const int* in_sizes, int n_in,
                              void* d_out, int out_size, void* d_ws, size_t ws_size,
                              hipStream_t stream)
{
  (void)in_sizes; (void)n_in; (void)ws_size;
  const float* x   = (const float*)d_in[0];
  const float* rw  = (const float*)d_in[1];
  const float* rb  = (const float*)d_in[2];
  const float* bw  = (const float*)d_in[3];
  const float* bb  = (const float*)d_in[4];
  const float* prc = (const float*)d_in[5];
  float* out = (float*)d_out;
  char* ws = (char*)d_ws;
  size_t off = 0;
  auto alloc = [&](size_t bytes) -> void* {
    void* p = ws + off;
    off = (off + bytes + 255) & ~(size_t)255;
    return p;
  };
  const size_t MSZ = (size_t)NCLS * NIND * NIND * 2;   // 32MB bf16 matrix
  float* phi    = (float*)alloc((size_t)BATCH * NIND * 4);
  u16*   phiB   = (u16*)  alloc((size_t)BATCH * NIND * 2);
  u16*   phiTB  = (u16*)  alloc((size_t)NIND * BATCH * 2);
  float* wmat   = (float*)alloc((size_t)NCLS * BATCH * 4);
  u16*   Pb     = (u16*)  alloc(MSZ);
  unsigned* gbound = (unsigned*)alloc((size_t)NCLS * 4);
  float* partial = (float*)alloc((size_t)8 * NCLS * BATCH * 4);
  u16*   Xa     = (u16*)alloc(MSZ);
  u16*   B2     = (u16*)alloc(MSZ);
  u16*   BY     = (u16*)alloc(MSZ);
  // phiW (64MB) aliases Xa+B2 (contiguous 32MB+32MB): dead before cheb writes Xa,
  // and B2's first write (Newton mode-1) happens after phiW is dead.
  u16*   phiW   = Xa;

  hipMemsetAsync(d_out, 0, (size_t)out_size * sizeof(float), stream);
  hipMemsetAsync(gbound, 0, (size_t)NCLS * 4, stream);
  phi_kernel<<<dim3(BATCH/64, NIND/64), 256, 0, stream>>>(x, rw, rb, phi, phiB, phiTB);
  logits_kernel<<<dim3(BATCH/64), 256, 0, stream>>>(phi, bw, bb, out, wmat);
  scalew_kernel<<<dim3(1024, NCLS), 256, 0, stream>>>(phiTB, wmat, phiW);
  gram_kernel<<<dim3(36, NCLS), 256, 0, stream>>>(phiW, phiTB, prc, Pb);
  gersh_kernel<<<dim3(16, NCLS), 256, 0, stream>>>(Pb, gbound);
  const dim3 gg(64, NCLS);
  // Chebyshev degree-2 init: BY = P^2, then X1 = b2*P^2 + b1*P + b0*I
  ntgemm_kernel<<<gg, 256, 0, stream>>>(Pb, Pb, (u16*)nullptr, BY, 0);   // BY = P^2
  cheb_kernel<<<dim3(512, NCLS), 256, 0, stream>>>(Pb, BY, gbound, Xa);
  // 2 Newton iterations: BY = X*P ; X' = 2X - X*BY^T
  ntgemm_kernel<<<gg, 256, 0, stream>>>(Xa, Pb, (u16*)nullptr, BY, 0);
  ntgemm_kernel<<<gg, 256, 0, stream>>>(Xa, BY, Xa, B2, 1);
  ntgemm_kernel<<<gg, 256, 0, stream>>>(B2, Pb, (u16*)nullptr, BY, 0);
  ntgemm_kernel<<<gg, 256, 0, stream>>>(B2, BY, B2, Xa, 1);
  // variances: var_b = phi^T M phi, M = Xa
  vgemm_kernel<<<dim3(128, NCLS), 256, 0, stream>>>(phiB, Xa, partial);
  reduce_kernel<<<dim3(128), 256, 0, stream>>>(partial, out);
}

// Round 15
// 620.314 us; speedup vs baseline: 1.5912x; 1.0442x over previous
//
#include <hip/hip_runtime.h>
#include <hip/hip_bf16.h>

#define BATCH 2048
#define FEAT  768
#define NIND  1024
#define NCLS  16

typedef unsigned short u16;
typedef __attribute__((ext_vector_type(8))) __bf16 bf16x8;
typedef __attribute__((ext_vector_type(4))) float f32x4;

static __device__ __forceinline__ unsigned f2bf(float f) {
  unsigned u = __float_as_uint(f);
  unsigned r = ((u >> 16) & 1u) + 0x7FFFu;
  return (u + r) >> 16;                       // RNE bf16 in low 16 bits
}
static __device__ __forceinline__ float bflo(unsigned x) {
  return __uint_as_float((x & 0xFFFFu) << 16);
}
static __device__ __forceinline__ float bfhi(unsigned x) {
  return __uint_as_float(x & 0xFFFF0000u);
}

// async 16B global->LDS (LDS dest = wave-uniform base + lane*16)
static __device__ __forceinline__ void gload16(const u16* g, u16* l) {
  __builtin_amdgcn_global_load_lds(
      (const __attribute__((address_space(1))) void*)g,
      (__attribute__((address_space(3))) void*)l, 16, 0, 0);
}

// pack 8 bf16 (as uint4) scaled by wv[0..7] back to 8 bf16 (uint4)
static __device__ __forceinline__ uint4 scale8(uint4 v, const float* wv) {
  unsigned out[4];
  const unsigned* in = (const unsigned*)&v;
  #pragma unroll
  for (int i = 0; i < 4; ++i) {
    float lo = bflo(in[i]) * wv[2*i];
    float hi = bfhi(in[i]) * wv[2*i+1];
    __hip_bfloat162 pk = __float22bfloat162_rn(float2{lo, hi});
    out[i] = *(unsigned*)&pk;
  }
  return uint4{out[0], out[1], out[2], out[3]};
}

// K0a: xB = bf16(x), elementwise
__global__ __launch_bounds__(256) void xcast_kernel(
    const float* __restrict__ x, u16* __restrict__ xB)
{
  size_t f = ((size_t)blockIdx.x * 256 + threadIdx.x) * 8;
  float4 a = *(const float4*)(x + f);
  float4 b = *(const float4*)(x + f + 4);
  uint4 o;
  o.x = (f2bf(a.x) & 0xFFFFu) | (f2bf(a.y) << 16);
  o.y = (f2bf(a.z) & 0xFFFFu) | (f2bf(a.w) << 16);
  o.z = (f2bf(b.x) & 0xFFFFu) | (f2bf(b.y) << 16);
  o.w = (f2bf(b.z) & 0xFFFFu) | (f2bf(b.w) << 16);
  *(uint4*)(xB + f) = o;
}

// K0b: rwT[i][k] = bf16(rw[k][i])  (LDS-tiled transpose)
__global__ __launch_bounds__(256) void rwt_kernel(
    const float* __restrict__ rw, u16* __restrict__ rwT)
{
  __shared__ float ts[64][65];
  const int k0 = blockIdx.x * 64, i0 = blockIdx.y * 64;
  const int tid = threadIdx.x;
  #pragma unroll
  for (int t = 0; t < 4; ++t) {
    int f = t * 256 + tid;
    int r = f >> 4, c4 = (f & 15) << 2;
    *(float4*)(&ts[r][c4]) = *(const float4*)(rw + (size_t)(k0 + r) * NIND + i0 + c4);
  }
  __syncthreads();
  #pragma unroll
  for (int t = 0; t < 4; ++t) {
    int f = t * 256 + tid;
    int r = f >> 4, c4 = (f & 15) << 2;   // r = i-local, c4 = k-local base
    uint2 o;
    o.x = (f2bf(ts[c4+0][r]) & 0xFFFFu) | (f2bf(ts[c4+1][r]) << 16);
    o.y = (f2bf(ts[c4+2][r]) & 0xFFFFu) | (f2bf(ts[c4+3][r]) << 16);
    *(uint2*)(rwT + (size_t)(i0 + r) * FEAT + k0 + c4) = o;
  }
}

// K1 v2: MFMA phi. phiB[b][i], phiTB[i][b] = bf16(SC*cos(2*(x@W+b))). K=768.
__global__ __launch_bounds__(256) void phimm_kernel(
    const u16* __restrict__ xB, const u16* __restrict__ rwT,
    const float* __restrict__ rb, u16* __restrict__ phiB,
    u16* __restrict__ phiTB)
{
  __shared__ u16 sh[128 * 128];      // staging (2x 128x64) then transpose tile
  u16* Als = sh;
  u16* Bls = sh + 8192;
  const int b0 = blockIdx.x * 128, i0 = blockIdx.y * 128;
  const int tid = threadIdx.x;
  const int wid = tid >> 6, lane = tid & 63;
  const int wr = wid >> 1, wc = wid & 1;
  const u16* Ag = xB + (size_t)b0 * FEAT;
  const u16* Bg = rwT + (size_t)i0 * FEAT;
  f32x4 acc[4][4];
  #pragma unroll
  for (int m = 0; m < 4; ++m)
    #pragma unroll
    for (int n = 0; n < 4; ++n) acc[m][n] = (f32x4){0.f, 0.f, 0.f, 0.f};
  for (int kb = 0; kb < FEAT; kb += 64) {
    #pragma unroll
    for (int c = 0; c < 4; ++c) {
      int f = c * 256 + tid;
      int row = f >> 3, s = f & 7;
      int sc = (s ^ (row & 7)) << 3;
      gload16(Ag + (size_t)row * FEAT + kb + sc, Als + ((c * 256 + wid * 64) << 3));
      gload16(Bg + (size_t)row * FEAT + kb + sc, Bls + ((c * 256 + wid * 64) << 3));
    }
    __syncthreads();
    #pragma unroll
    for (int ks = 0; ks < 2; ++ks) {
      bf16x8 af[4], bfr[4];
      #pragma unroll
      for (int m = 0; m < 4; ++m) {
        int row = wr * 64 + m * 16 + (lane & 15);
        int kq = ks * 32 + (lane >> 4) * 8;
        int idx = (row * 64 + kq) ^ ((row & 7) << 3);
        af[m] = *(const bf16x8*)(&Als[idx]);
      }
      #pragma unroll
      for (int n = 0; n < 4; ++n) {
        int row = wc * 64 + n * 16 + (lane & 15);
        int kq = ks * 32 + (lane >> 4) * 8;
        int idx = (row * 64 + kq) ^ ((row & 7) << 3);
        bfr[n] = *(const bf16x8*)(&Bls[idx]);
      }
      #pragma unroll
      for (int m = 0; m < 4; ++m)
        #pragma unroll
        for (int n = 0; n < 4; ++n)
          acc[m][n] = __builtin_amdgcn_mfma_f32_16x16x32_bf16(af[m], bfr[n], acc[m][n], 0, 0, 0);
    }
    __syncthreads();
  }
  const float SC = 0.04419417382415922f;   // sqrt(2/1024)
  float rbl[4];
  #pragma unroll
  for (int n = 0; n < 4; ++n) rbl[n] = rb[i0 + wc * 64 + n * 16 + (lane & 15)];
  #pragma unroll
  for (int m = 0; m < 4; ++m) {
    #pragma unroll
    for (int n = 0; n < 4; ++n) {
      #pragma unroll
      for (int r = 0; r < 4; ++r) {
        int lb = wr * 64 + m * 16 + (lane >> 4) * 4 + r;
        int li = wc * 64 + n * 16 + (lane & 15);
        float proj = 2.0f * (acc[m][n][r] + rbl[n]);
        u16 bv = (u16)f2bf(SC * cosf(proj));
        phiB[(size_t)(b0 + lb) * NIND + i0 + li] = bv;
        int idx = (li * 128 + lb) ^ ((li & 7) << 3);
        sh[idx] = bv;
      }
    }
  }
  __syncthreads();
  #pragma unroll
  for (int t = 0; t < 8; ++t) {
    int f = t * 256 + tid;             // 2048 uint4-slots over 128x128 u16
    int li = f >> 4, c8 = (f & 15) << 3;
    int idx = (li * 128 + c8) ^ ((li & 7) << 3);
    uint4 v = *(const uint4*)(&sh[idx]);
    *(uint4*)(phiTB + (size_t)(i0 + li) * BATCH + b0 + c8) = v;
  }
}

// K2 v3: logits from phiB (bf16), 16 batch rows per block, thread = (row, class)
__global__ __launch_bounds__(256) void logits_kernel(
    const u16* __restrict__ phiB, const float* __restrict__ bw,
    const float* __restrict__ bbias, float* __restrict__ out,
    float* __restrict__ wmat)
{
  __shared__ float ph[16][132];
  __shared__ float bwl[16][132];
  __shared__ float lg[16][17];
  const int b0 = blockIdx.x * 16;
  const int tid = threadIdx.x;
  const int bl = tid & 15, kq = tid >> 4;
  float acc = 0.f;
  for (int kb = 0; kb < NIND; kb += 128) {
    {
      int row = tid >> 4, c8 = (tid & 15) << 3;
      uint4 v = *(const uint4*)(phiB + (size_t)(b0 + row) * NIND + kb + c8);
      const unsigned* u = (const unsigned*)&v;
      #pragma unroll
      for (int j = 0; j < 4; ++j) {
        ph[row][c8 + 2*j]     = bflo(u[j]);
        ph[row][c8 + 2*j + 1] = bfhi(u[j]);
      }
    }
    #pragma unroll
    for (int t = 0; t < 2; ++t) {
      int f = t * 256 + tid;
      int row = f >> 5, c4 = (f & 31) << 2;
      *(float4*)(&bwl[row][c4]) = *(const float4*)(bw + (size_t)row * NIND + kb + c4);
    }
    __syncthreads();
    #pragma unroll 8
    for (int q = 0; q < 128; q += 4) {
      float4 a = *(const float4*)(&ph[bl][q]);
      float4 b4 = *(const float4*)(&bwl[kq][q]);
      acc += a.x*b4.x + a.y*b4.y + a.z*b4.z + a.w*b4.w;
    }
    __syncthreads();
  }
  float v = acc + bbias[kq];
  lg[bl][kq] = v;
  out[(size_t)(b0 + bl) * NCLS + kq] = v;
  __syncthreads();
  if (tid < 16) {
    float mx = -1e30f;
    #pragma unroll
    for (int k = 0; k < 16; ++k) mx = fmaxf(mx, lg[tid][k]);
    float s = 0.f, ex[16];
    #pragma unroll
    for (int k = 0; k < 16; ++k) { ex[k] = expf(lg[tid][k] - mx); s += ex[k]; }
    float inv = 1.0f / s;
    #pragma unroll
    for (int k = 0; k < 16; ++k) {
      float p = ex[k] * inv;
      wmat[(size_t)k * BATCH + b0 + tid] = p * (1.0f - p);
    }
  }
}

// K2b: phiW[k][i][b] = bf16(wmat[k][b] * phi[i][b])  (from bf16 phiTB)
__global__ __launch_bounds__(256) void scalew_kernel(
    const u16* __restrict__ phiTB, const float* __restrict__ wmat,
    u16* __restrict__ phiW)
{
  const int k = blockIdx.y;
  size_t flat = ((size_t)blockIdx.x * 256 + threadIdx.x) * 8;
  int b = (int)(flat & 2047);
  uint4 pv = *(const uint4*)(phiTB + flat);
  float4 w0 = *(const float4*)(wmat + (size_t)k * BATCH + b);
  float4 w1 = *(const float4*)(wmat + (size_t)k * BATCH + b + 4);
  float wv[8] = {w0.x, w0.y, w0.z, w0.w, w1.x, w1.y, w1.z, w1.w};
  *(uint4*)(phiW + (size_t)k * NIND * BATCH + flat) = scale8(pv, wv);
}

// K3: MFMA bf16 gram -> Pb bf16. BOTH operands via gload_lds (A = phiW, B = phiTB).
__global__ __launch_bounds__(256) void gram_kernel(
    const u16* __restrict__ phiW, const u16* __restrict__ phiTB,
    const float* __restrict__ prec, u16* __restrict__ Pb)
{
  __shared__ u16 Als[128 * 64];
  __shared__ u16 Bls[128 * 64];
  int p = blockIdx.x;
  int ti = 0;
  while ((ti + 1) * (ti + 2) / 2 <= p) ++ti;
  int tj = p - ti * (ti + 1) / 2;
  const int k = blockIdx.y;
  const int i0 = ti * 128, j0 = tj * 128;
  const bool diag = (ti == tj);
  const int tid = threadIdx.x;
  const int wid = tid >> 6, lane = tid & 63;
  const int wr = wid >> 1, wc = wid & 1;
  const u16* Ag = phiW + (size_t)k * NIND * BATCH + (size_t)i0 * BATCH;
  const u16* Bg = phiTB + (size_t)j0 * BATCH;
  f32x4 acc[4][4];
  #pragma unroll
  for (int m = 0; m < 4; ++m)
    #pragma unroll
    for (int n = 0; n < 4; ++n) acc[m][n] = (f32x4){0.f, 0.f, 0.f, 0.f};
  for (int b0 = 0; b0 < BATCH; b0 += 64) {
    #pragma unroll
    for (int c = 0; c < 4; ++c) {
      int f = c * 256 + tid;
      int row = f >> 3, s = f & 7;
      int sc = (s ^ (row & 7)) << 3;
      gload16(Ag + (size_t)row * BATCH + b0 + sc, Als + ((c * 256 + wid * 64) << 3));
      gload16(Bg + (size_t)row * BATCH + b0 + sc, Bls + ((c * 256 + wid * 64) << 3));
    }
    __syncthreads();
    #pragma unroll
    for (int ks = 0; ks < 2; ++ks) {
      bf16x8 af[4], bfr[4];
      #pragma unroll
      for (int m = 0; m < 4; ++m) {
        int row = wr * 64 + m * 16 + (lane & 15);
        int kb = ks * 32 + (lane >> 4) * 8;
        int idx = (row * 64 + kb) ^ ((row & 7) << 3);
        af[m] = *(const bf16x8*)(&Als[idx]);
      }
      #pragma unroll
      for (int n = 0; n < 4; ++n) {
        int row = wc * 64 + n * 16 + (lane & 15);
        int kb = ks * 32 + (lane >> 4) * 8;
        int idx = (row * 64 + kb) ^ ((row & 7) << 3);
        bfr[n] = *(const bf16x8*)(&Bls[idx]);
      }
      #pragma unroll
      for (int m = 0; m < 4; ++m)
        #pragma unroll
        for (int n = 0; n < 4; ++n)
          acc[m][n] = __builtin_amdgcn_mfma_f32_16x16x32_bf16(af[m], bfr[n], acc[m][n], 0, 0, 0);
    }
    __syncthreads();
  }
  const size_t kb2 = (size_t)k * NIND * NIND;
  #pragma unroll
  for (int m = 0; m < 4; ++m) {
    #pragma unroll
    for (int n = 0; n < 4; ++n) {
      #pragma unroll
      for (int r = 0; r < 4; ++r) {
        int gi = i0 + wr * 64 + m * 16 + (lane >> 4) * 4 + r;
        int gj = j0 + wc * 64 + n * 16 + (lane & 15);
        size_t idx = kb2 + (size_t)gi * NIND + gj;
        float v = acc[m][n][r] + prec[idx];
        u16 bv = (u16)f2bf(v);
        Pb[idx] = bv;
        if (!diag) Pb[kb2 + (size_t)gj * NIND + gi] = bv;
      }
    }
  }
}

// K4: Gershgorin bound per class: gmax[k] = max_i sum_j |P_ij| (certified >= lambda_max)
__global__ __launch_bounds__(256) void gersh_kernel(
    const u16* __restrict__ Pb, unsigned* __restrict__ gmax)
{
  __shared__ float psum[64][17];
  const int k = blockIdx.y, rbk = blockIdx.x;
  const int tid = threadIdx.x;
  const size_t mb = (size_t)k * NIND * NIND;
  #pragma unroll
  for (int p = 0; p < 4; ++p) {
    int rl = p * 16 + (tid >> 4);
    int row = rbk * 64 + rl;
    int ch = tid & 15;
    float s = 0.f;
    const u16* base = Pb + mb + (size_t)row * NIND + ch * 64;
    #pragma unroll
    for (int c8 = 0; c8 < 8; ++c8) {
      uint4 u = *(const uint4*)(base + c8 * 8);
      const unsigned* uu = (const unsigned*)&u;
      #pragma unroll
      for (int q = 0; q < 4; ++q)
        s += fabsf(bflo(uu[q])) + fabsf(bfhi(uu[q]));
    }
    psum[rl][ch] = s;
  }
  __syncthreads();
  if (tid < 64) {
    float s = 0.f;
    #pragma unroll
    for (int j = 0; j < 16; ++j) s += psum[tid][j];
    psum[tid][16] = s;
  }
  __syncthreads();
  if (tid == 0) {
    float mx = 0.f;
    for (int t = 0; t < 64; ++t) mx = fmaxf(mx, psum[t][16]);
    atomicMax(gmax + k, __float_as_uint(mx));
  }
}

// K5: Chebyshev degree-2 initializer: X1 = b2*P^2 + b1*P + b0*I
__global__ __launch_bounds__(256) void cheb_kernel(
    const u16* __restrict__ Pb, const u16* __restrict__ Psq,
    const unsigned* __restrict__ gmax, u16* __restrict__ X)
{
  const int k = blockIdx.y;
  float G = __uint_as_float(gmax[k]) * 1.001f + 0.01f;
  if (G < 1.05f) G = 1.05f;
  float s = G + 1.0f, dd = G - 1.0f;
  float D3 = 4.0f * s * s * s - 3.0f * s * dd * dd;
  float b2 = 32.0f / D3;
  float b1 = -48.0f * s / D3;
  float b0 = (24.0f * s * s - 6.0f * dd * dd) / D3;
  size_t flat = ((size_t)blockIdx.x * 256 + threadIdx.x) * 8;
  int i = (int)(flat >> 10), j0 = (int)(flat & 1023);
  const size_t mb = (size_t)k * NIND * NIND;
  uint4 up = *(const uint4*)(Pb + mb + flat);
  uint4 uq = *(const uint4*)(Psq + mb + flat);
  const unsigned* pp = (const unsigned*)&up;
  const unsigned* qq = (const unsigned*)&uq;
  unsigned ow[4];
  #pragma unroll
  for (int q = 0; q < 4; ++q) {
    float lo = b2 * bflo(qq[q]) + b1 * bflo(pp[q]);
    float hi = b2 * bfhi(qq[q]) + b1 * bfhi(pp[q]);
    int cj = j0 + 2 * q;
    if (i == cj) lo += b0;
    if (i == cj + 1) hi += b0;
    ow[q] = (f2bf(lo) & 0xFFFFu) | (f2bf(hi) << 16);
  }
  *(uint4*)(X + mb + flat) = uint4{ow[0], ow[1], ow[2], ow[3]};
}

// K6: C = A (*) B^T; mode 1: C = 2*Xadd - A(*)B^T. Full 64 tiles, XCD swizzle.
__global__ __launch_bounds__(256) void ntgemm_kernel(
    const u16* __restrict__ A, const u16* __restrict__ B,
    const u16* __restrict__ Xadd, u16* __restrict__ C, int mode)
{
  __shared__ u16 Als[128 * 64];
  __shared__ u16 Bls[128 * 64];
  const int k = blockIdx.y;
  const int ti = blockIdx.x & 7, tj = blockIdx.x >> 3;   // XCD swizzle (T1)
  const int i0 = ti * 128, j0 = tj * 128;
  const int tid = threadIdx.x;
  const int wid = tid >> 6, lane = tid & 63;
  const int wr = wid >> 1, wc = wid & 1;
  const size_t mb = (size_t)k * NIND * NIND;
  const u16* Ag = A + mb + (size_t)i0 * NIND;
  const u16* Bg = B + mb + (size_t)j0 * NIND;
  f32x4 acc[4][4];
  #pragma unroll
  for (int m = 0; m < 4; ++m)
    #pragma unroll
    for (int n = 0; n < 4; ++n) acc[m][n] = (f32x4){0.f, 0.f, 0.f, 0.f};
  for (int kb = 0; kb < NIND; kb += 64) {
    #pragma unroll
    for (int c = 0; c < 4; ++c) {
      int f = c * 256 + tid;
      int row = f >> 3, s = f & 7;
      int sc = (s ^ (row & 7)) << 3;
      gload16(Ag + (size_t)row * NIND + kb + sc, Als + ((c * 256 + wid * 64) << 3));
      gload16(Bg + (size_t)row * NIND + kb + sc, Bls + ((c * 256 + wid * 64) << 3));
    }
    __syncthreads();
    #pragma unroll
    for (int ks = 0; ks < 2; ++ks) {
      bf16x8 af[4], bfr[4];
      #pragma unroll
      for (int m = 0; m < 4; ++m) {
        int row = wr * 64 + m * 16 + (lane & 15);
        int kq = ks * 32 + (lane >> 4) * 8;
        int idx = (row * 64 + kq) ^ ((row & 7) << 3);
        af[m] = *(const bf16x8*)(&Als[idx]);
      }
      #pragma unroll
      for (int n = 0; n < 4; ++n) {
        int row = wc * 64 + n * 16 + (lane & 15);
        int kq = ks * 32 + (lane >> 4) * 8;
        int idx = (row * 64 + kq) ^ ((row & 7) << 3);
        bfr[n] = *(const bf16x8*)(&Bls[idx]);
      }
      #pragma unroll
      for (int m = 0; m < 4; ++m)
        #pragma unroll
        for (int n = 0; n < 4; ++n)
          acc[m][n] = __builtin_amdgcn_mfma_f32_16x16x32_bf16(af[m], bfr[n], acc[m][n], 0, 0, 0);
    }
    __syncthreads();
  }
  #pragma unroll
  for (int m = 0; m < 4; ++m) {
    #pragma unroll
    for (int n = 0; n < 4; ++n) {
      #pragma unroll
      for (int r = 0; r < 4; ++r) {
        int gi = i0 + wr * 64 + m * 16 + (lane >> 4) * 4 + r;
        int gj = j0 + wc * 64 + n * 16 + (lane & 15);
        size_t idx = mb + (size_t)gi * NIND + gj;
        float v = acc[m][n][r];
        if (mode) v = 2.0f * bflo((unsigned)Xadd[idx]) - v;
        C[idx] = (u16)f2bf(v);
      }
    }
  }
}

// K7: variance GEMM: C = phi (*) M^T; epilogue * phi[b][i], row-reduce -> partial
__global__ __launch_bounds__(256) void vgemm_kernel(
    const u16* __restrict__ phiB, const u16* __restrict__ M,
    float* __restrict__ partial)
{
  __shared__ u16 Als[128 * 64];
  __shared__ u16 Bls[128 * 64];
  __shared__ float red[128][33];
  const int btile = blockIdx.x >> 3, It = blockIdx.x & 7;
  const int k = blockIdx.y;
  const int b0 = btile * 128, i0 = It * 128;
  const int tid = threadIdx.x;
  const int wid = tid >> 6, lane = tid & 63;
  const int wr = wid >> 1, wc = wid & 1;
  const int q = lane >> 4, l15 = lane & 15;
  const u16* Ag = phiB + (size_t)b0 * NIND;
  const u16* Bg = M + (size_t)k * NIND * NIND + (size_t)i0 * NIND;
  f32x4 acc[4][4];
  #pragma unroll
  for (int m = 0; m < 4; ++m)
    #pragma unroll
    for (int n = 0; n < 4; ++n) acc[m][n] = (f32x4){0.f, 0.f, 0.f, 0.f};
  for (int kb = 0; kb < NIND; kb += 64) {
    #pragma unroll
    for (int c = 0; c < 4; ++c) {
      int f = c * 256 + tid;
      int row = f >> 3, s = f & 7;
      int sc = (s ^ (row & 7)) << 3;
      gload16(Ag + (size_t)row * NIND + kb + sc, Als + ((c * 256 + wid * 64) << 3));
      gload16(Bg + (size_t)row * NIND + kb + sc, Bls + ((c * 256 + wid * 64) << 3));
    }
    __syncthreads();
    #pragma unroll
    for (int ks = 0; ks < 2; ++ks) {
      bf16x8 af[4], bfr[4];
      #pragma unroll
      for (int m = 0; m < 4; ++m) {
        int row = wr * 64 + m * 16 + l15;
        int kq = ks * 32 + q * 8;
        int idx = (row * 64 + kq) ^ ((row & 7) << 3);
        af[m] = *(const bf16x8*)(&Als[idx]);
      }
      #pragma unroll
      for (int n = 0; n < 4; ++n) {
        int row = wc * 64 + n * 16 + l15;
        int kq = ks * 32 + q * 8;
        int idx = (row * 64 + kq) ^ ((row & 7) << 3);
        bfr[n] = *(const bf16x8*)(&Bls[idx]);
      }
      #pragma unroll
      for (int m = 0; m < 4; ++m)
        #pragma unroll
        for (int n = 0; n < 4; ++n)
          acc[m][n] = __builtin_amdgcn_mfma_f32_16x16x32_bf16(af[m], bfr[n], acc[m][n], 0, 0, 0);
    }
    __syncthreads();
  }
  float vs[4][4] = {};
  #pragma unroll
  for (int m = 0; m < 4; ++m) {
    #pragma unroll
    for (int r = 0; r < 4; ++r) {
      int gb = b0 + wr * 64 + m * 16 + q * 4 + r;
      #pragma unroll
      for (int n = 0; n < 4; ++n) {
        int gi = i0 + wc * 64 + n * 16 + l15;
        float pv = bflo((unsigned)phiB[(size_t)gb * NIND + gi]);
        vs[m][r] += acc[m][n][r] * pv;
      }
    }
  }
  #pragma unroll
  for (int m = 0; m < 4; ++m)
    #pragma unroll
    for (int r = 0; r < 4; ++r)
      red[wr * 64 + m * 16 + q * 4 + r][wc * 16 + l15] = vs[m][r];
  __syncthreads();
  if (tid < 128) {
    float s = 0.f;
    #pragma unroll
    for (int t = 0; t < 32; ++t) s += red[tid][t];
    partial[((size_t)It * NCLS + k) * BATCH + b0 + tid] = s;
  }
}

// K8: out variances[b][k] = sum_It partial[It][k][b]
__global__ __launch_bounds__(256) void reduce_kernel(
    const float* __restrict__ partial, float* __restrict__ out)
{
  int t = blockIdx.x * 256 + threadIdx.x;
  int k = t >> 11, b = t & 2047;
  float s = 0.f;
  #pragma unroll
  for (int It = 0; It < 8; ++It)
    s += partial[((size_t)It * NCLS + k) * BATCH + b];
  out[(size_t)BATCH * NCLS + (size_t)b * NCLS + k] = s;
}

extern "C" void kernel_launch(void* const* d_in, const int* in_sizes, int n_in,
                              void* d_out, int out_size, void* d_ws, size_t ws_size,
                              hipStream_t stream)
{
  (void)in_sizes; (void)n_in; (void)ws_size;
  const float* x   = (const float*)d_in[0];
  const float* rw  = (const float*)d_in[1];
  const float* rb  = (const float*)d_in[2];
  const float* bw  = (const float*)d_in[3];
  const float* bb  = (const float*)d_in[4];
  const float* prc = (const float*)d_in[5];
  float* out = (float*)d_out;
  char* ws = (char*)d_ws;
  size_t off = 0;
  auto alloc = [&](size_t bytes) -> void* {
    void* p = ws + off;
    off = (off + bytes + 255) & ~(size_t)255;
    return p;
  };
  const size_t MSZ = (size_t)NCLS * NIND * NIND * 2;   // 32MB bf16 matrix
  u16*   xB     = (u16*)  alloc((size_t)BATCH * FEAT * 2);
  u16*   rwT    = (u16*)  alloc((size_t)NIND * FEAT * 2);
  u16*   phiB   = (u16*)  alloc((size_t)BATCH * NIND * 2);
  u16*   phiTB  = (u16*)  alloc((size_t)NIND * BATCH * 2);
  float* wmat   = (float*)alloc((size_t)NCLS * BATCH * 4);
  u16*   Pb     = (u16*)  alloc(MSZ);
  unsigned* gbound = (unsigned*)alloc((size_t)NCLS * 4);
  float* partial = (float*)alloc((size_t)8 * NCLS * BATCH * 4);
  u16*   Xa     = (u16*)alloc(MSZ);
  u16*   B2     = (u16*)alloc(MSZ);
  u16*   BY     = (u16*)alloc(MSZ);
  // phiW (64MB) aliases Xa+B2 (contiguous): dead before cheb writes Xa.
  u16*   phiW   = Xa;

  hipMemsetAsync(d_out, 0, (size_t)out_size * sizeof(float), stream);
  hipMemsetAsync(gbound, 0, (size_t)NCLS * 4, stream);
  xcast_kernel<<<dim3(BATCH * FEAT / 2048), 256, 0, stream>>>(x, xB);
  rwt_kernel<<<dim3(FEAT / 64, NIND / 64), 256, 0, stream>>>(rw, rwT);
  phimm_kernel<<<dim3(BATCH / 128, NIND / 128), 256, 0, stream>>>(xB, rwT, rb, phiB, phiTB);
  logits_kernel<<<dim3(BATCH / 16), 256, 0, stream>>>(phiB, bw, bb, out, wmat);
  scalew_kernel<<<dim3(1024, NCLS), 256, 0, stream>>>(phiTB, wmat, phiW);
  gram_kernel<<<dim3(36, NCLS), 256, 0, stream>>>(phiW, phiTB, prc, Pb);
  gersh_kernel<<<dim3(16, NCLS), 256, 0, stream>>>(Pb, gbound);
  const dim3 gg(64, NCLS);
  // Chebyshev degree-2 init: BY = P^2, then X1 = b2*P^2 + b1*P + b0*I
  ntgemm_kernel<<<gg, 256, 0, stream>>>(Pb, Pb, (u16*)nullptr, BY, 0);   // BY = P^2
  cheb_kernel<<<dim3(512, NCLS), 256, 0, stream>>>(Pb, BY, gbound, Xa);
  // 2 Newton iterations: BY = X*P ; X' = 2X - X*BY^T
  ntgemm_kernel<<<gg, 256, 0, stream>>>(Xa, Pb, (u16*)nullptr, BY, 0);
  ntgemm_kernel<<<gg, 256, 0, stream>>>(Xa, BY, Xa, B2, 1);
  ntgemm_kernel<<<gg, 256, 0, stream>>>(B2, Pb, (u16*)nullptr, BY, 0);
  ntgemm_kernel<<<gg, 256, 0, stream>>>(B2, BY, B2, Xa, 1);
  // variances: var_b = phi^T M phi, M = Xa
  vgemm_kernel<<<dim3(128, NCLS), 256, 0, stream>>>(phiB, Xa, partial);
  reduce_kernel<<<dim3(128), 256, 0, stream>>>(partial, out);
}

// Round 16
// 617.967 us; speedup vs baseline: 1.5973x; 1.0038x over previous
//
#include <hip/hip_runtime.h>
#include <hip/hip_bf16.h>

#define BATCH 2048
#define FEAT  768
#define NIND  1024
#define NCLS  16

typedef unsigned short u16;
typedef __attribute__((ext_vector_type(8))) __bf16 bf16x8;
typedef __attribute__((ext_vector_type(4))) float f32x4;

static __device__ __forceinline__ unsigned f2bf(float f) {
  unsigned u = __float_as_uint(f);
  unsigned r = ((u >> 16) & 1u) + 0x7FFFu;
  return (u + r) >> 16;                       // RNE bf16 in low 16 bits
}
static __device__ __forceinline__ float bflo(unsigned x) {
  return __uint_as_float((x & 0xFFFFu) << 16);
}
static __device__ __forceinline__ float bfhi(unsigned x) {
  return __uint_as_float(x & 0xFFFF0000u);
}

// async 16B global->LDS (LDS dest = wave-uniform base + lane*16)
static __device__ __forceinline__ void gload16(const u16* g, u16* l) {
  __builtin_amdgcn_global_load_lds(
      (const __attribute__((address_space(1))) void*)g,
      (__attribute__((address_space(3))) void*)l, 16, 0, 0);
}

// pack 8 bf16 (as uint4) scaled by wv[0..7] back to 8 bf16 (uint4)
static __device__ __forceinline__ uint4 scale8(uint4 v, const float* wv) {
  unsigned out[4];
  const unsigned* in = (const unsigned*)&v;
  #pragma unroll
  for (int i = 0; i < 4; ++i) {
    float lo = bflo(in[i]) * wv[2*i];
    float hi = bfhi(in[i]) * wv[2*i+1];
    __hip_bfloat162 pk = __float22bfloat162_rn(float2{lo, hi});
    out[i] = *(unsigned*)&pk;
  }
  return uint4{out[0], out[1], out[2], out[3]};
}

// K0a: xB = bf16(x), elementwise
__global__ __launch_bounds__(256) void xcast_kernel(
    const float* __restrict__ x, u16* __restrict__ xB)
{
  size_t f = ((size_t)blockIdx.x * 256 + threadIdx.x) * 8;
  float4 a = *(const float4*)(x + f);
  float4 b = *(const float4*)(x + f + 4);
  uint4 o;
  o.x = (f2bf(a.x) & 0xFFFFu) | (f2bf(a.y) << 16);
  o.y = (f2bf(a.z) & 0xFFFFu) | (f2bf(a.w) << 16);
  o.z = (f2bf(b.x) & 0xFFFFu) | (f2bf(b.y) << 16);
  o.w = (f2bf(b.z) & 0xFFFFu) | (f2bf(b.w) << 16);
  *(uint4*)(xB + f) = o;
}

// K0b: rwT[i][k] = bf16(rw[k][i])  (LDS-tiled transpose)
__global__ __launch_bounds__(256) void rwt_kernel(
    const float* __restrict__ rw, u16* __restrict__ rwT)
{
  __shared__ float ts[64][65];
  const int k0 = blockIdx.x * 64, i0 = blockIdx.y * 64;
  const int tid = threadIdx.x;
  #pragma unroll
  for (int t = 0; t < 4; ++t) {
    int f = t * 256 + tid;
    int r = f >> 4, c4 = (f & 15) << 2;
    *(float4*)(&ts[r][c4]) = *(const float4*)(rw + (size_t)(k0 + r) * NIND + i0 + c4);
  }
  __syncthreads();
  #pragma unroll
  for (int t = 0; t < 4; ++t) {
    int f = t * 256 + tid;
    int r = f >> 4, c4 = (f & 15) << 2;   // r = i-local, c4 = k-local base
    uint2 o;
    o.x = (f2bf(ts[c4+0][r]) & 0xFFFFu) | (f2bf(ts[c4+1][r]) << 16);
    o.y = (f2bf(ts[c4+2][r]) & 0xFFFFu) | (f2bf(ts[c4+3][r]) << 16);
    *(uint2*)(rwT + (size_t)(i0 + r) * FEAT + k0 + c4) = o;
  }
}

// K1 v2: MFMA phi. phiB[b][i], phiTB[i][b] = bf16(SC*cos(2*(x@W+b))). K=768.
__global__ __launch_bounds__(256) void phimm_kernel(
    const u16* __restrict__ xB, const u16* __restrict__ rwT,
    const float* __restrict__ rb, u16* __restrict__ phiB,
    u16* __restrict__ phiTB)
{
  __shared__ u16 sh[128 * 128];      // staging (2x 128x64) then transpose tile
  u16* Als = sh;
  u16* Bls = sh + 8192;
  const int b0 = blockIdx.x * 128, i0 = blockIdx.y * 128;
  const int tid = threadIdx.x;
  const int wid = tid >> 6, lane = tid & 63;
  const int wr = wid >> 1, wc = wid & 1;
  const u16* Ag = xB + (size_t)b0 * FEAT;
  const u16* Bg = rwT + (size_t)i0 * FEAT;
  f32x4 acc[4][4];
  #pragma unroll
  for (int m = 0; m < 4; ++m)
    #pragma unroll
    for (int n = 0; n < 4; ++n) acc[m][n] = (f32x4){0.f, 0.f, 0.f, 0.f};
  for (int kb = 0; kb < FEAT; kb += 64) {
    #pragma unroll
    for (int c = 0; c < 4; ++c) {
      int f = c * 256 + tid;
      int row = f >> 3, s = f & 7;
      int sc = (s ^ (row & 7)) << 3;
      gload16(Ag + (size_t)row * FEAT + kb + sc, Als + ((c * 256 + wid * 64) << 3));
      gload16(Bg + (size_t)row * FEAT + kb + sc, Bls + ((c * 256 + wid * 64) << 3));
    }
    __syncthreads();
    #pragma unroll
    for (int ks = 0; ks < 2; ++ks) {
      bf16x8 af[4], bfr[4];
      #pragma unroll
      for (int m = 0; m < 4; ++m) {
        int row = wr * 64 + m * 16 + (lane & 15);
        int kq = ks * 32 + (lane >> 4) * 8;
        int idx = (row * 64 + kq) ^ ((row & 7) << 3);
        af[m] = *(const bf16x8*)(&Als[idx]);
      }
      #pragma unroll
      for (int n = 0; n < 4; ++n) {
        int row = wc * 64 + n * 16 + (lane & 15);
        int kq = ks * 32 + (lane >> 4) * 8;
        int idx = (row * 64 + kq) ^ ((row & 7) << 3);
        bfr[n] = *(const bf16x8*)(&Bls[idx]);
      }
      #pragma unroll
      for (int m = 0; m < 4; ++m)
        #pragma unroll
        for (int n = 0; n < 4; ++n)
          acc[m][n] = __builtin_amdgcn_mfma_f32_16x16x32_bf16(af[m], bfr[n], acc[m][n], 0, 0, 0);
    }
    __syncthreads();
  }
  const float SC = 0.04419417382415922f;   // sqrt(2/1024)
  float rbl[4];
  #pragma unroll
  for (int n = 0; n < 4; ++n) rbl[n] = rb[i0 + wc * 64 + n * 16 + (lane & 15)];
  #pragma unroll
  for (int m = 0; m < 4; ++m) {
    #pragma unroll
    for (int n = 0; n < 4; ++n) {
      #pragma unroll
      for (int r = 0; r < 4; ++r) {
        int lb = wr * 64 + m * 16 + (lane >> 4) * 4 + r;
        int li = wc * 64 + n * 16 + (lane & 15);
        float proj = 2.0f * (acc[m][n][r] + rbl[n]);
        u16 bv = (u16)f2bf(SC * cosf(proj));
        phiB[(size_t)(b0 + lb) * NIND + i0 + li] = bv;
        int idx = (li * 128 + lb) ^ ((li & 7) << 3);
        sh[idx] = bv;
      }
    }
  }
  __syncthreads();
  #pragma unroll
  for (int t = 0; t < 8; ++t) {
    int f = t * 256 + tid;             // 2048 uint4-slots over 128x128 u16
    int li = f >> 4, c8 = (f & 15) << 3;
    int idx = (li * 128 + c8) ^ ((li & 7) << 3);
    uint4 v = *(const uint4*)(&sh[idx]);
    *(uint4*)(phiTB + (size_t)(i0 + li) * BATCH + b0 + c8) = v;
  }
}

// K2 v3: logits from phiB (bf16), 16 batch rows per block, thread = (row, class)
__global__ __launch_bounds__(256) void logits_kernel(
    const u16* __restrict__ phiB, const float* __restrict__ bw,
    const float* __restrict__ bbias, float* __restrict__ out,
    float* __restrict__ wmat)
{
  __shared__ float ph[16][132];
  __shared__ float bwl[16][132];
  __shared__ float lg[16][17];
  const int b0 = blockIdx.x * 16;
  const int tid = threadIdx.x;
  const int bl = tid & 15, kq = tid >> 4;
  float acc = 0.f;
  for (int kb = 0; kb < NIND; kb += 128) {
    {
      int row = tid >> 4, c8 = (tid & 15) << 3;
      uint4 v = *(const uint4*)(phiB + (size_t)(b0 + row) * NIND + kb + c8);
      const unsigned* u = (const unsigned*)&v;
      #pragma unroll
      for (int j = 0; j < 4; ++j) {
        ph[row][c8 + 2*j]     = bflo(u[j]);
        ph[row][c8 + 2*j + 1] = bfhi(u[j]);
      }
    }
    #pragma unroll
    for (int t = 0; t < 2; ++t) {
      int f = t * 256 + tid;
      int row = f >> 5, c4 = (f & 31) << 2;
      *(float4*)(&bwl[row][c4]) = *(const float4*)(bw + (size_t)row * NIND + kb + c4);
    }
    __syncthreads();
    #pragma unroll 8
    for (int q = 0; q < 128; q += 4) {
      float4 a = *(const float4*)(&ph[bl][q]);
      float4 b4 = *(const float4*)(&bwl[kq][q]);
      acc += a.x*b4.x + a.y*b4.y + a.z*b4.z + a.w*b4.w;
    }
    __syncthreads();
  }
  float v = acc + bbias[kq];
  lg[bl][kq] = v;
  out[(size_t)(b0 + bl) * NCLS + kq] = v;
  __syncthreads();
  if (tid < 16) {
    float mx = -1e30f;
    #pragma unroll
    for (int k = 0; k < 16; ++k) mx = fmaxf(mx, lg[tid][k]);
    float s = 0.f, ex[16];
    #pragma unroll
    for (int k = 0; k < 16; ++k) { ex[k] = expf(lg[tid][k] - mx); s += ex[k]; }
    float inv = 1.0f / s;
    #pragma unroll
    for (int k = 0; k < 16; ++k) {
      float p = ex[k] * inv;
      wmat[(size_t)k * BATCH + b0 + tid] = p * (1.0f - p);
    }
  }
}

// K2b: phiW[k][i][b] = bf16(wmat[k][b] * phi[i][b])  (from bf16 phiTB)
__global__ __launch_bounds__(256) void scalew_kernel(
    const u16* __restrict__ phiTB, const float* __restrict__ wmat,
    u16* __restrict__ phiW)
{
  const int k = blockIdx.y;
  size_t flat = ((size_t)blockIdx.x * 256 + threadIdx.x) * 8;
  int b = (int)(flat & 2047);
  uint4 pv = *(const uint4*)(phiTB + flat);
  float4 w0 = *(const float4*)(wmat + (size_t)k * BATCH + b);
  float4 w1 = *(const float4*)(wmat + (size_t)k * BATCH + b + 4);
  float wv[8] = {w0.x, w0.y, w0.z, w0.w, w1.x, w1.y, w1.z, w1.w};
  *(uint4*)(phiW + (size_t)k * NIND * BATCH + flat) = scale8(pv, wv);
}

// K3 v7: MFMA bf16 gram -> Pb bf16. Padded 8x8 tile grid with ti = bx&7 so that
// XCD = linear_id%8 = ti: all blocks sharing a phiW A-panel (k,ti) land on the
// same XCD -> A-panel L2-resident. Upper-triangle blocks (tj>ti) exit early.
__global__ __launch_bounds__(256) void gram_kernel(
    const u16* __restrict__ phiW, const u16* __restrict__ phiTB,
    const float* __restrict__ prec, u16* __restrict__ Pb)
{
  __shared__ u16 Als[128 * 64];
  __shared__ u16 Bls[128 * 64];
  const int ti = blockIdx.x & 7, tj = blockIdx.x >> 3;
  if (tj > ti) return;
  const int k = blockIdx.y;
  const int i0 = ti * 128, j0 = tj * 128;
  const bool diag = (ti == tj);
  const int tid = threadIdx.x;
  const int wid = tid >> 6, lane = tid & 63;
  const int wr = wid >> 1, wc = wid & 1;
  const u16* Ag = phiW + (size_t)k * NIND * BATCH + (size_t)i0 * BATCH;
  const u16* Bg = phiTB + (size_t)j0 * BATCH;
  f32x4 acc[4][4];
  #pragma unroll
  for (int m = 0; m < 4; ++m)
    #pragma unroll
    for (int n = 0; n < 4; ++n) acc[m][n] = (f32x4){0.f, 0.f, 0.f, 0.f};
  for (int b0 = 0; b0 < BATCH; b0 += 64) {
    #pragma unroll
    for (int c = 0; c < 4; ++c) {
      int f = c * 256 + tid;
      int row = f >> 3, s = f & 7;
      int sc = (s ^ (row & 7)) << 3;
      gload16(Ag + (size_t)row * BATCH + b0 + sc, Als + ((c * 256 + wid * 64) << 3));
      gload16(Bg + (size_t)row * BATCH + b0 + sc, Bls + ((c * 256 + wid * 64) << 3));
    }
    __syncthreads();
    #pragma unroll
    for (int ks = 0; ks < 2; ++ks) {
      bf16x8 af[4], bfr[4];
      #pragma unroll
      for (int m = 0; m < 4; ++m) {
        int row = wr * 64 + m * 16 + (lane & 15);
        int kb = ks * 32 + (lane >> 4) * 8;
        int idx = (row * 64 + kb) ^ ((row & 7) << 3);
        af[m] = *(const bf16x8*)(&Als[idx]);
      }
      #pragma unroll
      for (int n = 0; n < 4; ++n) {
        int row = wc * 64 + n * 16 + (lane & 15);
        int kb = ks * 32 + (lane >> 4) * 8;
        int idx = (row * 64 + kb) ^ ((row & 7) << 3);
        bfr[n] = *(const bf16x8*)(&Bls[idx]);
      }
      #pragma unroll
      for (int m = 0; m < 4; ++m)
        #pragma unroll
        for (int n = 0; n < 4; ++n)
          acc[m][n] = __builtin_amdgcn_mfma_f32_16x16x32_bf16(af[m], bfr[n], acc[m][n], 0, 0, 0);
    }
    __syncthreads();
  }
  const size_t kb2 = (size_t)k * NIND * NIND;
  #pragma unroll
  for (int m = 0; m < 4; ++m) {
    #pragma unroll
    for (int n = 0; n < 4; ++n) {
      #pragma unroll
      for (int r = 0; r < 4; ++r) {
        int gi = i0 + wr * 64 + m * 16 + (lane >> 4) * 4 + r;
        int gj = j0 + wc * 64 + n * 16 + (lane & 15);
        size_t idx = kb2 + (size_t)gi * NIND + gj;
        float v = acc[m][n][r] + prec[idx];
        u16 bv = (u16)f2bf(v);
        Pb[idx] = bv;
        if (!diag) Pb[kb2 + (size_t)gj * NIND + gi] = bv;
      }
    }
  }
}

// K4: Gershgorin bound per class: gmax[k] = max_i sum_j |P_ij| (certified >= lambda_max)
__global__ __launch_bounds__(256) void gersh_kernel(
    const u16* __restrict__ Pb, unsigned* __restrict__ gmax)
{
  __shared__ float psum[64][17];
  const int k = blockIdx.y, rbk = blockIdx.x;
  const int tid = threadIdx.x;
  const size_t mb = (size_t)k * NIND * NIND;
  #pragma unroll
  for (int p = 0; p < 4; ++p) {
    int rl = p * 16 + (tid >> 4);
    int row = rbk * 64 + rl;
    int ch = tid & 15;
    float s = 0.f;
    const u16* base = Pb + mb + (size_t)row * NIND + ch * 64;
    #pragma unroll
    for (int c8 = 0; c8 < 8; ++c8) {
      uint4 u = *(const uint4*)(base + c8 * 8);
      const unsigned* uu = (const unsigned*)&u;
      #pragma unroll
      for (int q = 0; q < 4; ++q)
        s += fabsf(bflo(uu[q])) + fabsf(bfhi(uu[q]));
    }
    psum[rl][ch] = s;
  }
  __syncthreads();
  if (tid < 64) {
    float s = 0.f;
    #pragma unroll
    for (int j = 0; j < 16; ++j) s += psum[tid][j];
    psum[tid][16] = s;
  }
  __syncthreads();
  if (tid == 0) {
    float mx = 0.f;
    for (int t = 0; t < 64; ++t) mx = fmaxf(mx, psum[t][16]);
    atomicMax(gmax + k, __float_as_uint(mx));
  }
}

// K5: Chebyshev degree-2 initializer: X1 = b2*P^2 + b1*P + b0*I
__global__ __launch_bounds__(256) void cheb_kernel(
    const u16* __restrict__ Pb, const u16* __restrict__ Psq,
    const unsigned* __restrict__ gmax, u16* __restrict__ X)
{
  const int k = blockIdx.y;
  float G = __uint_as_float(gmax[k]) * 1.001f + 0.01f;
  if (G < 1.05f) G = 1.05f;
  float s = G + 1.0f, dd = G - 1.0f;
  float D3 = 4.0f * s * s * s - 3.0f * s * dd * dd;
  float b2 = 32.0f / D3;
  float b1 = -48.0f * s / D3;
  float b0 = (24.0f * s * s - 6.0f * dd * dd) / D3;
  size_t flat = ((size_t)blockIdx.x * 256 + threadIdx.x) * 8;
  int i = (int)(flat >> 10), j0 = (int)(flat & 1023);
  const size_t mb = (size_t)k * NIND * NIND;
  uint4 up = *(const uint4*)(Pb + mb + flat);
  uint4 uq = *(const uint4*)(Psq + mb + flat);
  const unsigned* pp = (const unsigned*)&up;
  const unsigned* qq = (const unsigned*)&uq;
  unsigned ow[4];
  #pragma unroll
  for (int q = 0; q < 4; ++q) {
    float lo = b2 * bflo(qq[q]) + b1 * bflo(pp[q]);
    float hi = b2 * bfhi(qq[q]) + b1 * bfhi(pp[q]);
    int cj = j0 + 2 * q;
    if (i == cj) lo += b0;
    if (i == cj + 1) hi += b0;
    ow[q] = (f2bf(lo) & 0xFFFFu) | (f2bf(hi) << 16);
  }
  *(uint4*)(X + mb + flat) = uint4{ow[0], ow[1], ow[2], ow[3]};
}

// K6: C = A (*) B^T; mode 1: C = 2*Xadd - A(*)B^T. Full 64 tiles, XCD swizzle.
__global__ __launch_bounds__(256) void ntgemm_kernel(
    const u16* __restrict__ A, const u16* __restrict__ B,
    const u16* __restrict__ Xadd, u16* __restrict__ C, int mode)
{
  __shared__ u16 Als[128 * 64];
  __shared__ u16 Bls[128 * 64];
  const int k = blockIdx.y;
  const int ti = blockIdx.x & 7, tj = blockIdx.x >> 3;   // XCD swizzle (T1)
  const int i0 = ti * 128, j0 = tj * 128;
  const int tid = threadIdx.x;
  const int wid = tid >> 6, lane = tid & 63;
  const int wr = wid >> 1, wc = wid & 1;
  const size_t mb = (size_t)k * NIND * NIND;
  const u16* Ag = A + mb + (size_t)i0 * NIND;
  const u16* Bg = B + mb + (size_t)j0 * NIND;
  f32x4 acc[4][4];
  #pragma unroll
  for (int m = 0; m < 4; ++m)
    #pragma unroll
    for (int n = 0; n < 4; ++n) acc[m][n] = (f32x4){0.f, 0.f, 0.f, 0.f};
  for (int kb = 0; kb < NIND; kb += 64) {
    #pragma unroll
    for (int c = 0; c < 4; ++c) {
      int f = c * 256 + tid;
      int row = f >> 3, s = f & 7;
      int sc = (s ^ (row & 7)) << 3;
      gload16(Ag + (size_t)row * NIND + kb + sc, Als + ((c * 256 + wid * 64) << 3));
      gload16(Bg + (size_t)row * NIND + kb + sc, Bls + ((c * 256 + wid * 64) << 3));
    }
    __syncthreads();
    #pragma unroll
    for (int ks = 0; ks < 2; ++ks) {
      bf16x8 af[4], bfr[4];
      #pragma unroll
      for (int m = 0; m < 4; ++m) {
        int row = wr * 64 + m * 16 + (lane & 15);
        int kq = ks * 32 + (lane >> 4) * 8;
        int idx = (row * 64 + kq) ^ ((row & 7) << 3);
        af[m] = *(const bf16x8*)(&Als[idx]);
      }
      #pragma unroll
      for (int n = 0; n < 4; ++n) {
        int row = wc * 64 + n * 16 + (lane & 15);
        int kq = ks * 32 + (lane >> 4) * 8;
        int idx = (row * 64 + kq) ^ ((row & 7) << 3);
        bfr[n] = *(const bf16x8*)(&Bls[idx]);
      }
      #pragma unroll
      for (int m = 0; m < 4; ++m)
        #pragma unroll
        for (int n = 0; n < 4; ++n)
          acc[m][n] = __builtin_amdgcn_mfma_f32_16x16x32_bf16(af[m], bfr[n], acc[m][n], 0, 0, 0);
    }
    __syncthreads();
  }
  #pragma unroll
  for (int m = 0; m < 4; ++m) {
    #pragma unroll
    for (int n = 0; n < 4; ++n) {
      #pragma unroll
      for (int r = 0; r < 4; ++r) {
        int gi = i0 + wr * 64 + m * 16 + (lane >> 4) * 4 + r;
        int gj = j0 + wc * 64 + n * 16 + (lane & 15);
        size_t idx = mb + (size_t)gi * NIND + gj;
        float v = acc[m][n][r];
        if (mode) v = 2.0f * bflo((unsigned)Xadd[idx]) - v;
        C[idx] = (u16)f2bf(v);
      }
    }
  }
}

// K7: variance GEMM: C = phi (*) M^T; epilogue * phi[b][i], row-reduce -> partial
__global__ __launch_bounds__(256) void vgemm_kernel(
    const u16* __restrict__ phiB, const u16* __restrict__ M,
    float* __restrict__ partial)
{
  __shared__ u16 Als[128 * 64];
  __shared__ u16 Bls[128 * 64];
  __shared__ float red[128][33];
  const int btile = blockIdx.x >> 3, It = blockIdx.x & 7;
  const int k = blockIdx.y;
  const int b0 = btile * 128, i0 = It * 128;
  const int tid = threadIdx.x;
  const int wid = tid >> 6, lane = tid & 63;
  const int wr = wid >> 1, wc = wid & 1;
  const int q = lane >> 4, l15 = lane & 15;
  const u16* Ag = phiB + (size_t)b0 * NIND;
  const u16* Bg = M + (size_t)k * NIND * NIND + (size_t)i0 * NIND;
  f32x4 acc[4][4];
  #pragma unroll
  for (int m = 0; m < 4; ++m)
    #pragma unroll
    for (int n = 0; n < 4; ++n) acc[m][n] = (f32x4){0.f, 0.f, 0.f, 0.f};
  for (int kb = 0; kb < NIND; kb += 64) {
    #pragma unroll
    for (int c = 0; c < 4; ++c) {
      int f = c * 256 + tid;
      int row = f >> 3, s = f & 7;
      int sc = (s ^ (row & 7)) << 3;
      gload16(Ag + (size_t)row * NIND + kb + sc, Als + ((c * 256 + wid * 64) << 3));
      gload16(Bg + (size_t)row * NIND + kb + sc, Bls + ((c * 256 + wid * 64) << 3));
    }
    __syncthreads();
    #pragma unroll
    for (int ks = 0; ks < 2; ++ks) {
      bf16x8 af[4], bfr[4];
      #pragma unroll
      for (int m = 0; m < 4; ++m) {
        int row = wr * 64 + m * 16 + l15;
        int kq = ks * 32 + q * 8;
        int idx = (row * 64 + kq) ^ ((row & 7) << 3);
        af[m] = *(const bf16x8*)(&Als[idx]);
      }
      #pragma unroll
      for (int n = 0; n < 4; ++n) {
        int row = wc * 64 + n * 16 + l15;
        int kq = ks * 32 + q * 8;
        int idx = (row * 64 + kq) ^ ((row & 7) << 3);
        bfr[n] = *(const bf16x8*)(&Bls[idx]);
      }
      #pragma unroll
      for (int m = 0; m < 4; ++m)
        #pragma unroll
        for (int n = 0; n < 4; ++n)
          acc[m][n] = __builtin_amdgcn_mfma_f32_16x16x32_bf16(af[m], bfr[n], acc[m][n], 0, 0, 0);
    }
    __syncthreads();
  }
  float vs[4][4] = {};
  #pragma unroll
  for (int m = 0; m < 4; ++m) {
    #pragma unroll
    for (int r = 0; r < 4; ++r) {
      int gb = b0 + wr * 64 + m * 16 + q * 4 + r;
      #pragma unroll
      for (int n = 0; n < 4; ++n) {
        int gi = i0 + wc * 64 + n * 16 + l15;
        float pv = bflo((unsigned)phiB[(size_t)gb * NIND + gi]);
        vs[m][r] += acc[m][n][r] * pv;
      }
    }
  }
  #pragma unroll
  for (int m = 0; m < 4; ++m)
    #pragma unroll
    for (int r = 0; r < 4; ++r)
      red[wr * 64 + m * 16 + q * 4 + r][wc * 16 + l15] = vs[m][r];
  __syncthreads();
  if (tid < 128) {
    float s = 0.f;
    #pragma unroll
    for (int t = 0; t < 32; ++t) s += red[tid][t];
    partial[((size_t)It * NCLS + k) * BATCH + b0 + tid] = s;
  }
}

// K8: out variances[b][k] = sum_It partial[It][k][b]
__global__ __launch_bounds__(256) void reduce_kernel(
    const float* __restrict__ partial, float* __restrict__ out)
{
  int t = blockIdx.x * 256 + threadIdx.x;
  int k = t >> 11, b = t & 2047;
  float s = 0.f;
  #pragma unroll
  for (int It = 0; It < 8; ++It)
    s += partial[((size_t)It * NCLS + k) * BATCH + b];
  out[(size_t)BATCH * NCLS + (size_t)b * NCLS + k] = s;
}

extern "C" void kernel_launch(void* const* d_in, const int* in_sizes, int n_in,
                              void* d_out, int out_size, void* d_ws, size_t ws_size,
                              hipStream_t stream)
{
  (void)in_sizes; (void)n_in; (void)ws_size;
  const float* x   = (const float*)d_in[0];
  const float* rw  = (const float*)d_in[1];
  const float* rb  = (const float*)d_in[2];
  const float* bw  = (const float*)d_in[3];
  const float* bb  = (const float*)d_in[4];
  const float* prc = (const float*)d_in[5];
  float* out = (float*)d_out;
  char* ws = (char*)d_ws;
  size_t off = 0;
  auto alloc = [&](size_t bytes) -> void* {
    void* p = ws + off;
    off = (off + bytes + 255) & ~(size_t)255;
    return p;
  };
  const size_t MSZ = (size_t)NCLS * NIND * NIND * 2;   // 32MB bf16 matrix
  u16*   xB     = (u16*)  alloc((size_t)BATCH * FEAT * 2);
  u16*   rwT    = (u16*)  alloc((size_t)NIND * FEAT * 2);
  u16*   phiB   = (u16*)  alloc((size_t)BATCH * NIND * 2);
  u16*   phiTB  = (u16*)  alloc((size_t)NIND * BATCH * 2);
  float* wmat   = (float*)alloc((size_t)NCLS * BATCH * 4);
  u16*   Pb     = (u16*)  alloc(MSZ);
  unsigned* gbound = (unsigned*)alloc((size_t)NCLS * 4);
  float* partial = (float*)alloc((size_t)8 * NCLS * BATCH * 4);
  u16*   Xa     = (u16*)alloc(MSZ);
  u16*   B2     = (u16*)alloc(MSZ);
  u16*   BY     = (u16*)alloc(MSZ);
  // phiW (64MB) aliases Xa+B2 (contiguous): dead before cheb writes Xa.
  u16*   phiW   = Xa;

  hipMemsetAsync(d_out, 0, (size_t)out_size * sizeof(float), stream);
  hipMemsetAsync(gbound, 0, (size_t)NCLS * 4, stream);
  xcast_kernel<<<dim3(BATCH * FEAT / 2048), 256, 0, stream>>>(x, xB);
  rwt_kernel<<<dim3(FEAT / 64, NIND / 64), 256, 0, stream>>>(rw, rwT);
  phimm_kernel<<<dim3(BATCH / 128, NIND / 128), 256, 0, stream>>>(xB, rwT, rb, phiB, phiTB);
  logits_kernel<<<dim3(BATCH / 16), 256, 0, stream>>>(phiB, bw, bb, out, wmat);
  scalew_kernel<<<dim3(1024, NCLS), 256, 0, stream>>>(phiTB, wmat, phiW);
  gram_kernel<<<dim3(64, NCLS), 256, 0, stream>>>(phiW, phiTB, prc, Pb);
  gersh_kernel<<<dim3(16, NCLS), 256, 0, stream>>>(Pb, gbound);
  const dim3 gg(64, NCLS);
  // Chebyshev degree-2 init: BY = P^2, then X1 = b2*P^2 + b1*P + b0*I
  ntgemm_kernel<<<gg, 256, 0, stream>>>(Pb, Pb, (u16*)nullptr, BY, 0);   // BY = P^2
  cheb_kernel<<<dim3(512, NCLS), 256, 0, stream>>>(Pb, BY, gbound, Xa);
  // 2 Newton iterations: BY = X*P ; X' = 2X - X*BY^T
  ntgemm_kernel<<<gg, 256, 0, stream>>>(Xa, Pb, (u16*)nullptr, BY, 0);
  ntgemm_kernel<<<gg, 256, 0, stream>>>(Xa, BY, Xa, B2, 1);
  ntgemm_kernel<<<gg, 256, 0, stream>>>(B2, Pb, (u16*)nullptr, BY, 0);
  ntgemm_kernel<<<gg, 256, 0, stream>>>(B2, BY, B2, Xa, 1);
  // variances: var_b = phi^T M phi, M = Xa
  vgemm_kernel<<<dim3(128, NCLS), 256, 0, stream>>>(phiB, Xa, partial);
  reduce_kernel<<<dim3(128), 256, 0, stream>>>(partial, out);
}

// Round 17
// 588.432 us; speedup vs baseline: 1.6774x; 1.0502x over previous
//
#include <hip/hip_runtime.h>
#include <hip/hip_bf16.h>

#define BATCH 2048
#define FEAT  768
#define NIND  1024
#define NCLS  16

typedef unsigned short u16;
typedef __attribute__((ext_vector_type(8))) __bf16 bf16x8;
typedef __attribute__((ext_vector_type(4))) float f32x4;

static __device__ __forceinline__ unsigned f2bf(float f) {
  unsigned u = __float_as_uint(f);
  unsigned r = ((u >> 16) & 1u) + 0x7FFFu;
  return (u + r) >> 16;                       // RNE bf16 in low 16 bits
}
static __device__ __forceinline__ float bflo(unsigned x) {
  return __uint_as_float((x & 0xFFFFu) << 16);
}
static __device__ __forceinline__ float bfhi(unsigned x) {
  return __uint_as_float(x & 0xFFFF0000u);
}

// async 16B global->LDS (LDS dest = wave-uniform base + lane*16)
static __device__ __forceinline__ void gload16(const u16* g, u16* l) {
  __builtin_amdgcn_global_load_lds(
      (const __attribute__((address_space(1))) void*)g,
      (__attribute__((address_space(3))) void*)l, 16, 0, 0);
}

// pack 8 bf16 (as uint4) scaled by wv[0..7] back to 8 bf16 (uint4)
static __device__ __forceinline__ uint4 scale8(uint4 v, const float* wv) {
  unsigned out[4];
  const unsigned* in = (const unsigned*)&v;
  #pragma unroll
  for (int i = 0; i < 4; ++i) {
    float lo = bflo(in[i]) * wv[2*i];
    float hi = bfhi(in[i]) * wv[2*i+1];
    __hip_bfloat162 pk = __float22bfloat162_rn(float2{lo, hi});
    out[i] = *(unsigned*)&pk;
  }
  return uint4{out[0], out[1], out[2], out[3]};
}

// K0a: xB = bf16(x), elementwise
__global__ __launch_bounds__(256) void xcast_kernel(
    const float* __restrict__ x, u16* __restrict__ xB)
{
  size_t f = ((size_t)blockIdx.x * 256 + threadIdx.x) * 8;
  float4 a = *(const float4*)(x + f);
  float4 b = *(const float4*)(x + f + 4);
  uint4 o;
  o.x = (f2bf(a.x) & 0xFFFFu) | (f2bf(a.y) << 16);
  o.y = (f2bf(a.z) & 0xFFFFu) | (f2bf(a.w) << 16);
  o.z = (f2bf(b.x) & 0xFFFFu) | (f2bf(b.y) << 16);
  o.w = (f2bf(b.z) & 0xFFFFu) | (f2bf(b.w) << 16);
  *(uint4*)(xB + f) = o;
}

// K0b: rwT[i][k] = bf16(rw[k][i])  (LDS-tiled transpose)
__global__ __launch_bounds__(256) void rwt_kernel(
    const float* __restrict__ rw, u16* __restrict__ rwT)
{
  __shared__ float ts[64][65];
  const int k0 = blockIdx.x * 64, i0 = blockIdx.y * 64;
  const int tid = threadIdx.x;
  #pragma unroll
  for (int t = 0; t < 4; ++t) {
    int f = t * 256 + tid;
    int r = f >> 4, c4 = (f & 15) << 2;
    *(float4*)(&ts[r][c4]) = *(const float4*)(rw + (size_t)(k0 + r) * NIND + i0 + c4);
  }
  __syncthreads();
  #pragma unroll
  for (int t = 0; t < 4; ++t) {
    int f = t * 256 + tid;
    int r = f >> 4, c4 = (f & 15) << 2;   // r = i-local, c4 = k-local base
    uint2 o;
    o.x = (f2bf(ts[c4+0][r]) & 0xFFFFu) | (f2bf(ts[c4+1][r]) << 16);
    o.y = (f2bf(ts[c4+2][r]) & 0xFFFFu) | (f2bf(ts[c4+3][r]) << 16);
    *(uint2*)(rwT + (size_t)(i0 + r) * FEAT + k0 + c4) = o;
  }
}

// K1: MFMA phi. phiB[b][i], phiTB[i][b] = bf16(SC*cos(2*(x@W+b))). K=768.
__global__ __launch_bounds__(256) void phimm_kernel(
    const u16* __restrict__ xB, const u16* __restrict__ rwT,
    const float* __restrict__ rb, u16* __restrict__ phiB,
    u16* __restrict__ phiTB)
{
  __shared__ u16 sh[128 * 128];      // staging (2x 128x64) then transpose tile
  u16* Als = sh;
  u16* Bls = sh + 8192;
  const int b0 = blockIdx.x * 128, i0 = blockIdx.y * 128;
  const int tid = threadIdx.x;
  const int wid = tid >> 6, lane = tid & 63;
  const int wr = wid >> 1, wc = wid & 1;
  const u16* Ag = xB + (size_t)b0 * FEAT;
  const u16* Bg = rwT + (size_t)i0 * FEAT;
  f32x4 acc[4][4];
  #pragma unroll
  for (int m = 0; m < 4; ++m)
    #pragma unroll
    for (int n = 0; n < 4; ++n) acc[m][n] = (f32x4){0.f, 0.f, 0.f, 0.f};
  for (int kb = 0; kb < FEAT; kb += 64) {
    #pragma unroll
    for (int c = 0; c < 4; ++c) {
      int f = c * 256 + tid;
      int row = f >> 3, s = f & 7;
      int sc = (s ^ (row & 7)) << 3;
      gload16(Ag + (size_t)row * FEAT + kb + sc, Als + ((c * 256 + wid * 64) << 3));
      gload16(Bg + (size_t)row * FEAT + kb + sc, Bls + ((c * 256 + wid * 64) << 3));
    }
    __syncthreads();
    #pragma unroll
    for (int ks = 0; ks < 2; ++ks) {
      bf16x8 af[4], bfr[4];
      #pragma unroll
      for (int m = 0; m < 4; ++m) {
        int row = wr * 64 + m * 16 + (lane & 15);
        int kq = ks * 32 + (lane >> 4) * 8;
        int idx = (row * 64 + kq) ^ ((row & 7) << 3);
        af[m] = *(const bf16x8*)(&Als[idx]);
      }
      #pragma unroll
      for (int n = 0; n < 4; ++n) {
        int row = wc * 64 + n * 16 + (lane & 15);
        int kq = ks * 32 + (lane >> 4) * 8;
        int idx = (row * 64 + kq) ^ ((row & 7) << 3);
        bfr[n] = *(const bf16x8*)(&Bls[idx]);
      }
      #pragma unroll
      for (int m = 0; m < 4; ++m)
        #pragma unroll
        for (int n = 0; n < 4; ++n)
          acc[m][n] = __builtin_amdgcn_mfma_f32_16x16x32_bf16(af[m], bfr[n], acc[m][n], 0, 0, 0);
    }
    __syncthreads();
  }
  const float SC = 0.04419417382415922f;   // sqrt(2/1024)
  float rbl[4];
  #pragma unroll
  for (int n = 0; n < 4; ++n) rbl[n] = rb[i0 + wc * 64 + n * 16 + (lane & 15)];
  #pragma unroll
  for (int m = 0; m < 4; ++m) {
    #pragma unroll
    for (int n = 0; n < 4; ++n) {
      #pragma unroll
      for (int r = 0; r < 4; ++r) {
        int lb = wr * 64 + m * 16 + (lane >> 4) * 4 + r;
        int li = wc * 64 + n * 16 + (lane & 15);
        float proj = 2.0f * (acc[m][n][r] + rbl[n]);
        u16 bv = (u16)f2bf(SC * cosf(proj));
        phiB[(size_t)(b0 + lb) * NIND + i0 + li] = bv;
        int idx = (li * 128 + lb) ^ ((li & 7) << 3);
        sh[idx] = bv;
      }
    }
  }
  __syncthreads();
  #pragma unroll
  for (int t = 0; t < 8; ++t) {
    int f = t * 256 + tid;             // 2048 uint4-slots over 128x128 u16
    int li = f >> 4, c8 = (f & 15) << 3;
    int idx = (li * 128 + c8) ^ ((li & 7) << 3);
    uint4 v = *(const uint4*)(&sh[idx]);
    *(uint4*)(phiTB + (size_t)(i0 + li) * BATCH + b0 + c8) = v;
  }
}

// K2: logits from phiB (bf16), 16 batch rows per block, thread = (row, class)
__global__ __launch_bounds__(256) void logits_kernel(
    const u16* __restrict__ phiB, const float* __restrict__ bw,
    const float* __restrict__ bbias, float* __restrict__ out,
    float* __restrict__ wmat)
{
  __shared__ float ph[16][132];
  __shared__ float bwl[16][132];
  __shared__ float lg[16][17];
  const int b0 = blockIdx.x * 16;
  const int tid = threadIdx.x;
  const int bl = tid & 15, kq = tid >> 4;
  float acc = 0.f;
  for (int kb = 0; kb < NIND; kb += 128) {
    {
      int row = tid >> 4, c8 = (tid & 15) << 3;
      uint4 v = *(const uint4*)(phiB + (size_t)(b0 + row) * NIND + kb + c8);
      const unsigned* u = (const unsigned*)&v;
      #pragma unroll
      for (int j = 0; j < 4; ++j) {
        ph[row][c8 + 2*j]     = bflo(u[j]);
        ph[row][c8 + 2*j + 1] = bfhi(u[j]);
      }
    }
    #pragma unroll
    for (int t = 0; t < 2; ++t) {
      int f = t * 256 + tid;
      int row = f >> 5, c4 = (f & 31) << 2;
      *(float4*)(&bwl[row][c4]) = *(const float4*)(bw + (size_t)row * NIND + kb + c4);
    }
    __syncthreads();
    #pragma unroll 8
    for (int q = 0; q < 128; q += 4) {
      float4 a = *(const float4*)(&ph[bl][q]);
      float4 b4 = *(const float4*)(&bwl[kq][q]);
      acc += a.x*b4.x + a.y*b4.y + a.z*b4.z + a.w*b4.w;
    }
    __syncthreads();
  }
  float v = acc + bbias[kq];
  lg[bl][kq] = v;
  out[(size_t)(b0 + bl) * NCLS + kq] = v;
  __syncthreads();
  if (tid < 16) {
    float mx = -1e30f;
    #pragma unroll
    for (int k = 0; k < 16; ++k) mx = fmaxf(mx, lg[tid][k]);
    float s = 0.f, ex[16];
    #pragma unroll
    for (int k = 0; k < 16; ++k) { ex[k] = expf(lg[tid][k] - mx); s += ex[k]; }
    float inv = 1.0f / s;
    #pragma unroll
    for (int k = 0; k < 16; ++k) {
      float p = ex[k] * inv;
      wmat[(size_t)k * BATCH + b0 + tid] = p * (1.0f - p);
    }
  }
}

// K2b: phiW[k][i][b] = bf16(wmat[k][b] * phi[i][b])  (from bf16 phiTB)
__global__ __launch_bounds__(256) void scalew_kernel(
    const u16* __restrict__ phiTB, const float* __restrict__ wmat,
    u16* __restrict__ phiW)
{
  const int k = blockIdx.y;
  size_t flat = ((size_t)blockIdx.x * 256 + threadIdx.x) * 8;
  int b = (int)(flat & 2047);
  uint4 pv = *(const uint4*)(phiTB + flat);
  float4 w0 = *(const float4*)(wmat + (size_t)k * BATCH + b);
  float4 w1 = *(const float4*)(wmat + (size_t)k * BATCH + b + 4);
  float wv[8] = {w0.x, w0.y, w0.z, w0.w, w1.x, w1.y, w1.z, w1.w};
  *(uint4*)(phiW + (size_t)k * NIND * BATCH + flat) = scale8(pv, wv);
}

// K3 v8: MFMA bf16 gram -> Pb bf16. FULL 64-tile grid, every tile computed
// directly (no mirror writes, no early exit): 1024 active blocks = 4/CU to
// hide the 2-barrier-per-K-step latency (R16 showed locality alone is not
// the bottleneck). Slight P asymmetry (~bf16 noise) is harmless: Newton
// contracts under ||I-XP|| and the final quadratic form only sees sym(M).
__global__ __launch_bounds__(256) void gram_kernel(
    const u16* __restrict__ phiW, const u16* __restrict__ phiTB,
    const float* __restrict__ prec, u16* __restrict__ Pb)
{
  __shared__ u16 Als[128 * 64];
  __shared__ u16 Bls[128 * 64];
  const int ti = blockIdx.x & 7, tj = blockIdx.x >> 3;   // XCD = ti
  const int k = blockIdx.y;
  const int i0 = ti * 128, j0 = tj * 128;
  const int tid = threadIdx.x;
  const int wid = tid >> 6, lane = tid & 63;
  const int wr = wid >> 1, wc = wid & 1;
  const u16* Ag = phiW + (size_t)k * NIND * BATCH + (size_t)i0 * BATCH;
  const u16* Bg = phiTB + (size_t)j0 * BATCH;
  f32x4 acc[4][4];
  #pragma unroll
  for (int m = 0; m < 4; ++m)
    #pragma unroll
    for (int n = 0; n < 4; ++n) acc[m][n] = (f32x4){0.f, 0.f, 0.f, 0.f};
  for (int b0 = 0; b0 < BATCH; b0 += 64) {
    #pragma unroll
    for (int c = 0; c < 4; ++c) {
      int f = c * 256 + tid;
      int row = f >> 3, s = f & 7;
      int sc = (s ^ (row & 7)) << 3;
      gload16(Ag + (size_t)row * BATCH + b0 + sc, Als + ((c * 256 + wid * 64) << 3));
      gload16(Bg + (size_t)row * BATCH + b0 + sc, Bls + ((c * 256 + wid * 64) << 3));
    }
    __syncthreads();
    #pragma unroll
    for (int ks = 0; ks < 2; ++ks) {
      bf16x8 af[4], bfr[4];
      #pragma unroll
      for (int m = 0; m < 4; ++m) {
        int row = wr * 64 + m * 16 + (lane & 15);
        int kb = ks * 32 + (lane >> 4) * 8;
        int idx = (row * 64 + kb) ^ ((row & 7) << 3);
        af[m] = *(const bf16x8*)(&Als[idx]);
      }
      #pragma unroll
      for (int n = 0; n < 4; ++n) {
        int row = wc * 64 + n * 16 + (lane & 15);
        int kb = ks * 32 + (lane >> 4) * 8;
        int idx = (row * 64 + kb) ^ ((row & 7) << 3);
        bfr[n] = *(const bf16x8*)(&Bls[idx]);
      }
      #pragma unroll
      for (int m = 0; m < 4; ++m)
        #pragma unroll
        for (int n = 0; n < 4; ++n)
          acc[m][n] = __builtin_amdgcn_mfma_f32_16x16x32_bf16(af[m], bfr[n], acc[m][n], 0, 0, 0);
    }
    __syncthreads();
  }
  const size_t kb2 = (size_t)k * NIND * NIND;
  #pragma unroll
  for (int m = 0; m < 4; ++m) {
    #pragma unroll
    for (int n = 0; n < 4; ++n) {
      #pragma unroll
      for (int r = 0; r < 4; ++r) {
        int gi = i0 + wr * 64 + m * 16 + (lane >> 4) * 4 + r;
        int gj = j0 + wc * 64 + n * 16 + (lane & 15);
        size_t idx = kb2 + (size_t)gi * NIND + gj;
        float v = acc[m][n][r] + prec[idx];
        Pb[idx] = (u16)f2bf(v);
      }
    }
  }
}

// K4: Gershgorin bound per class: gmax[k] = max_i sum_j |P_ij| (certified >= lambda_max)
__global__ __launch_bounds__(256) void gersh_kernel(
    const u16* __restrict__ Pb, unsigned* __restrict__ gmax)
{
  __shared__ float psum[64][17];
  const int k = blockIdx.y, rbk = blockIdx.x;
  const int tid = threadIdx.x;
  const size_t mb = (size_t)k * NIND * NIND;
  #pragma unroll
  for (int p = 0; p < 4; ++p) {
    int rl = p * 16 + (tid >> 4);
    int row = rbk * 64 + rl;
    int ch = tid & 15;
    float s = 0.f;
    const u16* base = Pb + mb + (size_t)row * NIND + ch * 64;
    #pragma unroll
    for (int c8 = 0; c8 < 8; ++c8) {
      uint4 u = *(const uint4*)(base + c8 * 8);
      const unsigned* uu = (const unsigned*)&u;
      #pragma unroll
      for (int q = 0; q < 4; ++q)
        s += fabsf(bflo(uu[q])) + fabsf(bfhi(uu[q]));
    }
    psum[rl][ch] = s;
  }
  __syncthreads();
  if (tid < 64) {
    float s = 0.f;
    #pragma unroll
    for (int j = 0; j < 16; ++j) s += psum[tid][j];
    psum[tid][16] = s;
  }
  __syncthreads();
  if (tid == 0) {
    float mx = 0.f;
    for (int t = 0; t < 64; ++t) mx = fmaxf(mx, psum[t][16]);
    atomicMax(gmax + k, __float_as_uint(mx));
  }
}

// K5: Chebyshev degree-2 initializer: X1 = b2*P^2 + b1*P + b0*I
__global__ __launch_bounds__(256) void cheb_kernel(
    const u16* __restrict__ Pb, const u16* __restrict__ Psq,
    const unsigned* __restrict__ gmax, u16* __restrict__ X)
{
  const int k = blockIdx.y;
  float G = __uint_as_float(gmax[k]) * 1.001f + 0.01f;
  if (G < 1.05f) G = 1.05f;
  float s = G + 1.0f, dd = G - 1.0f;
  float D3 = 4.0f * s * s * s - 3.0f * s * dd * dd;
  float b2 = 32.0f / D3;
  float b1 = -48.0f * s / D3;
  float b0 = (24.0f * s * s - 6.0f * dd * dd) / D3;
  size_t flat = ((size_t)blockIdx.x * 256 + threadIdx.x) * 8;
  int i = (int)(flat >> 10), j0 = (int)(flat & 1023);
  const size_t mb = (size_t)k * NIND * NIND;
  uint4 up = *(const uint4*)(Pb + mb + flat);
  uint4 uq = *(const uint4*)(Psq + mb + flat);
  const unsigned* pp = (const unsigned*)&up;
  const unsigned* qq = (const unsigned*)&uq;
  unsigned ow[4];
  #pragma unroll
  for (int q = 0; q < 4; ++q) {
    float lo = b2 * bflo(qq[q]) + b1 * bflo(pp[q]);
    float hi = b2 * bfhi(qq[q]) + b1 * bfhi(pp[q]);
    int cj = j0 + 2 * q;
    if (i == cj) lo += b0;
    if (i == cj + 1) hi += b0;
    ow[q] = (f2bf(lo) & 0xFFFFu) | (f2bf(hi) << 16);
  }
  *(uint4*)(X + mb + flat) = uint4{ow[0], ow[1], ow[2], ow[3]};
}

// K6: C = A (*) B^T; mode 1: C = 2*Xadd - A(*)B^T. Full 64 tiles, XCD swizzle.
__global__ __launch_bounds__(256) void ntgemm_kernel(
    const u16* __restrict__ A, const u16* __restrict__ B,
    const u16* __restrict__ Xadd, u16* __restrict__ C, int mode)
{
  __shared__ u16 Als[128 * 64];
  __shared__ u16 Bls[128 * 64];
  const int k = blockIdx.y;
  const int ti = blockIdx.x & 7, tj = blockIdx.x >> 3;   // XCD swizzle (T1)
  const int i0 = ti * 128, j0 = tj * 128;
  const int tid = threadIdx.x;
  const int wid = tid >> 6, lane = tid & 63;
  const int wr = wid >> 1, wc = wid & 1;
  const size_t mb = (size_t)k * NIND * NIND;
  const u16* Ag = A + mb + (size_t)i0 * NIND;
  const u16* Bg = B + mb + (size_t)j0 * NIND;
  f32x4 acc[4][4];
  #pragma unroll
  for (int m = 0; m < 4; ++m)
    #pragma unroll
    for (int n = 0; n < 4; ++n) acc[m][n] = (f32x4){0.f, 0.f, 0.f, 0.f};
  for (int kb = 0; kb < NIND; kb += 64) {
    #pragma unroll
    for (int c = 0; c < 4; ++c) {
      int f = c * 256 + tid;
      int row = f >> 3, s = f & 7;
      int sc = (s ^ (row & 7)) << 3;
      gload16(Ag + (size_t)row * NIND + kb + sc, Als + ((c * 256 + wid * 64) << 3));
      gload16(Bg + (size_t)row * NIND + kb + sc, Bls + ((c * 256 + wid * 64) << 3));
    }
    __syncthreads();
    #pragma unroll
    for (int ks = 0; ks < 2; ++ks) {
      bf16x8 af[4], bfr[4];
      #pragma unroll
      for (int m = 0; m < 4; ++m) {
        int row = wr * 64 + m * 16 + (lane & 15);
        int kq = ks * 32 + (lane >> 4) * 8;
        int idx = (row * 64 + kq) ^ ((row & 7) << 3);
        af[m] = *(const bf16x8*)(&Als[idx]);
      }
      #pragma unroll
      for (int n = 0; n < 4; ++n) {
        int row = wc * 64 + n * 16 + (lane & 15);
        int kq = ks * 32 + (lane >> 4) * 8;
        int idx = (row * 64 + kq) ^ ((row & 7) << 3);
        bfr[n] = *(const bf16x8*)(&Bls[idx]);
      }
      #pragma unroll
      for (int m = 0; m < 4; ++m)
        #pragma unroll
        for (int n = 0; n < 4; ++n)
          acc[m][n] = __builtin_amdgcn_mfma_f32_16x16x32_bf16(af[m], bfr[n], acc[m][n], 0, 0, 0);
    }
    __syncthreads();
  }
  #pragma unroll
  for (int m = 0; m < 4; ++m) {
    #pragma unroll
    for (int n = 0; n < 4; ++n) {
      #pragma unroll
      for (int r = 0; r < 4; ++r) {
        int gi = i0 + wr * 64 + m * 16 + (lane >> 4) * 4 + r;
        int gj = j0 + wc * 64 + n * 16 + (lane & 15);
        size_t idx = mb + (size_t)gi * NIND + gj;
        float v = acc[m][n][r];
        if (mode) v = 2.0f * bflo((unsigned)Xadd[idx]) - v;
        C[idx] = (u16)f2bf(v);
      }
    }
  }
}

// K7: variance GEMM: C = phi (*) M^T; epilogue * phi[b][i], row-reduce -> partial
__global__ __launch_bounds__(256) void vgemm_kernel(
    const u16* __restrict__ phiB, const u16* __restrict__ M,
    float* __restrict__ partial)
{
  __shared__ u16 Als[128 * 64];
  __shared__ u16 Bls[128 * 64];
  __shared__ float red[128][33];
  const int btile = blockIdx.x >> 3, It = blockIdx.x & 7;
  const int k = blockIdx.y;
  const int b0 = btile * 128, i0 = It * 128;
  const int tid = threadIdx.x;
  const int wid = tid >> 6, lane = tid & 63;
  const int wr = wid >> 1, wc = wid & 1;
  const int q = lane >> 4, l15 = lane & 15;
  const u16* Ag = phiB + (size_t)b0 * NIND;
  const u16* Bg = M + (size_t)k * NIND * NIND + (size_t)i0 * NIND;
  f32x4 acc[4][4];
  #pragma unroll
  for (int m = 0; m < 4; ++m)
    #pragma unroll
    for (int n = 0; n < 4; ++n) acc[m][n] = (f32x4){0.f, 0.f, 0.f, 0.f};
  for (int kb = 0; kb < NIND; kb += 64) {
    #pragma unroll
    for (int c = 0; c < 4; ++c) {
      int f = c * 256 + tid;
      int row = f >> 3, s = f & 7;
      int sc = (s ^ (row & 7)) << 3;
      gload16(Ag + (size_t)row * NIND + kb + sc, Als + ((c * 256 + wid * 64) << 3));
      gload16(Bg + (size_t)row * NIND + kb + sc, Bls + ((c * 256 + wid * 64) << 3));
    }
    __syncthreads();
    #pragma unroll
    for (int ks = 0; ks < 2; ++ks) {
      bf16x8 af[4], bfr[4];
      #pragma unroll
      for (int m = 0; m < 4; ++m) {
        int row = wr * 64 + m * 16 + l15;
        int kq = ks * 32 + q * 8;
        int idx = (row * 64 + kq) ^ ((row & 7) << 3);
        af[m] = *(const bf16x8*)(&Als[idx]);
      }
      #pragma unroll
      for (int n = 0; n < 4; ++n) {
        int row = wc * 64 + n * 16 + l15;
        int kq = ks * 32 + q * 8;
        int idx = (row * 64 + kq) ^ ((row & 7) << 3);
        bfr[n] = *(const bf16x8*)(&Bls[idx]);
      }
      #pragma unroll
      for (int m = 0; m < 4; ++m)
        #pragma unroll
        for (int n = 0; n < 4; ++n)
          acc[m][n] = __builtin_amdgcn_mfma_f32_16x16x32_bf16(af[m], bfr[n], acc[m][n], 0, 0, 0);
    }
    __syncthreads();
  }
  float vs[4][4] = {};
  #pragma unroll
  for (int m = 0; m < 4; ++m) {
    #pragma unroll
    for (int r = 0; r < 4; ++r) {
      int gb = b0 + wr * 64 + m * 16 + q * 4 + r;
      #pragma unroll
      for (int n = 0; n < 4; ++n) {
        int gi = i0 + wc * 64 + n * 16 + l15;
        float pv = bflo((unsigned)phiB[(size_t)gb * NIND + gi]);
        vs[m][r] += acc[m][n][r] * pv;
      }
    }
  }
  #pragma unroll
  for (int m = 0; m < 4; ++m)
    #pragma unroll
    for (int r = 0; r < 4; ++r)
      red[wr * 64 + m * 16 + q * 4 + r][wc * 16 + l15] = vs[m][r];
  __syncthreads();
  if (tid < 128) {
    float s = 0.f;
    #pragma unroll
    for (int t = 0; t < 32; ++t) s += red[tid][t];
    partial[((size_t)It * NCLS + k) * BATCH + b0 + tid] = s;
  }
}

// K8: out variances[b][k] = sum_It partial[It][k][b]
__global__ __launch_bounds__(256) void reduce_kernel(
    const float* __restrict__ partial, float* __restrict__ out)
{
  int t = blockIdx.x * 256 + threadIdx.x;
  int k = t >> 11, b = t & 2047;
  float s = 0.f;
  #pragma unroll
  for (int It = 0; It < 8; ++It)
    s += partial[((size_t)It * NCLS + k) * BATCH + b];
  out[(size_t)BATCH * NCLS + (size_t)b * NCLS + k] = s;
}

extern "C" void kernel_launch(void* const* d_in, const int* in_sizes, int n_in,
                              void* d_out, int out_size, void* d_ws, size_t ws_size,
                              hipStream_t stream)
{
  (void)in_sizes; (void)n_in; (void)ws_size;
  const float* x   = (const float*)d_in[0];
  const float* rw  = (const float*)d_in[1];
  const float* rb  = (const float*)d_in[2];
  const float* bw  = (const float*)d_in[3];
  const float* bb  = (const float*)d_in[4];
  const float* prc = (const float*)d_in[5];
  float* out = (float*)d_out;
  char* ws = (char*)d_ws;
  size_t off = 0;
  auto alloc = [&](size_t bytes) -> void* {
    void* p = ws + off;
    off = (off + bytes + 255) & ~(size_t)255;
    return p;
  };
  const size_t MSZ = (size_t)NCLS * NIND * NIND * 2;   // 32MB bf16 matrix
  u16*   xB     = (u16*)  alloc((size_t)BATCH * FEAT * 2);
  u16*   rwT    = (u16*)  alloc((size_t)NIND * FEAT * 2);
  u16*   phiB   = (u16*)  alloc((size_t)BATCH * NIND * 2);
  u16*   phiTB  = (u16*)  alloc((size_t)NIND * BATCH * 2);
  float* wmat   = (float*)alloc((size_t)NCLS * BATCH * 4);
  u16*   Pb     = (u16*)  alloc(MSZ);
  unsigned* gbound = (unsigned*)alloc((size_t)NCLS * 4);
  float* partial = (float*)alloc((size_t)8 * NCLS * BATCH * 4);
  u16*   Xa     = (u16*)alloc(MSZ);
  u16*   B2     = (u16*)alloc(MSZ);
  u16*   BY     = (u16*)alloc(MSZ);
  // phiW (64MB) aliases Xa+B2 (contiguous): dead before cheb writes Xa.
  u16*   phiW   = Xa;

  hipMemsetAsync(d_out, 0, (size_t)out_size * sizeof(float), stream);
  hipMemsetAsync(gbound, 0, (size_t)NCLS * 4, stream);
  xcast_kernel<<<dim3(BATCH * FEAT / 2048), 256, 0, stream>>>(x, xB);
  rwt_kernel<<<dim3(FEAT / 64, NIND / 64), 256, 0, stream>>>(rw, rwT);
  phimm_kernel<<<dim3(BATCH / 128, NIND / 128), 256, 0, stream>>>(xB, rwT, rb, phiB, phiTB);
  logits_kernel<<<dim3(BATCH / 16), 256, 0, stream>>>(phiB, bw, bb, out, wmat);
  scalew_kernel<<<dim3(1024, NCLS), 256, 0, stream>>>(phiTB, wmat, phiW);
  gram_kernel<<<dim3(64, NCLS), 256, 0, stream>>>(phiW, phiTB, prc, Pb);
  gersh_kernel<<<dim3(16, NCLS), 256, 0, stream>>>(Pb, gbound);
  const dim3 gg(64, NCLS);
  // Chebyshev degree-2 init: BY = P^2, then X1 = b2*P^2 + b1*P + b0*I
  ntgemm_kernel<<<gg, 256, 0, stream>>>(Pb, Pb, (u16*)nullptr, BY, 0);   // BY = P^2
  cheb_kernel<<<dim3(512, NCLS), 256, 0, stream>>>(Pb, BY, gbound, Xa);
  // 2 Newton iterations: BY = X*P ; X' = 2X - X*BY^T
  ntgemm_kernel<<<gg, 256, 0, stream>>>(Xa, Pb, (u16*)nullptr, BY, 0);
  ntgemm_kernel<<<gg, 256, 0, stream>>>(Xa, BY, Xa, B2, 1);
  ntgemm_kernel<<<gg, 256, 0, stream>>>(B2, Pb, (u16*)nullptr, BY, 0);
  ntgemm_kernel<<<gg, 256, 0, stream>>>(B2, BY, B2, Xa, 1);
  // variances: var_b = phi^T M phi, M = Xa
  vgemm_kernel<<<dim3(128, NCLS), 256, 0, stream>>>(phiB, Xa, partial);
  reduce_kernel<<<dim3(128), 256, 0, stream>>>(partial, out);
}

// Round 18
// 531.872 us; speedup vs baseline: 1.8558x; 1.1063x over previous
//
#include <hip/hip_runtime.h>
#include <hip/hip_bf16.h>

#define BATCH 2048
#define FEAT  768
#define NIND  1024
#define NCLS  16

typedef unsigned short u16;
typedef __attribute__((ext_vector_type(8))) __bf16 bf16x8;
typedef __attribute__((ext_vector_type(4))) float f32x4;

static __device__ __forceinline__ unsigned f2bf(float f) {
  unsigned u = __float_as_uint(f);
  unsigned r = ((u >> 16) & 1u) + 0x7FFFu;
  return (u + r) >> 16;                       // RNE bf16 in low 16 bits
}
static __device__ __forceinline__ float bflo(unsigned x) {
  return __uint_as_float((x & 0xFFFFu) << 16);
}
static __device__ __forceinline__ float bfhi(unsigned x) {
  return __uint_as_float(x & 0xFFFF0000u);
}

// async 16B global->LDS (LDS dest = wave-uniform base + lane*16)
static __device__ __forceinline__ void gload16(const u16* g, u16* l) {
  __builtin_amdgcn_global_load_lds(
      (const __attribute__((address_space(1))) void*)g,
      (__attribute__((address_space(3))) void*)l, 16, 0, 0);
}

// pack 8 bf16 (as uint4) scaled by wv[0..7] back to 8 bf16 (uint4)
static __device__ __forceinline__ uint4 scale8(uint4 v, const float* wv) {
  unsigned out[4];
  const unsigned* in = (const unsigned*)&v;
  #pragma unroll
  for (int i = 0; i < 4; ++i) {
    float lo = bflo(in[i]) * wv[2*i];
    float hi = bfhi(in[i]) * wv[2*i+1];
    __hip_bfloat162 pk = __float22bfloat162_rn(float2{lo, hi});
    out[i] = *(unsigned*)&pk;
  }
  return uint4{out[0], out[1], out[2], out[3]};
}

// K0a: xB = bf16(x), elementwise
__global__ __launch_bounds__(256) void xcast_kernel(
    const float* __restrict__ x, u16* __restrict__ xB)
{
  size_t f = ((size_t)blockIdx.x * 256 + threadIdx.x) * 8;
  float4 a = *(const float4*)(x + f);
  float4 b = *(const float4*)(x + f + 4);
  uint4 o;
  o.x = (f2bf(a.x) & 0xFFFFu) | (f2bf(a.y) << 16);
  o.y = (f2bf(a.z) & 0xFFFFu) | (f2bf(a.w) << 16);
  o.z = (f2bf(b.x) & 0xFFFFu) | (f2bf(b.y) << 16);
  o.w = (f2bf(b.z) & 0xFFFFu) | (f2bf(b.w) << 16);
  *(uint4*)(xB + f) = o;
}

// K0b: rwT[i][k] = bf16(rw[k][i])  (LDS-tiled transpose)
__global__ __launch_bounds__(256) void rwt_kernel(
    const float* __restrict__ rw, u16* __restrict__ rwT)
{
  __shared__ float ts[64][65];
  const int k0 = blockIdx.x * 64, i0 = blockIdx.y * 64;
  const int tid = threadIdx.x;
  #pragma unroll
  for (int t = 0; t < 4; ++t) {
    int f = t * 256 + tid;
    int r = f >> 4, c4 = (f & 15) << 2;
    *(float4*)(&ts[r][c4]) = *(const float4*)(rw + (size_t)(k0 + r) * NIND + i0 + c4);
  }
  __syncthreads();
  #pragma unroll
  for (int t = 0; t < 4; ++t) {
    int f = t * 256 + tid;
    int r = f >> 4, c4 = (f & 15) << 2;   // r = i-local, c4 = k-local base
    uint2 o;
    o.x = (f2bf(ts[c4+0][r]) & 0xFFFFu) | (f2bf(ts[c4+1][r]) << 16);
    o.y = (f2bf(ts[c4+2][r]) & 0xFFFFu) | (f2bf(ts[c4+3][r]) << 16);
    *(uint2*)(rwT + (size_t)(i0 + r) * FEAT + k0 + c4) = o;
  }
}

// K1: MFMA phi. phiB[b][i], phiTB[i][b] = bf16(SC*cos(2*(x@W+b))). K=768.
__global__ __launch_bounds__(256) void phimm_kernel(
    const u16* __restrict__ xB, const u16* __restrict__ rwT,
    const float* __restrict__ rb, u16* __restrict__ phiB,
    u16* __restrict__ phiTB)
{
  __shared__ u16 sh[128 * 128];      // staging (2x 128x64) then transpose tile
  u16* Als = sh;
  u16* Bls = sh + 8192;
  const int b0 = blockIdx.x * 128, i0 = blockIdx.y * 128;
  const int tid = threadIdx.x;
  const int wid = tid >> 6, lane = tid & 63;
  const int wr = wid >> 1, wc = wid & 1;
  const u16* Ag = xB + (size_t)b0 * FEAT;
  const u16* Bg = rwT + (size_t)i0 * FEAT;
  f32x4 acc[4][4];
  #pragma unroll
  for (int m = 0; m < 4; ++m)
    #pragma unroll
    for (int n = 0; n < 4; ++n) acc[m][n] = (f32x4){0.f, 0.f, 0.f, 0.f};
  for (int kb = 0; kb < FEAT; kb += 64) {
    #pragma unroll
    for (int c = 0; c < 4; ++c) {
      int f = c * 256 + tid;
      int row = f >> 3, s = f & 7;
      int sc = (s ^ (row & 7)) << 3;
      gload16(Ag + (size_t)row * FEAT + kb + sc, Als + ((c * 256 + wid * 64) << 3));
      gload16(Bg + (size_t)row * FEAT + kb + sc, Bls + ((c * 256 + wid * 64) << 3));
    }
    __syncthreads();
    #pragma unroll
    for (int ks = 0; ks < 2; ++ks) {
      bf16x8 af[4], bfr[4];
      #pragma unroll
      for (int m = 0; m < 4; ++m) {
        int row = wr * 64 + m * 16 + (lane & 15);
        int kq = ks * 32 + (lane >> 4) * 8;
        int idx = (row * 64 + kq) ^ ((row & 7) << 3);
        af[m] = *(const bf16x8*)(&Als[idx]);
      }
      #pragma unroll
      for (int n = 0; n < 4; ++n) {
        int row = wc * 64 + n * 16 + (lane & 15);
        int kq = ks * 32 + (lane >> 4) * 8;
        int idx = (row * 64 + kq) ^ ((row & 7) << 3);
        bfr[n] = *(const bf16x8*)(&Bls[idx]);
      }
      #pragma unroll
      for (int m = 0; m < 4; ++m)
        #pragma unroll
        for (int n = 0; n < 4; ++n)
          acc[m][n] = __builtin_amdgcn_mfma_f32_16x16x32_bf16(af[m], bfr[n], acc[m][n], 0, 0, 0);
    }
    __syncthreads();
  }
  const float SC = 0.04419417382415922f;   // sqrt(2/1024)
  float rbl[4];
  #pragma unroll
  for (int n = 0; n < 4; ++n) rbl[n] = rb[i0 + wc * 64 + n * 16 + (lane & 15)];
  #pragma unroll
  for (int m = 0; m < 4; ++m) {
    #pragma unroll
    for (int n = 0; n < 4; ++n) {
      #pragma unroll
      for (int r = 0; r < 4; ++r) {
        int lb = wr * 64 + m * 16 + (lane >> 4) * 4 + r;
        int li = wc * 64 + n * 16 + (lane & 15);
        float proj = 2.0f * (acc[m][n][r] + rbl[n]);
        u16 bv = (u16)f2bf(SC * cosf(proj));
        phiB[(size_t)(b0 + lb) * NIND + i0 + li] = bv;
        int idx = (li * 128 + lb) ^ ((li & 7) << 3);
        sh[idx] = bv;
      }
    }
  }
  __syncthreads();
  #pragma unroll
  for (int t = 0; t < 8; ++t) {
    int f = t * 256 + tid;             // 2048 uint4-slots over 128x128 u16
    int li = f >> 4, c8 = (f & 15) << 3;
    int idx = (li * 128 + c8) ^ ((li & 7) << 3);
    uint4 v = *(const uint4*)(&sh[idx]);
    *(uint4*)(phiTB + (size_t)(i0 + li) * BATCH + b0 + c8) = v;
  }
}

// K2: logits from phiB (bf16), 16 batch rows per block, thread = (row, class)
__global__ __launch_bounds__(256) void logits_kernel(
    const u16* __restrict__ phiB, const float* __restrict__ bw,
    const float* __restrict__ bbias, float* __restrict__ out,
    float* __restrict__ wmat)
{
  __shared__ float ph[16][132];
  __shared__ float bwl[16][132];
  __shared__ float lg[16][17];
  const int b0 = blockIdx.x * 16;
  const int tid = threadIdx.x;
  const int bl = tid & 15, kq = tid >> 4;
  float acc = 0.f;
  for (int kb = 0; kb < NIND; kb += 128) {
    {
      int row = tid >> 4, c8 = (tid & 15) << 3;
      uint4 v = *(const uint4*)(phiB + (size_t)(b0 + row) * NIND + kb + c8);
      const unsigned* u = (const unsigned*)&v;
      #pragma unroll
      for (int j = 0; j < 4; ++j) {
        ph[row][c8 + 2*j]     = bflo(u[j]);
        ph[row][c8 + 2*j + 1] = bfhi(u[j]);
      }
    }
    #pragma unroll
    for (int t = 0; t < 2; ++t) {
      int f = t * 256 + tid;
      int row = f >> 5, c4 = (f & 31) << 2;
      *(float4*)(&bwl[row][c4]) = *(const float4*)(bw + (size_t)row * NIND + kb + c4);
    }
    __syncthreads();
    #pragma unroll 8
    for (int q = 0; q < 128; q += 4) {
      float4 a = *(const float4*)(&ph[bl][q]);
      float4 b4 = *(const float4*)(&bwl[kq][q]);
      acc += a.x*b4.x + a.y*b4.y + a.z*b4.z + a.w*b4.w;
    }
    __syncthreads();
  }
  float v = acc + bbias[kq];
  lg[bl][kq] = v;
  out[(size_t)(b0 + bl) * NCLS + kq] = v;
  __syncthreads();
  if (tid < 16) {
    float mx = -1e30f;
    #pragma unroll
    for (int k = 0; k < 16; ++k) mx = fmaxf(mx, lg[tid][k]);
    float s = 0.f, ex[16];
    #pragma unroll
    for (int k = 0; k < 16; ++k) { ex[k] = expf(lg[tid][k] - mx); s += ex[k]; }
    float inv = 1.0f / s;
    #pragma unroll
    for (int k = 0; k < 16; ++k) {
      float p = ex[k] * inv;
      wmat[(size_t)k * BATCH + b0 + tid] = p * (1.0f - p);
    }
  }
}

// K2b: phiW[k][i][b] = bf16(wmat[k][b] * phi[i][b])  (from bf16 phiTB)
__global__ __launch_bounds__(256) void scalew_kernel(
    const u16* __restrict__ phiTB, const float* __restrict__ wmat,
    u16* __restrict__ phiW)
{
  const int k = blockIdx.y;
  size_t flat = ((size_t)blockIdx.x * 256 + threadIdx.x) * 8;
  int b = (int)(flat & 2047);
  uint4 pv = *(const uint4*)(phiTB + flat);
  float4 w0 = *(const float4*)(wmat + (size_t)k * BATCH + b);
  float4 w1 = *(const float4*)(wmat + (size_t)k * BATCH + b + 4);
  float wv[8] = {w0.x, w0.y, w0.z, w0.w, w1.x, w1.y, w1.z, w1.w};
  *(uint4*)(phiW + (size_t)k * NIND * BATCH + flat) = scale8(pv, wv);
}

// K3: MFMA bf16 gram -> Pb bf16. FULL 64-tile grid (4 blocks/CU hides the
// 2-barrier-per-K-step latency; R17-verified). XCD = ti.
__global__ __launch_bounds__(256) void gram_kernel(
    const u16* __restrict__ phiW, const u16* __restrict__ phiTB,
    const float* __restrict__ prec, u16* __restrict__ Pb)
{
  __shared__ u16 Als[128 * 64];
  __shared__ u16 Bls[128 * 64];
  const int ti = blockIdx.x & 7, tj = blockIdx.x >> 3;   // XCD = ti
  const int k = blockIdx.y;
  const int i0 = ti * 128, j0 = tj * 128;
  const int tid = threadIdx.x;
  const int wid = tid >> 6, lane = tid & 63;
  const int wr = wid >> 1, wc = wid & 1;
  const u16* Ag = phiW + (size_t)k * NIND * BATCH + (size_t)i0 * BATCH;
  const u16* Bg = phiTB + (size_t)j0 * BATCH;
  f32x4 acc[4][4];
  #pragma unroll
  for (int m = 0; m < 4; ++m)
    #pragma unroll
    for (int n = 0; n < 4; ++n) acc[m][n] = (f32x4){0.f, 0.f, 0.f, 0.f};
  for (int b0 = 0; b0 < BATCH; b0 += 64) {
    #pragma unroll
    for (int c = 0; c < 4; ++c) {
      int f = c * 256 + tid;
      int row = f >> 3, s = f & 7;
      int sc = (s ^ (row & 7)) << 3;
      gload16(Ag + (size_t)row * BATCH + b0 + sc, Als + ((c * 256 + wid * 64) << 3));
      gload16(Bg + (size_t)row * BATCH + b0 + sc, Bls + ((c * 256 + wid * 64) << 3));
    }
    __syncthreads();
    #pragma unroll
    for (int ks = 0; ks < 2; ++ks) {
      bf16x8 af[4], bfr[4];
      #pragma unroll
      for (int m = 0; m < 4; ++m) {
        int row = wr * 64 + m * 16 + (lane & 15);
        int kb = ks * 32 + (lane >> 4) * 8;
        int idx = (row * 64 + kb) ^ ((row & 7) << 3);
        af[m] = *(const bf16x8*)(&Als[idx]);
      }
      #pragma unroll
      for (int n = 0; n < 4; ++n) {
        int row = wc * 64 + n * 16 + (lane & 15);
        int kb = ks * 32 + (lane >> 4) * 8;
        int idx = (row * 64 + kb) ^ ((row & 7) << 3);
        bfr[n] = *(const bf16x8*)(&Bls[idx]);
      }
      #pragma unroll
      for (int m = 0; m < 4; ++m)
        #pragma unroll
        for (int n = 0; n < 4; ++n)
          acc[m][n] = __builtin_amdgcn_mfma_f32_16x16x32_bf16(af[m], bfr[n], acc[m][n], 0, 0, 0);
    }
    __syncthreads();
  }
  const size_t kb2 = (size_t)k * NIND * NIND;
  #pragma unroll
  for (int m = 0; m < 4; ++m) {
    #pragma unroll
    for (int n = 0; n < 4; ++n) {
      #pragma unroll
      for (int r = 0; r < 4; ++r) {
        int gi = i0 + wr * 64 + m * 16 + (lane >> 4) * 4 + r;
        int gj = j0 + wc * 64 + n * 16 + (lane & 15);
        size_t idx = kb2 + (size_t)gi * NIND + gj;
        float v = acc[m][n][r] + prec[idx];
        Pb[idx] = (u16)f2bf(v);
      }
    }
  }
}

// K4: Gershgorin bound per class: gmax[k] = max_i sum_j |P_ij| (certified >= lambda_max)
__global__ __launch_bounds__(256) void gersh_kernel(
    const u16* __restrict__ Pb, unsigned* __restrict__ gmax)
{
  __shared__ float psum[64][17];
  const int k = blockIdx.y, rbk = blockIdx.x;
  const int tid = threadIdx.x;
  const size_t mb = (size_t)k * NIND * NIND;
  #pragma unroll
  for (int p = 0; p < 4; ++p) {
    int rl = p * 16 + (tid >> 4);
    int row = rbk * 64 + rl;
    int ch = tid & 15;
    float s = 0.f;
    const u16* base = Pb + mb + (size_t)row * NIND + ch * 64;
    #pragma unroll
    for (int c8 = 0; c8 < 8; ++c8) {
      uint4 u = *(const uint4*)(base + c8 * 8);
      const unsigned* uu = (const unsigned*)&u;
      #pragma unroll
      for (int q = 0; q < 4; ++q)
        s += fabsf(bflo(uu[q])) + fabsf(bfhi(uu[q]));
    }
    psum[rl][ch] = s;
  }
  __syncthreads();
  if (tid < 64) {
    float s = 0.f;
    #pragma unroll
    for (int j = 0; j < 16; ++j) s += psum[tid][j];
    psum[tid][16] = s;
  }
  __syncthreads();
  if (tid == 0) {
    float mx = 0.f;
    for (int t = 0; t < 64; ++t) mx = fmaxf(mx, psum[t][16]);
    atomicMax(gmax + k, __float_as_uint(mx));
  }
}

// K6: GEMM C = A (*) B^T with epilogue modes. Full 64 tiles, XCD swizzle.
// mode 0: C = acc
// mode 1: C = 2*Xadd - acc                      (Newton second half)
// mode 2: C = a3*acc + a2*Xadd + a1*Pex + a0*I  (deg-3 Chebyshev init;
//         A=P^2, B=P so acc = P^3; coefficients from certified G.
//         Formulas HW-validated in R13: residual = 1/T4((G+1)/(G-1)).)
__global__ __launch_bounds__(256) void ntgemm_kernel(
    const u16* __restrict__ A, const u16* __restrict__ B,
    const u16* __restrict__ Xadd, const u16* __restrict__ Pex,
    const unsigned* __restrict__ gmax, u16* __restrict__ C, int mode)
{
  __shared__ u16 Als[128 * 64];
  __shared__ u16 Bls[128 * 64];
  const int k = blockIdx.y;
  const int ti = blockIdx.x & 7, tj = blockIdx.x >> 3;   // XCD swizzle (T1)
  const int i0 = ti * 128, j0 = tj * 128;
  const int tid = threadIdx.x;
  const int wid = tid >> 6, lane = tid & 63;
  const int wr = wid >> 1, wc = wid & 1;
  const size_t mb = (size_t)k * NIND * NIND;
  const u16* Ag = A + mb + (size_t)i0 * NIND;
  const u16* Bg = B + mb + (size_t)j0 * NIND;
  f32x4 acc[4][4];
  #pragma unroll
  for (int m = 0; m < 4; ++m)
    #pragma unroll
    for (int n = 0; n < 4; ++n) acc[m][n] = (f32x4){0.f, 0.f, 0.f, 0.f};
  for (int kb = 0; kb < NIND; kb += 64) {
    #pragma unroll
    for (int c = 0; c < 4; ++c) {
      int f = c * 256 + tid;
      int row = f >> 3, s = f & 7;
      int sc = (s ^ (row & 7)) << 3;
      gload16(Ag + (size_t)row * NIND + kb + sc, Als + ((c * 256 + wid * 64) << 3));
      gload16(Bg + (size_t)row * NIND + kb + sc, Bls + ((c * 256 + wid * 64) << 3));
    }
    __syncthreads();
    #pragma unroll
    for (int ks = 0; ks < 2; ++ks) {
      bf16x8 af[4], bfr[4];
      #pragma unroll
      for (int m = 0; m < 4; ++m) {
        int row = wr * 64 + m * 16 + (lane & 15);
        int kq = ks * 32 + (lane >> 4) * 8;
        int idx = (row * 64 + kq) ^ ((row & 7) << 3);
        af[m] = *(const bf16x8*)(&Als[idx]);
      }
      #pragma unroll
      for (int n = 0; n < 4; ++n) {
        int row = wc * 64 + n * 16 + (lane & 15);
        int kq = ks * 32 + (lane >> 4) * 8;
        int idx = (row * 64 + kq) ^ ((row & 7) << 3);
        bfr[n] = *(const bf16x8*)(&Bls[idx]);
      }
      #pragma unroll
      for (int m = 0; m < 4; ++m)
        #pragma unroll
        for (int n = 0; n < 4; ++n)
          acc[m][n] = __builtin_amdgcn_mfma_f32_16x16x32_bf16(af[m], bfr[n], acc[m][n], 0, 0, 0);
    }
    __syncthreads();
  }
  float a0 = 0.f, a1 = 0.f, a2 = 0.f, a3 = 0.f;
  if (mode == 2) {
    float G = __uint_as_float(gmax[k]) * 1.001f + 0.01f;
    if (G < 1.05f) G = 1.05f;
    float s = 1.0f + G, dd = G - 1.0f;
    float s2 = s * s, d2 = dd * dd;
    float D = 8.0f * s2 * s2 - 8.0f * d2 * s2 + d2 * d2;
    a3 = -128.0f / D;
    a2 = 256.0f * s / D;
    a1 = -(192.0f * s2 - 32.0f * d2) / D;
    a0 = (64.0f * s2 * s - 32.0f * d2 * s) / D;
  }
  #pragma unroll
  for (int m = 0; m < 4; ++m) {
    #pragma unroll
    for (int n = 0; n < 4; ++n) {
      #pragma unroll
      for (int r = 0; r < 4; ++r) {
        int gi = i0 + wr * 64 + m * 16 + (lane >> 4) * 4 + r;
        int gj = j0 + wc * 64 + n * 16 + (lane & 15);
        size_t idx = mb + (size_t)gi * NIND + gj;
        float v = acc[m][n][r];
        if (mode == 1) {
          v = 2.0f * bflo((unsigned)Xadd[idx]) - v;
        } else if (mode == 2) {
          v = a3 * v + a2 * bflo((unsigned)Xadd[idx]) + a1 * bflo((unsigned)Pex[idx]);
          if (gi == gj) v += a0;
        }
        C[idx] = (u16)f2bf(v);
      }
    }
  }
}

// K7: variance GEMM: C = phi (*) M^T; epilogue * phi[b][i], row-reduce -> partial
__global__ __launch_bounds__(256) void vgemm_kernel(
    const u16* __restrict__ phiB, const u16* __restrict__ M,
    float* __restrict__ partial)
{
  __shared__ u16 Als[128 * 64];
  __shared__ u16 Bls[128 * 64];
  __shared__ float red[128][33];
  const int btile = blockIdx.x >> 3, It = blockIdx.x & 7;
  const int k = blockIdx.y;
  const int b0 = btile * 128, i0 = It * 128;
  const int tid = threadIdx.x;
  const int wid = tid >> 6, lane = tid & 63;
  const int wr = wid >> 1, wc = wid & 1;
  const int q = lane >> 4, l15 = lane & 15;
  const u16* Ag = phiB + (size_t)b0 * NIND;
  const u16* Bg = M + (size_t)k * NIND * NIND + (size_t)i0 * NIND;
  f32x4 acc[4][4];
  #pragma unroll
  for (int m = 0; m < 4; ++m)
    #pragma unroll
    for (int n = 0; n < 4; ++n) acc[m][n] = (f32x4){0.f, 0.f, 0.f, 0.f};
  for (int kb = 0; kb < NIND; kb += 64) {
    #pragma unroll
    for (int c = 0; c < 4; ++c) {
      int f = c * 256 + tid;
      int row = f >> 3, s = f & 7;
      int sc = (s ^ (row & 7)) << 3;
      gload16(Ag + (size_t)row * NIND + kb + sc, Als + ((c * 256 + wid * 64) << 3));
      gload16(Bg + (size_t)row * NIND + kb + sc, Bls + ((c * 256 + wid * 64) << 3));
    }
    __syncthreads();
    #pragma unroll
    for (int ks = 0; ks < 2; ++ks) {
      bf16x8 af[4], bfr[4];
      #pragma unroll
      for (int m = 0; m < 4; ++m) {
        int row = wr * 64 + m * 16 + l15;
        int kq = ks * 32 + q * 8;
        int idx = (row * 64 + kq) ^ ((row & 7) << 3);
        af[m] = *(const bf16x8*)(&Als[idx]);
      }
      #pragma unroll
      for (int n = 0; n < 4; ++n) {
        int row = wc * 64 + n * 16 + l15;
        int kq = ks * 32 + q * 8;
        int idx = (row * 64 + kq) ^ ((row & 7) << 3);
        bfr[n] = *(const bf16x8*)(&Bls[idx]);
      }
      #pragma unroll
      for (int m = 0; m < 4; ++m)
        #pragma unroll
        for (int n = 0; n < 4; ++n)
          acc[m][n] = __builtin_amdgcn_mfma_f32_16x16x32_bf16(af[m], bfr[n], acc[m][n], 0, 0, 0);
    }
    __syncthreads();
  }
  float vs[4][4] = {};
  #pragma unroll
  for (int m = 0; m < 4; ++m) {
    #pragma unroll
    for (int r = 0; r < 4; ++r) {
      int gb = b0 + wr * 64 + m * 16 + q * 4 + r;
      #pragma unroll
      for (int n = 0; n < 4; ++n) {
        int gi = i0 + wc * 64 + n * 16 + l15;
        float pv = bflo((unsigned)phiB[(size_t)gb * NIND + gi]);
        vs[m][r] += acc[m][n][r] * pv;
      }
    }
  }
  #pragma unroll
  for (int m = 0; m < 4; ++m)
    #pragma unroll
    for (int r = 0; r < 4; ++r)
      red[wr * 64 + m * 16 + q * 4 + r][wc * 16 + l15] = vs[m][r];
  __syncthreads();
  if (tid < 128) {
    float s = 0.f;
    #pragma unroll
    for (int t = 0; t < 32; ++t) s += red[tid][t];
    partial[((size_t)It * NCLS + k) * BATCH + b0 + tid] = s;
  }
}

// K8: out variances[b][k] = sum_It partial[It][k][b]
__global__ __launch_bounds__(256) void reduce_kernel(
    const float* __restrict__ partial, float* __restrict__ out)
{
  int t = blockIdx.x * 256 + threadIdx.x;
  int k = t >> 11, b = t & 2047;
  float s = 0.f;
  #pragma unroll
  for (int It = 0; It < 8; ++It)
    s += partial[((size_t)It * NCLS + k) * BATCH + b];
  out[(size_t)BATCH * NCLS + (size_t)b * NCLS + k] = s;
}

extern "C" void kernel_launch(void* const* d_in, const int* in_sizes, int n_in,
                              void* d_out, int out_size, void* d_ws, size_t ws_size,
                              hipStream_t stream)
{
  (void)in_sizes; (void)n_in; (void)ws_size;
  const float* x   = (const float*)d_in[0];
  const float* rw  = (const float*)d_in[1];
  const float* rb  = (const float*)d_in[2];
  const float* bw  = (const float*)d_in[3];
  const float* bb  = (const float*)d_in[4];
  const float* prc = (const float*)d_in[5];
  float* out = (float*)d_out;
  char* ws = (char*)d_ws;
  size_t off = 0;
  auto alloc = [&](size_t bytes) -> void* {
    void* p = ws + off;
    off = (off + bytes + 255) & ~(size_t)255;
    return p;
  };
  const size_t MSZ = (size_t)NCLS * NIND * NIND * 2;   // 32MB bf16 matrix
  u16*   xB     = (u16*)  alloc((size_t)BATCH * FEAT * 2);
  u16*   rwT    = (u16*)  alloc((size_t)NIND * FEAT * 2);
  u16*   phiB   = (u16*)  alloc((size_t)BATCH * NIND * 2);
  u16*   phiTB  = (u16*)  alloc((size_t)NIND * BATCH * 2);
  float* wmat   = (float*)alloc((size_t)NCLS * BATCH * 4);
  u16*   Pb     = (u16*)  alloc(MSZ);
  unsigned* gbound = (unsigned*)alloc((size_t)NCLS * 4);
  float* partial = (float*)alloc((size_t)8 * NCLS * BATCH * 4);
  u16*   Xa     = (u16*)alloc(MSZ);
  u16*   B2     = (u16*)alloc(MSZ);
  u16*   BY     = (u16*)alloc(MSZ);
  // phiW (64MB) aliases Xa+B2 (contiguous): dead before G2 writes Xa.
  u16*   phiW   = Xa;

  hipMemsetAsync(d_out, 0, (size_t)out_size * sizeof(float), stream);
  hipMemsetAsync(gbound, 0, (size_t)NCLS * 4, stream);
  xcast_kernel<<<dim3(BATCH * FEAT / 2048), 256, 0, stream>>>(x, xB);
  rwt_kernel<<<dim3(FEAT / 64, NIND / 64), 256, 0, stream>>>(rw, rwT);
  phimm_kernel<<<dim3(BATCH / 128, NIND / 128), 256, 0, stream>>>(xB, rwT, rb, phiB, phiTB);
  logits_kernel<<<dim3(BATCH / 16), 256, 0, stream>>>(phiB, bw, bb, out, wmat);
  scalew_kernel<<<dim3(1024, NCLS), 256, 0, stream>>>(phiTB, wmat, phiW);
  gram_kernel<<<dim3(64, NCLS), 256, 0, stream>>>(phiW, phiTB, prc, Pb);
  gersh_kernel<<<dim3(16, NCLS), 256, 0, stream>>>(Pb, gbound);
  const dim3 gg(64, NCLS);
  // G1: BY = P^2
  ntgemm_kernel<<<gg, 256, 0, stream>>>(Pb, Pb, (u16*)nullptr, (u16*)nullptr,
                                        (unsigned*)nullptr, BY, 0);
  // G2: Xa = a3*P^3 + a2*P^2 + a1*P + a0*I  (cheb-3 fused into the P^3 GEMM)
  ntgemm_kernel<<<gg, 256, 0, stream>>>(BY, Pb, BY, Pb, gbound, Xa, 2);
  // G3+G4: one Newton iteration: BY = Xa*P ; B2 = 2*Xa - Xa*BY^T
  ntgemm_kernel<<<gg, 256, 0, stream>>>(Xa, Pb, (u16*)nullptr, (u16*)nullptr,
                                        (unsigned*)nullptr, BY, 0);
  ntgemm_kernel<<<gg, 256, 0, stream>>>(Xa, BY, Xa, (u16*)nullptr,
                                        (unsigned*)nullptr, B2, 1);
  // variances: var_b = phi^T M phi, M = B2
  vgemm_kernel<<<dim3(128, NCLS), 256, 0, stream>>>(phiB, B2, partial);
  reduce_kernel<<<dim3(128), 256, 0, stream>>>(partial, out);
}